// Round 1
// baseline (3983.097 us; speedup 1.0000x reference)
//
#include <hip/hip_runtime.h>

constexpr int kB = 4, kN = 1024, kIn = 8, kD = 128, kH = 8, kNC = 64,
              kDK = 16, kFF = 512, kEnc = 6, kR = kB * kN;

__device__ __forceinline__ float wredsum(float v) {
  v += __shfl_xor(v, 1);  v += __shfl_xor(v, 2);  v += __shfl_xor(v, 4);
  v += __shfl_xor(v, 8);  v += __shfl_xor(v, 16); v += __shfl_xor(v, 32);
  return v;
}
__device__ __forceinline__ float wredmax(float v) {
  v = fmaxf(v, __shfl_xor(v, 1));  v = fmaxf(v, __shfl_xor(v, 2));
  v = fmaxf(v, __shfl_xor(v, 4));  v = fmaxf(v, __shfl_xor(v, 8));
  v = fmaxf(v, __shfl_xor(v, 16)); v = fmaxf(v, __shfl_xor(v, 32));
  return v;
}

// ---- prologue kernels ----

__global__ __launch_bounds__(256) void repack_qkv(
    const float* __restrict__ wq, const float* __restrict__ wk,
    const float* __restrict__ wv, float* __restrict__ oq,
    float* __restrict__ ok, float* __restrict__ ov, int layers) {
  int i = blockIdx.x * 256 + threadIdx.x;
  if (i >= layers * kD * kD) return;
  int l = i / (kD * kD);
  int rem = i - l * kD * kD;
  int d = rem >> 7;
  int c = rem & 127;
  int src = ((l * kH + (c >> 4)) * kD + d) * kDK + (c & 15);
  oq[i] = wq[src]; ok[i] = wk[src]; ov[i] = wv[src];
}

__global__ __launch_bounds__(256) void pack_mask(
    const int* __restrict__ edge_mask, const int* __restrict__ pad_mask,
    unsigned long long* __restrict__ bits) {
  int row = blockIdx.x;  // b*N + q
  int b = row / kN;
  int lane = threadIdx.x & 63;
  int wv = threadIdx.x >> 6;
  for (int c0 = wv; c0 < 16; c0 += 4) {
    int k = c0 * 64 + lane;
    int m = edge_mask[(size_t)row * kN + k] + pad_mask[b * kN + k];
    unsigned long long bal = __ballot(m > 0);
    if (lane == 0) bits[(size_t)row * 16 + c0] = bal;
  }
}

__global__ __launch_bounds__(256) void pack_pad(
    const int* __restrict__ pad_mask, unsigned long long* __restrict__ bits) {
  int b = blockIdx.x;
  int lane = threadIdx.x & 63;
  int wv = threadIdx.x >> 6;
  for (int c0 = wv; c0 < 16; c0 += 4) {
    int k = c0 * 64 + lane;
    unsigned long long bal = __ballot(pad_mask[b * kN + k] > 0);
    if (lane == 0) bits[b * 16 + c0] = bal;
  }
}

__global__ __launch_bounds__(256) void init_proj(
    const float* __restrict__ ni, const float* __restrict__ W,
    const float* __restrict__ bias, float* __restrict__ x) {
  int i = blockIdx.x * 256 + threadIdx.x;  // r*128 + c
  int r = i >> 7, c = i & 127;
  float acc = bias[c];
#pragma unroll
  for (int k = 0; k < kIn; k++) acc = fmaf(ni[r * kIn + k], W[k * kD + c], acc);
  x[i] = acc;
}

// ---- layernorm: one wave per row ----
__global__ __launch_bounds__(256) void ln_kernel(
    const float* __restrict__ x, const float* __restrict__ g,
    const float* __restrict__ b, float* __restrict__ out, int rows) {
  int wid = (blockIdx.x * 256 + threadIdx.x) >> 6;
  if (wid >= rows) return;
  int lane = threadIdx.x & 63;
  float2 v = *(const float2*)(x + (size_t)wid * kD + lane * 2);
  float mean = wredsum(v.x + v.y) * (1.0f / kD);
  float dx = v.x - mean, dy = v.y - mean;
  float var = wredsum(dx * dx + dy * dy) * (1.0f / kD);
  float rstd = rsqrtf(var + 1e-5f);
  int c = lane * 2;
  float2 o;
  o.x = dx * rstd * g[c] + b[c];
  o.y = dy * rstd * g[c + 1] + b[c + 1];
  *(float2*)(out + (size_t)wid * kD + c) = o;
}

// ---- generic fp32 GEMM: out[r][c] = A[r][:K] @ W[:K][c] (+bias)(+resid)(relu) ----
// block: 256 threads -> 16 rows x 128 cols tile; grid.y picks 128-col slab.
__global__ __launch_bounds__(256) void gemm_f32(
    const float* __restrict__ A, const float* __restrict__ W,
    const float* __restrict__ bias, const float* __restrict__ resid,
    float* __restrict__ out, int Rr, int K, int C, int relu, int out_bhne) {
  __shared__ float As[16][128];
  int tc = threadIdx.x & 127;
  int rsel = threadIdx.x >> 7;
  int c = blockIdx.y * 128 + tc;
  int r0 = blockIdx.x * 16;
  float acc[8];
#pragma unroll
  for (int j = 0; j < 8; j++) acc[j] = 0.f;
  for (int k0 = 0; k0 < K; k0 += 128) {
#pragma unroll
    for (int t = threadIdx.x; t < 2048; t += 256) {
      int rr = t >> 7, kk = t & 127;
      As[rr][kk] = (r0 + rr < Rr) ? A[(size_t)(r0 + rr) * K + k0 + kk] : 0.f;
    }
    __syncthreads();
#pragma unroll 4
    for (int k = 0; k < 128; k++) {
      float w = W[(size_t)(k0 + k) * C + c];
#pragma unroll
      for (int j = 0; j < 8; j++) acc[j] = fmaf(As[rsel + j * 2][k], w, acc[j]);
    }
    __syncthreads();
  }
  float bv = bias ? bias[c] : 0.f;
#pragma unroll
  for (int j = 0; j < 8; j++) {
    int r = r0 + rsel + j * 2;
    if (r < Rr) {
      float v = acc[j] + bv;
      if (resid) v += resid[(size_t)r * C + c];
      if (relu) v = fmaxf(v, 0.f);
      size_t oi;
      if (out_bhne) {
        int bb = r / kN, n = r % kN;
        int hh = c >> 4, e = c & 15;
        oi = (((size_t)(bb * kH + hh)) * kN + n) * kDK + e;
      } else {
        oi = (size_t)r * C + c;
      }
      out[oi] = v;
    }
  }
}

// ---- attention: one wave per (b,h,q); lane owns keys k = c*64+lane ----
__global__ __launch_bounds__(256) void attn_kernel(
    const float* __restrict__ Q, const float* __restrict__ K,
    const float* __restrict__ V, const unsigned long long* __restrict__ bits,
    float* __restrict__ Hd, int nq) {
  int wid = (blockIdx.x * 256 + threadIdx.x) >> 6;
  int total = kB * kH * nq;
  if (wid >= total) return;
  int lane = threadIdx.x & 63;
  int q = wid % nq;
  int bh = wid / nq;
  int b = bh / kH, h = bh % kH;
  const float4* qp = (const float4*)(Q + ((size_t)bh * nq + q) * kDK);
  float4 q0 = qp[0], q1 = qp[1], q2 = qp[2], q3 = qp[3];
  const unsigned long long* mrow = bits + ((size_t)b * nq + q) * 16;
  const float* Kb = K + (size_t)bh * kN * kDK;
  const float* Vb = V + (size_t)bh * kN * kDK;
  float s[16];
#pragma unroll
  for (int cc = 0; cc < 16; cc++) {
    int k = cc * 64 + lane;
    const float4* kp = (const float4*)(Kb + (size_t)k * kDK);
    float4 k0 = kp[0], k1 = kp[1], k2 = kp[2], k3 = kp[3];
    float d = q0.x * k0.x + q0.y * k0.y + q0.z * k0.z + q0.w * k0.w
            + q1.x * k1.x + q1.y * k1.y + q1.z * k1.z + q1.w * k1.w
            + q2.x * k2.x + q2.y * k2.y + q2.z * k2.z + q2.w * k2.w
            + q3.x * k3.x + q3.y * k3.y + q3.z * k3.z + q3.w * k3.w;
    bool mk = (mrow[cc] >> lane) & 1ull;
    s[cc] = mk ? -1e8f : d * 0.25f;
  }
  float m = s[0];
#pragma unroll
  for (int cc = 1; cc < 16; cc++) m = fmaxf(m, s[cc]);
  m = wredmax(m);
  float sum = 0.f;
#pragma unroll
  for (int cc = 0; cc < 16; cc++) { s[cc] = __expf(s[cc] - m); sum += s[cc]; }
  sum = wredsum(sum);
  float inv = 1.0f / sum;
  float acc[16];
#pragma unroll
  for (int e = 0; e < 16; e++) acc[e] = 0.f;
#pragma unroll
  for (int cc = 0; cc < 16; cc++) {
    int k = cc * 64 + lane;
    const float4* vp = (const float4*)(Vb + (size_t)k * kDK);
    float4 v0 = vp[0], v1 = vp[1], v2 = vp[2], v3 = vp[3];
    float p = s[cc] * inv;
    acc[0] = fmaf(p, v0.x, acc[0]);  acc[1] = fmaf(p, v0.y, acc[1]);
    acc[2] = fmaf(p, v0.z, acc[2]);  acc[3] = fmaf(p, v0.w, acc[3]);
    acc[4] = fmaf(p, v1.x, acc[4]);  acc[5] = fmaf(p, v1.y, acc[5]);
    acc[6] = fmaf(p, v1.z, acc[6]);  acc[7] = fmaf(p, v1.w, acc[7]);
    acc[8] = fmaf(p, v2.x, acc[8]);  acc[9] = fmaf(p, v2.y, acc[9]);
    acc[10] = fmaf(p, v2.z, acc[10]); acc[11] = fmaf(p, v2.w, acc[11]);
    acc[12] = fmaf(p, v3.x, acc[12]); acc[13] = fmaf(p, v3.y, acc[13]);
    acc[14] = fmaf(p, v3.z, acc[14]); acc[15] = fmaf(p, v3.w, acc[15]);
  }
#pragma unroll
  for (int e = 0; e < 16; e++) acc[e] = wredsum(acc[e]);
  if (lane == 0) {
    float4* op = (float4*)(Hd + ((size_t)(b * nq + q)) * kD + h * kDK);
    op[0] = make_float4(acc[0], acc[1], acc[2], acc[3]);
    op[1] = make_float4(acc[4], acc[5], acc[6], acc[7]);
    op[2] = make_float4(acc[8], acc[9], acc[10], acc[11]);
    op[3] = make_float4(acc[12], acc[13], acc[14], acc[15]);
  }
}

// ---- decoder small kernels ----

__global__ __launch_bounds__(256) void gather_kernel(
    const float* __restrict__ enh, const int* __restrict__ tgt_idx,
    const int* __restrict__ cur_idx, const int* __restrict__ cen_idx,
    float* __restrict__ tgt_f, float* __restrict__ cur_f_out,
    float* __restrict__ cen_f_ws, float* __restrict__ cen_f_out) {
  int b = blockIdx.x;
  int t = threadIdx.x;
  int ti = tgt_idx[b];
  int cui = cur_idx[b];
  if (t < kD) {
    tgt_f[b * kD + t] = enh[((size_t)b * kN + ti) * kD + t];
    cur_f_out[b * kD + t] = enh[((size_t)b * kN + cui) * kD + t];
  }
  for (int i = t; i < kNC * kD; i += 256) {
    int c = i >> 7, e = i & 127;
    float v = enh[((size_t)b * kN + cen_idx[b * kNC + c]) * kD + e];
    cen_f_ws[((size_t)b * kNC + c) * kD + e] = v;
    cen_f_out[((size_t)b * kNC + c) * kD + e] = v;
  }
}

__global__ __launch_bounds__(256) void concat_kernel(
    const float* __restrict__ a, const float* __restrict__ b,
    float* __restrict__ out) {
  int i = blockIdx.x * 256 + threadIdx.x;  // B*256 elems
  int r = i >> 8, c = i & 255;
  out[i] = (c < kD) ? a[r * kD + c] : b[r * kD + c - kD];
}

__global__ __launch_bounds__(64) void ptr_tail(
    const float* __restrict__ Qp, const float* __restrict__ Kp,
    const int* __restrict__ center_mask, const int* __restrict__ center_index,
    const float* __restrict__ cen_f, float* __restrict__ logp_out,
    float* __restrict__ sel_idx_out, float* __restrict__ sel_feat_out) {
  int b = blockIdx.x;
  int lane = threadIdx.x;  // 64 threads = 1 wave, one per center
  const float4* qr = (const float4*)(Qp + b * kD);
  const float4* kr = (const float4*)(Kp + ((size_t)b * kNC + lane) * kD);
  float u = 0.f;
#pragma unroll
  for (int e = 0; e < kD / 4; e++) {
    float4 qv = qr[e], kv = kr[e];
    u += qv.x * kv.x + qv.y * kv.y + qv.z * kv.z + qv.w * kv.w;
  }
  u *= 0.08838834764831845f;  // 1/sqrt(128)
  u = 10.0f * tanhf(u);
  if (center_mask[b * kNC + lane] == 1) u = -1e8f;
  float m = wredmax(u);
  float ex = __expf(u - m);
  float sum = wredsum(ex);
  float logp = u - m - logf(sum);
  logp_out[b * kNC + lane] = logp;
  // argmax with first-index tie-break
  float bm = u; int bi = lane;
#pragma unroll
  for (int o = 32; o; o >>= 1) {
    float om = __shfl_xor(bm, o);
    int oi = __shfl_xor(bi, o);
    if (om > bm || (om == bm && oi < bi)) { bm = om; bi = oi; }
  }
  if (lane == 0) sel_idx_out[b] = (float)center_index[b * kNC + bi];
  const float* cf = cen_f + ((size_t)b * kNC + bi) * kD;
  sel_feat_out[b * kD + lane] = cf[lane];
  sel_feat_out[b * kD + 64 + lane] = cf[64 + lane];
}

// ---- host ----

extern "C" void kernel_launch(void* const* d_in, const int* in_sizes, int n_in,
                              void* d_out, int out_size, void* d_ws,
                              size_t ws_size, hipStream_t stream) {
  (void)in_sizes; (void)n_in; (void)out_size; (void)ws_size;
  const float* node_inputs = (const float*)d_in[0];
  const int* pad_mask = (const int*)d_in[1];
  const int* edge_mask = (const int*)d_in[2];
  const int* center_mask = (const int*)d_in[3];
  const int* center_index = (const int*)d_in[4];
  const int* target_index = (const int*)d_in[5];
  const int* current_index = (const int*)d_in[6];
  const float* init_W = (const float*)d_in[8];
  const float* init_b = (const float*)d_in[9];
  const float* enc_wq = (const float*)d_in[10];
  const float* enc_wk = (const float*)d_in[11];
  const float* enc_wv = (const float*)d_in[12];
  const float* enc_wo = (const float*)d_in[13];
  const float* enc_ln1_g = (const float*)d_in[14];
  const float* enc_ln1_b = (const float*)d_in[15];
  const float* enc_w1 = (const float*)d_in[16];
  const float* enc_b1 = (const float*)d_in[17];
  const float* enc_w2 = (const float*)d_in[18];
  const float* enc_b2 = (const float*)d_in[19];
  const float* enc_ln2_g = (const float*)d_in[20];
  const float* enc_ln2_b = (const float*)d_in[21];
  const float* dec_wq = (const float*)d_in[22];
  const float* dec_wk = (const float*)d_in[23];
  const float* dec_wv = (const float*)d_in[24];
  const float* dec_wo = (const float*)d_in[25];
  const float* dec_ln1_g = (const float*)d_in[26];
  const float* dec_ln1_b = (const float*)d_in[27];
  const float* dec_w1 = (const float*)d_in[28];
  const float* dec_b1 = (const float*)d_in[29];
  const float* dec_w2 = (const float*)d_in[30];
  const float* dec_b2 = (const float*)d_in[31];
  const float* dec_ln2_g = (const float*)d_in[32];
  const float* dec_ln2_b = (const float*)d_in[33];
  const float* tgt_W = (const float*)d_in[34];
  const float* tgt_b = (const float*)d_in[35];
  const float* ptr_wq = (const float*)d_in[36];
  const float* ptr_wk = (const float*)d_in[37];

  // output layout (floats, concatenated)
  float* out_enh = (float*)d_out;                 // B*N*D
  float* out_curf = out_enh + kB * kN * kD;       // B*D
  float* out_selidx = out_curf + kB * kD;         // B
  float* out_selfeat = out_selidx + kB;           // B*D
  float* out_logp = out_selfeat + kB * kD;        // B*NC
  float* out_cenf = out_logp + kB * kNC;          // B*NC*D

  // workspace layout
  char* wsp = (char*)d_ws;
  size_t off = 0;
  auto alloc = [&](size_t n) {
    char* p = wsp + off;
    off = (off + n + 255) & ~(size_t)255;
    return p;
  };
  float* x   = (float*)alloc(kR * kD * 4);
  float* h   = (float*)alloc(kR * kD * 4);   // also f / mem_n
  float* h2  = (float*)alloc(kR * kD * 4);
  float* Qb  = (float*)alloc(kR * kD * 4);
  float* Kb  = (float*)alloc(kR * kD * 4);
  float* Vb  = (float*)alloc(kR * kD * 4);
  float* Hd  = (float*)alloc(kR * kD * 4);
  float* tb  = (float*)alloc(kR * kFF * 4);
  unsigned long long* maskbits = (unsigned long long*)alloc(kR * 16 * 8);
  unsigned long long* padbits  = (unsigned long long*)alloc(kB * 16 * 8);
  float* ewq = (float*)alloc(kEnc * kD * kD * 4);
  float* ewk = (float*)alloc(kEnc * kD * kD * 4);
  float* ewv = (float*)alloc(kEnc * kD * kD * 4);
  float* dwq = (float*)alloc(kD * kD * 4);
  float* dwk = (float*)alloc(kD * kD * 4);
  float* dwv = (float*)alloc(kD * kD * 4);
  float* tgt_f = (float*)alloc(kB * kD * 4);
  float* tgt_n = (float*)alloc(kB * kD * 4);
  float* Qd    = (float*)alloc(kB * kD * 4);
  float* Hdd   = (float*)alloc(kB * kD * 4);
  float* dech  = (float*)alloc(kB * kD * 4);
  float* decf  = (float*)alloc(kB * kD * 4);
  float* dect  = (float*)alloc(kB * kFF * 4);
  float* enh_tgt = (float*)alloc(kB * kD * 4);
  float* catb  = (float*)alloc(kB * 2 * kD * 4);
  float* emb   = (float*)alloc(kB * kD * 4);
  float* Qp    = (float*)alloc(kB * kD * 4);
  float* Kp    = (float*)alloc(kB * kNC * kD * 4);
  float* cen_f = (float*)alloc(kB * kNC * kD * 4);

  // prologue
  repack_qkv<<<(kEnc * kD * kD + 255) / 256, 256, 0, stream>>>(
      enc_wq, enc_wk, enc_wv, ewq, ewk, ewv, kEnc);
  repack_qkv<<<(kD * kD + 255) / 256, 256, 0, stream>>>(
      dec_wq, dec_wk, dec_wv, dwq, dwk, dwv, 1);
  pack_mask<<<kB * kN, 256, 0, stream>>>(edge_mask, pad_mask, maskbits);
  pack_pad<<<kB, 256, 0, stream>>>(pad_mask, padbits);
  init_proj<<<kR * kD / 256, 256, 0, stream>>>(node_inputs, init_W, init_b, x);

  // encoder layers
  for (int l = 0; l < kEnc; l++) {
    const float* wq_l = ewq + (size_t)l * kD * kD;
    const float* wk_l = ewk + (size_t)l * kD * kD;
    const float* wv_l = ewv + (size_t)l * kD * kD;
    const float* wo_l = enc_wo + (size_t)l * kH * kDK * kD;
    ln_kernel<<<kR / 4, 256, 0, stream>>>(x, enc_ln1_g + l * kD,
                                          enc_ln1_b + l * kD, h, kR);
    dim3 g1(kR / 16, 1);
    gemm_f32<<<g1, 256, 0, stream>>>(h, wq_l, nullptr, nullptr, Qb, kR, kD, kD, 0, 1);
    gemm_f32<<<g1, 256, 0, stream>>>(h, wk_l, nullptr, nullptr, Kb, kR, kD, kD, 0, 1);
    gemm_f32<<<g1, 256, 0, stream>>>(h, wv_l, nullptr, nullptr, Vb, kR, kD, kD, 0, 1);
    attn_kernel<<<kB * kH * kN * 64 / 256, 256, 0, stream>>>(Qb, Kb, Vb,
                                                             maskbits, Hd, kN);
    gemm_f32<<<g1, 256, 0, stream>>>(Hd, wo_l, nullptr, x, h2, kR, kD, kD, 0, 0);
    ln_kernel<<<kR / 4, 256, 0, stream>>>(h2, enc_ln2_g + l * kD,
                                          enc_ln2_b + l * kD, h, kR);
    gemm_f32<<<dim3(kR / 16, kFF / 128), 256, 0, stream>>>(
        h, enc_w1 + (size_t)l * kD * kFF, enc_b1 + l * kFF, nullptr, tb,
        kR, kD, kFF, 1, 0);
    float* xout = (l == kEnc - 1) ? out_enh : x;
    gemm_f32<<<g1, 256, 0, stream>>>(tb, enc_w2 + (size_t)l * kFF * kD,
                                     enc_b2 + l * kD, h2, xout, kR, kFF, kD, 0, 0);
  }

  // decoder
  ln_kernel<<<kR / 4, 256, 0, stream>>>(out_enh, dec_ln1_g, dec_ln1_b, h, kR);
  gather_kernel<<<kB, 256, 0, stream>>>(out_enh, target_index, current_index,
                                        center_index, tgt_f, out_curf, cen_f,
                                        out_cenf);
  ln_kernel<<<1, 256, 0, stream>>>(tgt_f, dec_ln1_g, dec_ln1_b, tgt_n, kB);
  gemm_f32<<<dim3(1, 1), 256, 0, stream>>>(tgt_n, dwq, nullptr, nullptr, Qd,
                                           kB, kD, kD, 0, 0);
  gemm_f32<<<dim3(kR / 16, 1), 256, 0, stream>>>(h, dwk, nullptr, nullptr, Kb,
                                                 kR, kD, kD, 0, 1);
  gemm_f32<<<dim3(kR / 16, 1), 256, 0, stream>>>(h, dwv, nullptr, nullptr, Vb,
                                                 kR, kD, kD, 0, 1);
  attn_kernel<<<kB * kH * 64 / 256, 256, 0, stream>>>(Qd, Kb, Vb, padbits, Hdd, 1);
  gemm_f32<<<dim3(1, 1), 256, 0, stream>>>(Hdd, dec_wo, nullptr, tgt_f, dech,
                                           kB, kD, kD, 0, 0);
  ln_kernel<<<1, 256, 0, stream>>>(dech, dec_ln2_g, dec_ln2_b, decf, kB);
  gemm_f32<<<dim3(1, kFF / 128), 256, 0, stream>>>(decf, dec_w1, dec_b1,
                                                   nullptr, dect, kB, kD, kFF, 1, 0);
  gemm_f32<<<dim3(1, 1), 256, 0, stream>>>(dect, dec_w2, dec_b2, dech, enh_tgt,
                                           kB, kFF, kD, 0, 0);
  concat_kernel<<<kB, 256, 0, stream>>>(enh_tgt, tgt_f, catb);
  gemm_f32<<<dim3(1, 1), 256, 0, stream>>>(catb, tgt_W, tgt_b, nullptr, emb,
                                           kB, 2 * kD, kD, 0, 0);
  gemm_f32<<<dim3(1, 1), 256, 0, stream>>>(emb, ptr_wq, nullptr, nullptr, Qp,
                                           kB, kD, kD, 0, 0);
  gemm_f32<<<dim3(kB * kNC / 16, 1), 256, 0, stream>>>(cen_f, ptr_wk, nullptr,
                                                       nullptr, Kp, kB * kNC,
                                                       kD, kD, 0, 0);
  ptr_tail<<<kB, 64, 0, stream>>>(Qp, Kp, center_mask, center_index, cen_f,
                                  out_logp, out_selidx, out_selfeat);
}

// Round 3
// 2067.359 us; speedup vs baseline: 1.9267x; 1.9267x over previous
//
#include <hip/hip_runtime.h>

constexpr int kB = 4, kN = 1024, kIn = 8, kD = 128, kH = 8, kNC = 64,
              kDK = 16, kFF = 512, kEnc = 6, kR = kB * kN;

__device__ __forceinline__ float wredsum(float v) {
  v += __shfl_xor(v, 1);  v += __shfl_xor(v, 2);  v += __shfl_xor(v, 4);
  v += __shfl_xor(v, 8);  v += __shfl_xor(v, 16); v += __shfl_xor(v, 32);
  return v;
}
__device__ __forceinline__ float wredmax(float v) {
  v = fmaxf(v, __shfl_xor(v, 1));  v = fmaxf(v, __shfl_xor(v, 2));
  v = fmaxf(v, __shfl_xor(v, 4));  v = fmaxf(v, __shfl_xor(v, 8));
  v = fmaxf(v, __shfl_xor(v, 16)); v = fmaxf(v, __shfl_xor(v, 32));
  return v;
}

// ---- prologue kernels ----

// repack (l,h,d,e) -> [l][3][128][128] row-major (d -> col h*16+e)
__global__ __launch_bounds__(256) void repack_qkv(
    const float* __restrict__ wq, const float* __restrict__ wk,
    const float* __restrict__ wv, float* __restrict__ out, int layers) {
  int i = blockIdx.x * 256 + threadIdx.x;
  if (i >= layers * kD * kD) return;
  int l = i / (kD * kD);
  int rem = i - l * kD * kD;
  int d = rem >> 7;
  int c = rem & 127;
  int src = ((l * kH + (c >> 4)) * kD + d) * kDK + (c & 15);
  out[(size_t)(l * 3 + 0) * 16384 + rem] = wq[src];
  out[(size_t)(l * 3 + 1) * 16384 + rem] = wk[src];
  out[(size_t)(l * 3 + 2) * 16384 + rem] = wv[src];
}

// transposed bit mask: bits_t[(b*16 + tile)*N + q], bit k-in-tile
__global__ __launch_bounds__(256) void pack_mask(
    const int* __restrict__ edge_mask, const int* __restrict__ pad_mask,
    unsigned long long* __restrict__ bits_t) {
  int row = blockIdx.x;  // b*N + q
  int b = row / kN;
  int q = row % kN;
  int lane = threadIdx.x & 63;
  int wv = threadIdx.x >> 6;
  for (int c0 = wv; c0 < 16; c0 += 4) {
    int k = c0 * 64 + lane;
    int m = edge_mask[(size_t)row * kN + k] + pad_mask[b * kN + k];
    unsigned long long bal = __ballot(m > 0);
    if (lane == 0) bits_t[((size_t)b * 16 + c0) * kN + q] = bal;
  }
}

__global__ __launch_bounds__(256) void pack_pad(
    const int* __restrict__ pad_mask, unsigned long long* __restrict__ bits) {
  int b = blockIdx.x;
  int lane = threadIdx.x & 63;
  int wv = threadIdx.x >> 6;
  for (int c0 = wv; c0 < 16; c0 += 4) {
    int k = c0 * 64 + lane;
    unsigned long long bal = __ballot(pad_mask[b * kN + k] > 0);
    if (lane == 0) bits[b * 16 + c0] = bal;
  }
}

__global__ __launch_bounds__(256) void init_proj(
    const float* __restrict__ ni, const float* __restrict__ W,
    const float* __restrict__ bias, float* __restrict__ x) {
  int i = blockIdx.x * 256 + threadIdx.x;  // r*128 + c
  int r = i >> 7, c = i & 127;
  float acc = bias[c];
#pragma unroll
  for (int k = 0; k < kIn; k++) acc = fmaf(ni[r * kIn + k], W[k * kD + c], acc);
  x[i] = acc;
}

// ---- layernorm (decoder small uses): one wave per row ----
__global__ __launch_bounds__(256) void ln_kernel(
    const float* __restrict__ x, const float* __restrict__ g,
    const float* __restrict__ b, float* __restrict__ out, int rows) {
  int wid = (blockIdx.x * 256 + threadIdx.x) >> 6;
  if (wid >= rows) return;
  int lane = threadIdx.x & 63;
  float2 v = *(const float2*)(x + (size_t)wid * kD + lane * 2);
  float mean = wredsum(v.x + v.y) * (1.0f / kD);
  float dx = v.x - mean, dy = v.y - mean;
  float var = wredsum(dx * dx + dy * dy) * (1.0f / kD);
  float rstd = rsqrtf(var + 1e-5f);
  int c = lane * 2;
  float2 o;
  o.x = dx * rstd * g[c] + b[c];
  o.y = dy * rstd * g[c + 1] + b[c + 1];
  *(float2*)(out + (size_t)wid * kD + c) = o;
}

// ---- fused LN + QKV projection ----
// block: 16 rows; out Q/K/V in (b,h,n,e) layout
__global__ __launch_bounds__(256) void fused_ln_qkv(
    const float* __restrict__ x, const float* __restrict__ g,
    const float* __restrict__ beta, const float* __restrict__ Wqkv,
    float* __restrict__ Qo, float* __restrict__ Ko, float* __restrict__ Vo) {
  __shared__ float As[16][128];
  int r0 = blockIdx.x * 16;
  int w = threadIdx.x >> 6, lane = threadIdx.x & 63;
#pragma unroll
  for (int i = 0; i < 4; i++) {
    int rr = w * 4 + i;
    const float* xr = x + (size_t)(r0 + rr) * kD;
    float2 v = *(const float2*)(xr + lane * 2);
    float mean = wredsum(v.x + v.y) * (1.0f / kD);
    float dx = v.x - mean, dy = v.y - mean;
    float var = wredsum(dx * dx + dy * dy) * (1.0f / kD);
    float rstd = rsqrtf(var + 1e-5f);
    int c = lane * 2;
    As[rr][c] = dx * rstd * g[c] + beta[c];
    As[rr][c + 1] = dy * rstd * g[c + 1] + beta[c + 1];
  }
  __syncthreads();
  int c = threadIdx.x & 127, rsel = threadIdx.x >> 7;
  float accq[8] = {}, acck[8] = {}, accv[8] = {};
  const float* Wq = Wqkv;
  const float* Wk = Wqkv + 16384;
  const float* Wv = Wqkv + 32768;
#pragma unroll 4
  for (int k = 0; k < 128; k++) {
    float wq = Wq[k * 128 + c], wk = Wk[k * 128 + c], wv = Wv[k * 128 + c];
#pragma unroll
    for (int j = 0; j < 8; j++) {
      float a = As[rsel + 2 * j][k];
      accq[j] = fmaf(a, wq, accq[j]);
      acck[j] = fmaf(a, wk, acck[j]);
      accv[j] = fmaf(a, wv, accv[j]);
    }
  }
  int hh = c >> 4, e = c & 15;
#pragma unroll
  for (int j = 0; j < 8; j++) {
    int r = r0 + rsel + 2 * j;
    int b = r >> 10, n = r & 1023;
    size_t oi = (((size_t)(b * kH + hh)) * kN + n) * kDK + e;
    Qo[oi] = accq[j]; Ko[oi] = acck[j]; Vo[oi] = accv[j];
  }
}

// ---- fused LN + FFN1 (relu) ----
__global__ __launch_bounds__(256) void fused_ln_ffn1(
    const float* __restrict__ x, const float* __restrict__ g,
    const float* __restrict__ beta, const float* __restrict__ W1,
    const float* __restrict__ b1, float* __restrict__ tb) {
  __shared__ float As[16][128];
  int r0 = blockIdx.x * 16;
  int w = threadIdx.x >> 6, lane = threadIdx.x & 63;
#pragma unroll
  for (int i = 0; i < 4; i++) {
    int rr = w * 4 + i;
    const float* xr = x + (size_t)(r0 + rr) * kD;
    float2 v = *(const float2*)(xr + lane * 2);
    float mean = wredsum(v.x + v.y) * (1.0f / kD);
    float dx = v.x - mean, dy = v.y - mean;
    float var = wredsum(dx * dx + dy * dy) * (1.0f / kD);
    float rstd = rsqrtf(var + 1e-5f);
    int c = lane * 2;
    As[rr][c] = dx * rstd * g[c] + beta[c];
    As[rr][c + 1] = dy * rstd * g[c + 1] + beta[c + 1];
  }
  __syncthreads();
  int cg = threadIdx.x & 127, rsel = threadIdx.x >> 7;
  float acc[8][4] = {};
#pragma unroll 2
  for (int k = 0; k < 128; k++) {
    float4 wv4 = *(const float4*)(W1 + (size_t)k * kFF + cg * 4);
#pragma unroll
    for (int j = 0; j < 8; j++) {
      float a = As[rsel + 2 * j][k];
      acc[j][0] = fmaf(a, wv4.x, acc[j][0]);
      acc[j][1] = fmaf(a, wv4.y, acc[j][1]);
      acc[j][2] = fmaf(a, wv4.z, acc[j][2]);
      acc[j][3] = fmaf(a, wv4.w, acc[j][3]);
    }
  }
  float4 bv = *(const float4*)(b1 + cg * 4);
#pragma unroll
  for (int j = 0; j < 8; j++) {
    int r = r0 + rsel + 2 * j;
    float4 o;
    o.x = fmaxf(acc[j][0] + bv.x, 0.f);
    o.y = fmaxf(acc[j][1] + bv.y, 0.f);
    o.z = fmaxf(acc[j][2] + bv.z, 0.f);
    o.w = fmaxf(acc[j][3] + bv.w, 0.f);
    *(float4*)(tb + (size_t)r * kFF + cg * 4) = o;
  }
}

// ---- generic fp32 GEMM (kept for WO, FFN2, decoder) ----
__global__ __launch_bounds__(256) void gemm_f32(
    const float* __restrict__ A, const float* __restrict__ W,
    const float* __restrict__ bias, const float* __restrict__ resid,
    float* __restrict__ out, int Rr, int K, int C, int relu, int out_bhne) {
  __shared__ float As[16][128];
  int tc = threadIdx.x & 127;
  int rsel = threadIdx.x >> 7;
  int c = blockIdx.y * 128 + tc;
  int r0 = blockIdx.x * 16;
  float acc[8];
#pragma unroll
  for (int j = 0; j < 8; j++) acc[j] = 0.f;
  for (int k0 = 0; k0 < K; k0 += 128) {
#pragma unroll
    for (int t = threadIdx.x; t < 2048; t += 256) {
      int rr = t >> 7, kk = t & 127;
      As[rr][kk] = (r0 + rr < Rr) ? A[(size_t)(r0 + rr) * K + k0 + kk] : 0.f;
    }
    __syncthreads();
#pragma unroll 4
    for (int k = 0; k < 128; k++) {
      float w = W[(size_t)(k0 + k) * C + c];
#pragma unroll
      for (int j = 0; j < 8; j++) acc[j] = fmaf(As[rsel + j * 2][k], w, acc[j]);
    }
    __syncthreads();
  }
  float bv = bias ? bias[c] : 0.f;
#pragma unroll
  for (int j = 0; j < 8; j++) {
    int r = r0 + rsel + j * 2;
    if (r < Rr) {
      float v = acc[j] + bv;
      if (resid) v += resid[(size_t)r * C + c];
      if (relu) v = fmaxf(v, 0.f);
      size_t oi;
      if (out_bhne) {
        int bb = r / kN, n = r % kN;
        int hh = c >> 4, e = c & 15;
        oi = (((size_t)(bb * kH + hh)) * kN + n) * kDK + e;
      } else {
        oi = (size_t)r * C + c;
      }
      out[oi] = v;
    }
  }
}

// ---- flash attention: block = 64 q x 4 k-split waves ----
// grid (bh=32, qt=16); Q/K/V in (b,h,n,e); out Hd in (b,n,d)
__global__ __launch_bounds__(256) void attn_flash(
    const float* __restrict__ Q, const float* __restrict__ K,
    const float* __restrict__ V, const unsigned long long* __restrict__ bits_t,
    float* __restrict__ Hd) {
  __shared__ float Ks[4][64][16];
  __shared__ float Vs[4][64][16];
  __shared__ float Ms[4][64][20];  // 0..15 acc, 16 mx, 17 l (stride 20 = 16B-aligned)
  int bh = blockIdx.x, qt = blockIdx.y;
  int b = bh >> 3, h = bh & 7;
  int w = threadIdx.x >> 6, lane = threadIdx.x & 63;
  int q = qt * 64 + lane;
  const float4* qp = (const float4*)(Q + ((size_t)bh * kN + q) * kDK);
  float4 q0 = qp[0], q1 = qp[1], q2 = qp[2], q3 = qp[3];
  const float* Kb = K + (size_t)bh * kN * kDK;
  const float* Vb = V + (size_t)bh * kN * kDK;
  float mx = -3.0e38f, l = 0.f;
  float acc[16];
#pragma unroll
  for (int e = 0; e < 16; e++) acc[e] = 0.f;
  for (int t = 0; t < 4; t++) {
    int kk = w * 256 + t * 64 + lane;  // key this lane stages
    const float4* kp = (const float4*)(Kb + (size_t)kk * kDK);
    float4 ka = kp[0], kbv = kp[1], kc = kp[2], kd = kp[3];
    const float4* vp = (const float4*)(Vb + (size_t)kk * kDK);
    float4 va = vp[0], vb = vp[1], vc = vp[2], vd = vp[3];
    unsigned long long mb = bits_t[((size_t)b * 16 + w * 4 + t) * kN + q];
    ((float4*)Ks[w][lane])[0] = ka; ((float4*)Ks[w][lane])[1] = kbv;
    ((float4*)Ks[w][lane])[2] = kc; ((float4*)Ks[w][lane])[3] = kd;
    ((float4*)Vs[w][lane])[0] = va; ((float4*)Vs[w][lane])[1] = vb;
    ((float4*)Vs[w][lane])[2] = vc; ((float4*)Vs[w][lane])[3] = vd;
#pragma unroll 4
    for (int k2 = 0; k2 < 64; k2++) {
      const float4* kr = (const float4*)Ks[w][k2];
      float4 k0 = kr[0], k1 = kr[1], k2v = kr[2], k3 = kr[3];
      float s = q0.x * k0.x + q0.y * k0.y + q0.z * k0.z + q0.w * k0.w
              + q1.x * k1.x + q1.y * k1.y + q1.z * k1.z + q1.w * k1.w
              + q2.x * k2v.x + q2.y * k2v.y + q2.z * k2v.z + q2.w * k2v.w
              + q3.x * k3.x + q3.y * k3.y + q3.z * k3.z + q3.w * k3.w;
      s *= 0.25f;
      if ((mb >> k2) & 1ull) s = -1e8f;
      float d = s - mx;
      if (d > 8.f) {  // defer-rescale (rare)
        float sc = __expf(-d);
        l *= sc;
#pragma unroll
        for (int e = 0; e < 16; e++) acc[e] *= sc;
        mx = s; d = 0.f;
      }
      float p = __expf(d);
      l += p;
      const float4* vr = (const float4*)Vs[w][k2];
      float4 v0 = vr[0], v1 = vr[1], v2 = vr[2], v3 = vr[3];
      acc[0] = fmaf(p, v0.x, acc[0]);   acc[1] = fmaf(p, v0.y, acc[1]);
      acc[2] = fmaf(p, v0.z, acc[2]);   acc[3] = fmaf(p, v0.w, acc[3]);
      acc[4] = fmaf(p, v1.x, acc[4]);   acc[5] = fmaf(p, v1.y, acc[5]);
      acc[6] = fmaf(p, v1.z, acc[6]);   acc[7] = fmaf(p, v1.w, acc[7]);
      acc[8] = fmaf(p, v2.x, acc[8]);   acc[9] = fmaf(p, v2.y, acc[9]);
      acc[10] = fmaf(p, v2.z, acc[10]); acc[11] = fmaf(p, v2.w, acc[11]);
      acc[12] = fmaf(p, v3.x, acc[12]); acc[13] = fmaf(p, v3.y, acc[13]);
      acc[14] = fmaf(p, v3.z, acc[14]); acc[15] = fmaf(p, v3.w, acc[15]);
    }
  }
  // write partials
  ((float4*)Ms[w][lane])[0] = make_float4(acc[0], acc[1], acc[2], acc[3]);
  ((float4*)Ms[w][lane])[1] = make_float4(acc[4], acc[5], acc[6], acc[7]);
  ((float4*)Ms[w][lane])[2] = make_float4(acc[8], acc[9], acc[10], acc[11]);
  ((float4*)Ms[w][lane])[3] = make_float4(acc[12], acc[13], acc[14], acc[15]);
  Ms[w][lane][16] = mx;
  Ms[w][lane][17] = l;
  __syncthreads();
  // wave w combines elements [w*4, w*4+4) for q = lane
  float m0 = Ms[0][lane][16], m1 = Ms[1][lane][16];
  float m2 = Ms[2][lane][16], m3 = Ms[3][lane][16];
  float mstar = fmaxf(fmaxf(m0, m1), fmaxf(m2, m3));
  float f0 = __expf(m0 - mstar), f1 = __expf(m1 - mstar);
  float f2 = __expf(m2 - mstar), f3 = __expf(m3 - mstar);
  float L = f0 * Ms[0][lane][17] + f1 * Ms[1][lane][17] +
            f2 * Ms[2][lane][17] + f3 * Ms[3][lane][17];
  float invL = 1.0f / L;
  float o[4];
#pragma unroll
  for (int e = 0; e < 4; e++) {
    int ei = w * 4 + e;
    o[e] = (f0 * Ms[0][lane][ei] + f1 * Ms[1][lane][ei] +
            f2 * Ms[2][lane][ei] + f3 * Ms[3][lane][ei]) * invL;
  }
  *(float4*)(Hd + ((size_t)(b * kN + q)) * kD + h * kDK + w * 4) =
      make_float4(o[0], o[1], o[2], o[3]);
}

// ---- decoder attention (nq small): one wave per (b,h,q) ----
__global__ __launch_bounds__(256) void attn_kernel(
    const float* __restrict__ Q, const float* __restrict__ K,
    const float* __restrict__ V, const unsigned long long* __restrict__ bits,
    float* __restrict__ Hd, int nq) {
  int wid = (blockIdx.x * 256 + threadIdx.x) >> 6;
  int total = kB * kH * nq;
  if (wid >= total) return;
  int lane = threadIdx.x & 63;
  int q = wid % nq;
  int bh = wid / nq;
  int b = bh / kH, h = bh % kH;
  const float4* qp = (const float4*)(Q + ((size_t)bh * nq + q) * kDK);
  float4 q0 = qp[0], q1 = qp[1], q2 = qp[2], q3 = qp[3];
  const unsigned long long* mrow = bits + ((size_t)b * nq + q) * 16;
  const float* Kb = K + (size_t)bh * kN * kDK;
  const float* Vb = V + (size_t)bh * kN * kDK;
  float s[16];
#pragma unroll
  for (int cc = 0; cc < 16; cc++) {
    int k = cc * 64 + lane;
    const float4* kp = (const float4*)(Kb + (size_t)k * kDK);
    float4 k0 = kp[0], k1 = kp[1], k2 = kp[2], k3 = kp[3];
    float d = q0.x * k0.x + q0.y * k0.y + q0.z * k0.z + q0.w * k0.w
            + q1.x * k1.x + q1.y * k1.y + q1.z * k1.z + q1.w * k1.w
            + q2.x * k2.x + q2.y * k2.y + q2.z * k2.z + q2.w * k2.w
            + q3.x * k3.x + q3.y * k3.y + q3.z * k3.z + q3.w * k3.w;
    bool mk = (mrow[cc] >> lane) & 1ull;
    s[cc] = mk ? -1e8f : d * 0.25f;
  }
  float m = s[0];
#pragma unroll
  for (int cc = 1; cc < 16; cc++) m = fmaxf(m, s[cc]);
  m = wredmax(m);
  float sum = 0.f;
#pragma unroll
  for (int cc = 0; cc < 16; cc++) { s[cc] = __expf(s[cc] - m); sum += s[cc]; }
  sum = wredsum(sum);
  float inv = 1.0f / sum;
  float acc[16];
#pragma unroll
  for (int e = 0; e < 16; e++) acc[e] = 0.f;
#pragma unroll
  for (int cc = 0; cc < 16; cc++) {
    int k = cc * 64 + lane;
    const float4* vp = (const float4*)(Vb + (size_t)k * kDK);
    float4 v0 = vp[0], v1 = vp[1], v2 = vp[2], v3 = vp[3];
    float p = s[cc] * inv;
    acc[0] = fmaf(p, v0.x, acc[0]);  acc[1] = fmaf(p, v0.y, acc[1]);
    acc[2] = fmaf(p, v0.z, acc[2]);  acc[3] = fmaf(p, v0.w, acc[3]);
    acc[4] = fmaf(p, v1.x, acc[4]);  acc[5] = fmaf(p, v1.y, acc[5]);
    acc[6] = fmaf(p, v1.z, acc[6]);  acc[7] = fmaf(p, v1.w, acc[7]);
    acc[8] = fmaf(p, v2.x, acc[8]);  acc[9] = fmaf(p, v2.y, acc[9]);
    acc[10] = fmaf(p, v2.z, acc[10]); acc[11] = fmaf(p, v2.w, acc[11]);
    acc[12] = fmaf(p, v3.x, acc[12]); acc[13] = fmaf(p, v3.y, acc[13]);
    acc[14] = fmaf(p, v3.z, acc[14]); acc[15] = fmaf(p, v3.w, acc[15]);
  }
#pragma unroll
  for (int e = 0; e < 16; e++) acc[e] = wredsum(acc[e]);
  if (lane == 0) {
    float4* op = (float4*)(Hd + ((size_t)(b * nq + q)) * kD + h * kDK);
    op[0] = make_float4(acc[0], acc[1], acc[2], acc[3]);
    op[1] = make_float4(acc[4], acc[5], acc[6], acc[7]);
    op[2] = make_float4(acc[8], acc[9], acc[10], acc[11]);
    op[3] = make_float4(acc[12], acc[13], acc[14], acc[15]);
  }
}

// ---- decoder small kernels ----

__global__ __launch_bounds__(256) void gather_kernel(
    const float* __restrict__ enh, const int* __restrict__ tgt_idx,
    const int* __restrict__ cur_idx, const int* __restrict__ cen_idx,
    float* __restrict__ tgt_f, float* __restrict__ cur_f_out,
    float* __restrict__ cen_f_ws, float* __restrict__ cen_f_out) {
  int b = blockIdx.x;
  int t = threadIdx.x;
  int ti = tgt_idx[b];
  int cui = cur_idx[b];
  if (t < kD) {
    tgt_f[b * kD + t] = enh[((size_t)b * kN + ti) * kD + t];
    cur_f_out[b * kD + t] = enh[((size_t)b * kN + cui) * kD + t];
  }
  for (int i = t; i < kNC * kD; i += 256) {
    int c = i >> 7, e = i & 127;
    float v = enh[((size_t)b * kN + cen_idx[b * kNC + c]) * kD + e];
    cen_f_ws[((size_t)b * kNC + c) * kD + e] = v;
    cen_f_out[((size_t)b * kNC + c) * kD + e] = v;
  }
}

__global__ __launch_bounds__(256) void concat_kernel(
    const float* __restrict__ a, const float* __restrict__ b,
    float* __restrict__ out) {
  int i = blockIdx.x * 256 + threadIdx.x;
  int r = i >> 8, c = i & 255;
  out[i] = (c < kD) ? a[r * kD + c] : b[r * kD + c - kD];
}

__global__ __launch_bounds__(64) void ptr_tail(
    const float* __restrict__ Qp, const float* __restrict__ Kp,
    const int* __restrict__ center_mask, const int* __restrict__ center_index,
    const float* __restrict__ cen_f, float* __restrict__ logp_out,
    float* __restrict__ sel_idx_out, float* __restrict__ sel_feat_out) {
  int b = blockIdx.x;
  int lane = threadIdx.x;
  const float4* qr = (const float4*)(Qp + b * kD);
  const float4* kr = (const float4*)(Kp + ((size_t)b * kNC + lane) * kD);
  float u = 0.f;
#pragma unroll
  for (int e = 0; e < kD / 4; e++) {
    float4 qv = qr[e], kv = kr[e];
    u += qv.x * kv.x + qv.y * kv.y + qv.z * kv.z + qv.w * kv.w;
  }
  u *= 0.08838834764831845f;
  u = 10.0f * tanhf(u);
  if (center_mask[b * kNC + lane] == 1) u = -1e8f;
  float m = wredmax(u);
  float ex = __expf(u - m);
  float sum = wredsum(ex);
  float logp = u - m - logf(sum);
  logp_out[b * kNC + lane] = logp;
  float bm = u; int bi = lane;
#pragma unroll
  for (int o = 32; o; o >>= 1) {
    float om = __shfl_xor(bm, o);
    int oi = __shfl_xor(bi, o);
    if (om > bm || (om == bm && oi < bi)) { bm = om; bi = oi; }
  }
  if (lane == 0) sel_idx_out[b] = (float)center_index[b * kNC + bi];
  const float* cf = cen_f + ((size_t)b * kNC + bi) * kD;
  sel_feat_out[b * kD + lane] = cf[lane];
  sel_feat_out[b * kD + 64 + lane] = cf[64 + lane];
}

// ---- host ----

extern "C" void kernel_launch(void* const* d_in, const int* in_sizes, int n_in,
                              void* d_out, int out_size, void* d_ws,
                              size_t ws_size, hipStream_t stream) {
  (void)in_sizes; (void)n_in; (void)out_size; (void)ws_size;
  const float* node_inputs = (const float*)d_in[0];
  const int* pad_mask = (const int*)d_in[1];
  const int* edge_mask = (const int*)d_in[2];
  const int* center_mask = (const int*)d_in[3];
  const int* center_index = (const int*)d_in[4];
  const int* target_index = (const int*)d_in[5];
  const int* current_index = (const int*)d_in[6];
  const float* init_W = (const float*)d_in[8];
  const float* init_b = (const float*)d_in[9];
  const float* enc_wq = (const float*)d_in[10];
  const float* enc_wk = (const float*)d_in[11];
  const float* enc_wv = (const float*)d_in[12];
  const float* enc_wo = (const float*)d_in[13];
  const float* enc_ln1_g = (const float*)d_in[14];
  const float* enc_ln1_b = (const float*)d_in[15];
  const float* enc_w1 = (const float*)d_in[16];
  const float* enc_b1 = (const float*)d_in[17];
  const float* enc_w2 = (const float*)d_in[18];
  const float* enc_b2 = (const float*)d_in[19];
  const float* enc_ln2_g = (const float*)d_in[20];
  const float* enc_ln2_b = (const float*)d_in[21];
  const float* dec_wq = (const float*)d_in[22];
  const float* dec_wk = (const float*)d_in[23];
  const float* dec_wv = (const float*)d_in[24];
  const float* dec_wo = (const float*)d_in[25];
  const float* dec_ln1_g = (const float*)d_in[26];
  const float* dec_ln1_b = (const float*)d_in[27];
  const float* dec_w1 = (const float*)d_in[28];
  const float* dec_b1 = (const float*)d_in[29];
  const float* dec_w2 = (const float*)d_in[30];
  const float* dec_b2 = (const float*)d_in[31];
  const float* dec_ln2_g = (const float*)d_in[32];
  const float* dec_ln2_b = (const float*)d_in[33];
  const float* tgt_W = (const float*)d_in[34];
  const float* tgt_b = (const float*)d_in[35];
  const float* ptr_wq = (const float*)d_in[36];
  const float* ptr_wk = (const float*)d_in[37];

  float* out_enh = (float*)d_out;
  float* out_curf = out_enh + kB * kN * kD;
  float* out_selidx = out_curf + kB * kD;
  float* out_selfeat = out_selidx + kB;
  float* out_logp = out_selfeat + kB * kD;
  float* out_cenf = out_logp + kB * kNC;

  char* wsp = (char*)d_ws;
  size_t off = 0;
  auto alloc = [&](size_t n) {
    char* p = wsp + off;
    off = (off + n + 255) & ~(size_t)255;
    return p;
  };
  float* x   = (float*)alloc(kR * kD * 4);
  float* h2  = (float*)alloc(kR * kD * 4);
  float* Qb  = (float*)alloc(kR * kD * 4);
  float* Kb  = (float*)alloc(kR * kD * 4);
  float* Vb  = (float*)alloc(kR * kD * 4);
  float* Hd  = (float*)alloc(kR * kD * 4);
  float* tb  = (float*)alloc(kR * kFF * 4);
  unsigned long long* bits_t  = (unsigned long long*)alloc(kR * 16 * 8);
  unsigned long long* padbits = (unsigned long long*)alloc(kB * 16 * 8);
  float* ewqkv = (float*)alloc(kEnc * 3 * kD * kD * 4);
  float* dqkvW = (float*)alloc(3 * kD * kD * 4);
  float* tgt_f = (float*)alloc(kB * kD * 4);
  float* tgt_n = (float*)alloc(kB * kD * 4);
  float* Qd    = (float*)alloc(kB * kD * 4);
  float* Hdd   = (float*)alloc(kB * kD * 4);
  float* dech  = (float*)alloc(kB * kD * 4);
  float* decf  = (float*)alloc(kB * kD * 4);
  float* dect  = (float*)alloc(kB * kFF * 4);
  float* enh_tgt = (float*)alloc(kB * kD * 4);
  float* catb  = (float*)alloc(kB * 2 * kD * 4);
  float* emb   = (float*)alloc(kB * kD * 4);
  float* Qp    = (float*)alloc(kB * kD * 4);
  float* Kp    = (float*)alloc(kB * kNC * kD * 4);
  float* cen_f = (float*)alloc(kB * kNC * kD * 4);

  // prologue
  repack_qkv<<<(kEnc * kD * kD + 255) / 256, 256, 0, stream>>>(
      enc_wq, enc_wk, enc_wv, ewqkv, kEnc);
  repack_qkv<<<(kD * kD + 255) / 256, 256, 0, stream>>>(
      dec_wq, dec_wk, dec_wv, dqkvW, 1);
  pack_mask<<<kB * kN, 256, 0, stream>>>(edge_mask, pad_mask, bits_t);
  pack_pad<<<kB, 256, 0, stream>>>(pad_mask, padbits);
  init_proj<<<kR * kD / 256, 256, 0, stream>>>(node_inputs, init_W, init_b, x);

  // encoder: 5 dispatches/layer
  for (int l = 0; l < kEnc; l++) {
    const float* wo_l = enc_wo + (size_t)l * kH * kDK * kD;
    fused_ln_qkv<<<kR / 16, 256, 0, stream>>>(
        x, enc_ln1_g + l * kD, enc_ln1_b + l * kD,
        ewqkv + (size_t)l * 3 * kD * kD, Qb, Kb, Vb);
    attn_flash<<<dim3(kB * kH, kN / 64), 256, 0, stream>>>(Qb, Kb, Vb, bits_t, Hd);
    gemm_f32<<<dim3(kR / 16, 1), 256, 0, stream>>>(Hd, wo_l, nullptr, x, h2,
                                                   kR, kD, kD, 0, 0);
    fused_ln_ffn1<<<kR / 16, 256, 0, stream>>>(
        h2, enc_ln2_g + l * kD, enc_ln2_b + l * kD,
        enc_w1 + (size_t)l * kD * kFF, enc_b1 + l * kFF, tb);
    float* xout = (l == kEnc - 1) ? out_enh : x;
    gemm_f32<<<dim3(kR / 16, 1), 256, 0, stream>>>(
        tb, enc_w2 + (size_t)l * kFF * kD, enc_b2 + l * kD, h2, xout,
        kR, kFF, kD, 0, 0);
  }

  // decoder
  gather_kernel<<<kB, 256, 0, stream>>>(out_enh, target_index, current_index,
                                        center_index, tgt_f, out_curf, cen_f,
                                        out_cenf);
  // mem K/V: fused LN(dec_ln1) + projections (Q part computed but unused)
  fused_ln_qkv<<<kR / 16, 256, 0, stream>>>(out_enh, dec_ln1_g, dec_ln1_b,
                                            dqkvW, Qb, Kb, Vb);
  ln_kernel<<<1, 256, 0, stream>>>(tgt_f, dec_ln1_g, dec_ln1_b, tgt_n, kB);
  gemm_f32<<<dim3(1, 1), 256, 0, stream>>>(tgt_n, dqkvW, nullptr, nullptr, Qd,
                                           kB, kD, kD, 0, 0);
  attn_kernel<<<kB * kH * 64 / 256, 256, 0, stream>>>(Qd, Kb, Vb, padbits, Hdd, 1);
  gemm_f32<<<dim3(1, 1), 256, 0, stream>>>(Hdd, dec_wo, nullptr, tgt_f, dech,
                                           kB, kD, kD, 0, 0);
  ln_kernel<<<1, 256, 0, stream>>>(dech, dec_ln2_g, dec_ln2_b, decf, kB);
  gemm_f32<<<dim3(1, kFF / 128), 256, 0, stream>>>(decf, dec_w1, dec_b1,
                                                   nullptr, dect, kB, kD, kFF, 1, 0);
  gemm_f32<<<dim3(1, 1), 256, 0, stream>>>(dect, dec_w2, dec_b2, dech, enh_tgt,
                                           kB, kFF, kD, 0, 0);
  concat_kernel<<<kB, 256, 0, stream>>>(enh_tgt, tgt_f, catb);
  gemm_f32<<<dim3(1, 1), 256, 0, stream>>>(catb, tgt_W, tgt_b, nullptr, emb,
                                           kB, 2 * kD, kD, 0, 0);
  gemm_f32<<<dim3(1, 1), 256, 0, stream>>>(emb, ptr_wq, nullptr, nullptr, Qp,
                                           kB, kD, kD, 0, 0);
  gemm_f32<<<dim3(kB * kNC / 16, 1), 256, 0, stream>>>(cen_f, ptr_wk, nullptr,
                                                       nullptr, Kp, kB * kNC,
                                                       kD, kD, 0, 0);
  ptr_tail<<<kB, 64, 0, stream>>>(Qp, Kp, center_mask, center_index, cen_f,
                                  out_logp, out_selidx, out_selfeat);
}

// Round 4
// 1688.592 us; speedup vs baseline: 2.3588x; 1.2243x over previous
//
#include <hip/hip_runtime.h>

constexpr int kB = 4, kN = 1024, kIn = 8, kD = 128, kH = 8, kNC = 64,
              kDK = 16, kFF = 512, kEnc = 6, kR = kB * kN;

__device__ __forceinline__ float wredsum(float v) {
  v += __shfl_xor(v, 1);  v += __shfl_xor(v, 2);  v += __shfl_xor(v, 4);
  v += __shfl_xor(v, 8);  v += __shfl_xor(v, 16); v += __shfl_xor(v, 32);
  return v;
}
__device__ __forceinline__ float wredmax(float v) {
  v = fmaxf(v, __shfl_xor(v, 1));  v = fmaxf(v, __shfl_xor(v, 2));
  v = fmaxf(v, __shfl_xor(v, 4));  v = fmaxf(v, __shfl_xor(v, 8));
  v = fmaxf(v, __shfl_xor(v, 16)); v = fmaxf(v, __shfl_xor(v, 32));
  return v;
}

// ---- prologue kernels ----

// repack (l,h,d,e) -> [l][3][128][128] row-major (d -> col h*16+e)
__global__ __launch_bounds__(256) void repack_qkv(
    const float* __restrict__ wq, const float* __restrict__ wk,
    const float* __restrict__ wv, float* __restrict__ out, int layers) {
  int i = blockIdx.x * 256 + threadIdx.x;
  if (i >= layers * kD * kD) return;
  int l = i / (kD * kD);
  int rem = i - l * kD * kD;
  int d = rem >> 7;
  int c = rem & 127;
  int src = ((l * kH + (c >> 4)) * kD + d) * kDK + (c & 15);
  out[(size_t)(l * 3 + 0) * 16384 + rem] = wq[src];
  out[(size_t)(l * 3 + 1) * 16384 + rem] = wk[src];
  out[(size_t)(l * 3 + 2) * 16384 + rem] = wv[src];
}

// transposed bit mask: bits_t[(b*16 + tile)*N + q], bit k-in-tile
__global__ __launch_bounds__(256) void pack_mask(
    const int* __restrict__ edge_mask, const int* __restrict__ pad_mask,
    unsigned long long* __restrict__ bits_t) {
  int row = blockIdx.x;  // b*N + q
  int b = row / kN;
  int q = row % kN;
  int lane = threadIdx.x & 63;
  int wv = threadIdx.x >> 6;
  for (int c0 = wv; c0 < 16; c0 += 4) {
    int k = c0 * 64 + lane;
    int m = edge_mask[(size_t)row * kN + k] + pad_mask[b * kN + k];
    unsigned long long bal = __ballot(m > 0);
    if (lane == 0) bits_t[((size_t)b * 16 + c0) * kN + q] = bal;
  }
}

__global__ __launch_bounds__(256) void pack_pad(
    const int* __restrict__ pad_mask, unsigned long long* __restrict__ bits) {
  int b = blockIdx.x;
  int lane = threadIdx.x & 63;
  int wv = threadIdx.x >> 6;
  for (int c0 = wv; c0 < 16; c0 += 4) {
    int k = c0 * 64 + lane;
    unsigned long long bal = __ballot(pad_mask[b * kN + k] > 0);
    if (lane == 0) bits[b * 16 + c0] = bal;
  }
}

__global__ __launch_bounds__(256) void init_proj(
    const float* __restrict__ ni, const float* __restrict__ W,
    const float* __restrict__ bias, float* __restrict__ x) {
  int i = blockIdx.x * 256 + threadIdx.x;  // r*128 + c
  int r = i >> 7, c = i & 127;
  float acc = bias[c];
#pragma unroll
  for (int k = 0; k < kIn; k++) acc = fmaf(ni[r * kIn + k], W[k * kD + c], acc);
  x[i] = acc;
}

// ---- layernorm (decoder small uses): one wave per row ----
__global__ __launch_bounds__(256) void ln_kernel(
    const float* __restrict__ x, const float* __restrict__ g,
    const float* __restrict__ b, float* __restrict__ out, int rows) {
  int wid = (blockIdx.x * 256 + threadIdx.x) >> 6;
  if (wid >= rows) return;
  int lane = threadIdx.x & 63;
  float2 v = *(const float2*)(x + (size_t)wid * kD + lane * 2);
  float mean = wredsum(v.x + v.y) * (1.0f / kD);
  float dx = v.x - mean, dy = v.y - mean;
  float var = wredsum(dx * dx + dy * dy) * (1.0f / kD);
  float rstd = rsqrtf(var + 1e-5f);
  int c = lane * 2;
  float2 o;
  o.x = dx * rstd * g[c] + b[c];
  o.y = dy * rstd * g[c + 1] + b[c + 1];
  *(float2*)(out + (size_t)wid * kD + c) = o;
}

// ---- tile16: pipelined fp32 GEMM, A(16 rows) staged once in LDS (opt LN),
// W staged in 32-row LDS chunks, double-buffered via register prefetch.
// MODE 0: out row-major [R][Cfull]; MODE 2: QKV bhne out picked by blockIdx.y.
template <int K, int LN, int RELU, int MODE>
__global__ __launch_bounds__(256) void tile16(
    const float* __restrict__ A, const float* __restrict__ Wg,
    const float* __restrict__ gamma, const float* __restrict__ beta,
    const float* __restrict__ bias, const float* __restrict__ resid,
    float* __restrict__ O0, float* __restrict__ O1, float* __restrict__ O2,
    int Cfull) {
  __shared__ float As[16][K];
  __shared__ float Ws[2][32][128];
  constexpr int NC = K / 32;
  int r0 = blockIdx.x * 16;
  int y = blockIdx.y;
  const float* Wb;
  int wstride;
  if constexpr (MODE == 2) { Wb = Wg + (size_t)y * K * 128; wstride = 128; }
  else { Wb = Wg + (size_t)y * 128; wstride = Cfull; }

  // ---- stage A (with optional fused LN) ----
  if constexpr (LN) {
    static_assert(K == 128, "LN stage requires K==128");
    int w = threadIdx.x >> 6, lane = threadIdx.x & 63;
#pragma unroll
    for (int i = 0; i < 4; i++) {
      int rr = w * 4 + i;
      const float* xr = A + (size_t)(r0 + rr) * K;
      float2 v = *(const float2*)(xr + lane * 2);
      float mean = wredsum(v.x + v.y) * (1.0f / 128.f);
      float dx = v.x - mean, dy = v.y - mean;
      float var = wredsum(dx * dx + dy * dy) * (1.0f / 128.f);
      float rstd = rsqrtf(var + 1e-5f);
      int c = lane * 2;
      As[rr][c] = dx * rstd * gamma[c] + beta[c];
      As[rr][c + 1] = dy * rstd * gamma[c + 1] + beta[c + 1];
    }
  } else {
    constexpr int NF4 = K / 4;
#pragma unroll
    for (int f = threadIdx.x; f < 16 * NF4; f += 256) {
      int row = f / NF4, c4 = f % NF4;
      *(float4*)&As[row][c4 * 4] =
          *(const float4*)(A + (size_t)(r0 + row) * K + c4 * 4);
    }
  }

  int kk = threadIdx.x >> 3;       // 0..31 (W chunk row)
  int f8 = threadIdx.x & 7;        // 0..7
  float4 wreg[4];
  auto loadW = [&](int kc) {
    const float* Wrow = Wb + (size_t)(kc * 32 + kk) * wstride;
#pragma unroll
    for (int j = 0; j < 4; j++) wreg[j] = *(const float4*)(Wrow + (f8 + 8 * j) * 4);
  };
  auto writeW = [&](int buf) {
#pragma unroll
    for (int j = 0; j < 4; j++) *(float4*)&Ws[buf][kk][(f8 + 8 * j) * 4] = wreg[j];
  };

  loadW(0);
  writeW(0);

  int clocal = threadIdx.x & 127, rsel = threadIdx.x >> 7;
  float acc[8] = {};
  for (int kc = 0; kc < NC; kc++) {
    if (kc + 1 < NC) loadW(kc + 1);   // issue next chunk's global loads
    __syncthreads();                  // Ws[kc&1] (and As on first iter) ready
#pragma unroll
    for (int k4 = 0; k4 < 8; k4++) {
      float4 av[8];
#pragma unroll
      for (int j = 0; j < 8; j++)
        av[j] = *(const float4*)&As[rsel + 2 * j][kc * 32 + k4 * 4];
#pragma unroll
      for (int m = 0; m < 4; m++) {
        float w = Ws[kc & 1][k4 * 4 + m][clocal];
#pragma unroll
        for (int j = 0; j < 8; j++)
          acc[j] = fmaf(((const float*)&av[j])[m], w, acc[j]);
      }
    }
    if (kc + 1 < NC) writeW((kc + 1) & 1);  // waits loads, fills other buffer
  }

  // ---- epilogue ----
  int colg = y * 128 + clocal;
  float bv = bias ? bias[colg] : 0.f;
#pragma unroll
  for (int j = 0; j < 8; j++) {
    int r = r0 + rsel + 2 * j;
    float v = acc[j] + bv;
    if (resid) v += resid[(size_t)r * Cfull + colg];
    if (RELU) v = fmaxf(v, 0.f);
    if constexpr (MODE == 2) {
      int hh = clocal >> 4, e = clocal & 15;
      int bb = r >> 10, n = r & 1023;
      float* P = (y == 0) ? O0 : (y == 1) ? O1 : O2;
      P[(((size_t)(bb * kH + hh)) * kN + n) * kDK + e] = v;
    } else {
      O0[(size_t)r * Cfull + colg] = v;
    }
  }
}

// ---- small fp32 GEMM (decoder tiny shapes, Rr<=256) ----
__global__ __launch_bounds__(256) void gemm_f32(
    const float* __restrict__ A, const float* __restrict__ W,
    const float* __restrict__ bias, const float* __restrict__ resid,
    float* __restrict__ out, int Rr, int K, int C, int relu) {
  __shared__ float As[16][128];
  int tc = threadIdx.x & 127;
  int rsel = threadIdx.x >> 7;
  int c = blockIdx.y * 128 + tc;
  int r0 = blockIdx.x * 16;
  float acc[8];
#pragma unroll
  for (int j = 0; j < 8; j++) acc[j] = 0.f;
  for (int k0 = 0; k0 < K; k0 += 128) {
#pragma unroll
    for (int t = threadIdx.x; t < 2048; t += 256) {
      int rr = t >> 7, kkk = t & 127;
      As[rr][kkk] = (r0 + rr < Rr) ? A[(size_t)(r0 + rr) * K + k0 + kkk] : 0.f;
    }
    __syncthreads();
#pragma unroll 4
    for (int k = 0; k < 128; k++) {
      float w = W[(size_t)(k0 + k) * C + c];
#pragma unroll
      for (int j = 0; j < 8; j++) acc[j] = fmaf(As[rsel + j * 2][k], w, acc[j]);
    }
    __syncthreads();
  }
  float bv = bias ? bias[c] : 0.f;
#pragma unroll
  for (int j = 0; j < 8; j++) {
    int r = r0 + rsel + j * 2;
    if (r < Rr) {
      float v = acc[j] + bv;
      if (resid) v += resid[(size_t)r * C + c];
      if (relu) v = fmaxf(v, 0.f);
      out[(size_t)r * C + c] = v;
    }
  }
}

// ---- flash attention: block = 64 q x 4 k-split waves ----
__global__ __launch_bounds__(256) void attn_flash(
    const float* __restrict__ Q, const float* __restrict__ K,
    const float* __restrict__ V, const unsigned long long* __restrict__ bits_t,
    float* __restrict__ Hd) {
  __shared__ float Ks[4][64][16];
  __shared__ float Vs[4][64][16];
  __shared__ float Ms[4][64][20];
  int bh = blockIdx.x, qt = blockIdx.y;
  int b = bh >> 3, h = bh & 7;
  int w = threadIdx.x >> 6, lane = threadIdx.x & 63;
  int q = qt * 64 + lane;
  const float4* qp = (const float4*)(Q + ((size_t)bh * kN + q) * kDK);
  float4 q0 = qp[0], q1 = qp[1], q2 = qp[2], q3 = qp[3];
  const float* Kb = K + (size_t)bh * kN * kDK;
  const float* Vb = V + (size_t)bh * kN * kDK;
  float mx = -3.0e38f, l = 0.f;
  float acc[16];
#pragma unroll
  for (int e = 0; e < 16; e++) acc[e] = 0.f;
  for (int t = 0; t < 4; t++) {
    int kk = w * 256 + t * 64 + lane;
    const float4* kp = (const float4*)(Kb + (size_t)kk * kDK);
    float4 ka = kp[0], kbv = kp[1], kc = kp[2], kd = kp[3];
    const float4* vp = (const float4*)(Vb + (size_t)kk * kDK);
    float4 va = vp[0], vb = vp[1], vc = vp[2], vd = vp[3];
    unsigned long long mb = bits_t[((size_t)b * 16 + w * 4 + t) * kN + q];
    ((float4*)Ks[w][lane])[0] = ka; ((float4*)Ks[w][lane])[1] = kbv;
    ((float4*)Ks[w][lane])[2] = kc; ((float4*)Ks[w][lane])[3] = kd;
    ((float4*)Vs[w][lane])[0] = va; ((float4*)Vs[w][lane])[1] = vb;
    ((float4*)Vs[w][lane])[2] = vc; ((float4*)Vs[w][lane])[3] = vd;
#pragma unroll 4
    for (int k2 = 0; k2 < 64; k2++) {
      const float4* kr = (const float4*)Ks[w][k2];
      float4 k0 = kr[0], k1 = kr[1], k2v = kr[2], k3 = kr[3];
      float s = q0.x * k0.x + q0.y * k0.y + q0.z * k0.z + q0.w * k0.w
              + q1.x * k1.x + q1.y * k1.y + q1.z * k1.z + q1.w * k1.w
              + q2.x * k2v.x + q2.y * k2v.y + q2.z * k2v.z + q2.w * k2v.w
              + q3.x * k3.x + q3.y * k3.y + q3.z * k3.z + q3.w * k3.w;
      s *= 0.25f;
      if ((mb >> k2) & 1ull) s = -1e8f;
      float d = s - mx;
      if (d > 8.f) {
        float sc = __expf(-d);
        l *= sc;
#pragma unroll
        for (int e = 0; e < 16; e++) acc[e] *= sc;
        mx = s; d = 0.f;
      }
      float p = __expf(d);
      l += p;
      const float4* vr = (const float4*)Vs[w][k2];
      float4 v0 = vr[0], v1 = vr[1], v2 = vr[2], v3 = vr[3];
      acc[0] = fmaf(p, v0.x, acc[0]);   acc[1] = fmaf(p, v0.y, acc[1]);
      acc[2] = fmaf(p, v0.z, acc[2]);   acc[3] = fmaf(p, v0.w, acc[3]);
      acc[4] = fmaf(p, v1.x, acc[4]);   acc[5] = fmaf(p, v1.y, acc[5]);
      acc[6] = fmaf(p, v1.z, acc[6]);   acc[7] = fmaf(p, v1.w, acc[7]);
      acc[8] = fmaf(p, v2.x, acc[8]);   acc[9] = fmaf(p, v2.y, acc[9]);
      acc[10] = fmaf(p, v2.z, acc[10]); acc[11] = fmaf(p, v2.w, acc[11]);
      acc[12] = fmaf(p, v3.x, acc[12]); acc[13] = fmaf(p, v3.y, acc[13]);
      acc[14] = fmaf(p, v3.z, acc[14]); acc[15] = fmaf(p, v3.w, acc[15]);
    }
  }
  ((float4*)Ms[w][lane])[0] = make_float4(acc[0], acc[1], acc[2], acc[3]);
  ((float4*)Ms[w][lane])[1] = make_float4(acc[4], acc[5], acc[6], acc[7]);
  ((float4*)Ms[w][lane])[2] = make_float4(acc[8], acc[9], acc[10], acc[11]);
  ((float4*)Ms[w][lane])[3] = make_float4(acc[12], acc[13], acc[14], acc[15]);
  Ms[w][lane][16] = mx;
  Ms[w][lane][17] = l;
  __syncthreads();
  float m0 = Ms[0][lane][16], m1 = Ms[1][lane][16];
  float m2 = Ms[2][lane][16], m3 = Ms[3][lane][16];
  float mstar = fmaxf(fmaxf(m0, m1), fmaxf(m2, m3));
  float f0 = __expf(m0 - mstar), f1 = __expf(m1 - mstar);
  float f2 = __expf(m2 - mstar), f3 = __expf(m3 - mstar);
  float L = f0 * Ms[0][lane][17] + f1 * Ms[1][lane][17] +
            f2 * Ms[2][lane][17] + f3 * Ms[3][lane][17];
  float invL = 1.0f / L;
  float o[4];
#pragma unroll
  for (int e = 0; e < 4; e++) {
    int ei = w * 4 + e;
    o[e] = (f0 * Ms[0][lane][ei] + f1 * Ms[1][lane][ei] +
            f2 * Ms[2][lane][ei] + f3 * Ms[3][lane][ei]) * invL;
  }
  *(float4*)(Hd + ((size_t)(b * kN + q)) * kD + h * kDK + w * 4) =
      make_float4(o[0], o[1], o[2], o[3]);
}

// ---- decoder attention (nq small): one wave per (b,h,q) ----
__global__ __launch_bounds__(256) void attn_kernel(
    const float* __restrict__ Q, const float* __restrict__ K,
    const float* __restrict__ V, const unsigned long long* __restrict__ bits,
    float* __restrict__ Hd, int nq) {
  int wid = (blockIdx.x * 256 + threadIdx.x) >> 6;
  int total = kB * kH * nq;
  if (wid >= total) return;
  int lane = threadIdx.x & 63;
  int q = wid % nq;
  int bh = wid / nq;
  int b = bh / kH, h = bh % kH;
  const float4* qp = (const float4*)(Q + ((size_t)bh * nq + q) * kDK);
  float4 q0 = qp[0], q1 = qp[1], q2 = qp[2], q3 = qp[3];
  const unsigned long long* mrow = bits + ((size_t)b * nq + q) * 16;
  const float* Kb = K + (size_t)bh * kN * kDK;
  const float* Vb = V + (size_t)bh * kN * kDK;
  float s[16];
#pragma unroll
  for (int cc = 0; cc < 16; cc++) {
    int k = cc * 64 + lane;
    const float4* kp = (const float4*)(Kb + (size_t)k * kDK);
    float4 k0 = kp[0], k1 = kp[1], k2 = kp[2], k3 = kp[3];
    float d = q0.x * k0.x + q0.y * k0.y + q0.z * k0.z + q0.w * k0.w
            + q1.x * k1.x + q1.y * k1.y + q1.z * k1.z + q1.w * k1.w
            + q2.x * k2.x + q2.y * k2.y + q2.z * k2.z + q2.w * k2.w
            + q3.x * k3.x + q3.y * k3.y + q3.z * k3.z + q3.w * k3.w;
    bool mk = (mrow[cc] >> lane) & 1ull;
    s[cc] = mk ? -1e8f : d * 0.25f;
  }
  float m = s[0];
#pragma unroll
  for (int cc = 1; cc < 16; cc++) m = fmaxf(m, s[cc]);
  m = wredmax(m);
  float sum = 0.f;
#pragma unroll
  for (int cc = 0; cc < 16; cc++) { s[cc] = __expf(s[cc] - m); sum += s[cc]; }
  sum = wredsum(sum);
  float inv = 1.0f / sum;
  float acc[16];
#pragma unroll
  for (int e = 0; e < 16; e++) acc[e] = 0.f;
#pragma unroll
  for (int cc = 0; cc < 16; cc++) {
    int k = cc * 64 + lane;
    const float4* vp = (const float4*)(Vb + (size_t)k * kDK);
    float4 v0 = vp[0], v1 = vp[1], v2 = vp[2], v3 = vp[3];
    float p = s[cc] * inv;
    acc[0] = fmaf(p, v0.x, acc[0]);  acc[1] = fmaf(p, v0.y, acc[1]);
    acc[2] = fmaf(p, v0.z, acc[2]);  acc[3] = fmaf(p, v0.w, acc[3]);
    acc[4] = fmaf(p, v1.x, acc[4]);  acc[5] = fmaf(p, v1.y, acc[5]);
    acc[6] = fmaf(p, v1.z, acc[6]);  acc[7] = fmaf(p, v1.w, acc[7]);
    acc[8] = fmaf(p, v2.x, acc[8]);  acc[9] = fmaf(p, v2.y, acc[9]);
    acc[10] = fmaf(p, v2.z, acc[10]); acc[11] = fmaf(p, v2.w, acc[11]);
    acc[12] = fmaf(p, v3.x, acc[12]); acc[13] = fmaf(p, v3.y, acc[13]);
    acc[14] = fmaf(p, v3.z, acc[14]); acc[15] = fmaf(p, v3.w, acc[15]);
  }
#pragma unroll
  for (int e = 0; e < 16; e++) acc[e] = wredsum(acc[e]);
  if (lane == 0) {
    float4* op = (float4*)(Hd + ((size_t)(b * nq + q)) * kD + h * kDK);
    op[0] = make_float4(acc[0], acc[1], acc[2], acc[3]);
    op[1] = make_float4(acc[4], acc[5], acc[6], acc[7]);
    op[2] = make_float4(acc[8], acc[9], acc[10], acc[11]);
    op[3] = make_float4(acc[12], acc[13], acc[14], acc[15]);
  }
}

// ---- decoder small kernels ----

__global__ __launch_bounds__(256) void gather_kernel(
    const float* __restrict__ enh, const int* __restrict__ tgt_idx,
    const int* __restrict__ cur_idx, const int* __restrict__ cen_idx,
    float* __restrict__ tgt_f, float* __restrict__ cur_f_out,
    float* __restrict__ cen_f_ws, float* __restrict__ cen_f_out) {
  int b = blockIdx.x;
  int t = threadIdx.x;
  int ti = tgt_idx[b];
  int cui = cur_idx[b];
  if (t < kD) {
    tgt_f[b * kD + t] = enh[((size_t)b * kN + ti) * kD + t];
    cur_f_out[b * kD + t] = enh[((size_t)b * kN + cui) * kD + t];
  }
  for (int i = t; i < kNC * kD; i += 256) {
    int c = i >> 7, e = i & 127;
    float v = enh[((size_t)b * kN + cen_idx[b * kNC + c]) * kD + e];
    cen_f_ws[((size_t)b * kNC + c) * kD + e] = v;
    cen_f_out[((size_t)b * kNC + c) * kD + e] = v;
  }
}

__global__ __launch_bounds__(256) void concat_kernel(
    const float* __restrict__ a, const float* __restrict__ b,
    float* __restrict__ out) {
  int i = blockIdx.x * 256 + threadIdx.x;
  int r = i >> 8, c = i & 255;
  out[i] = (c < kD) ? a[r * kD + c] : b[r * kD + c - kD];
}

__global__ __launch_bounds__(64) void ptr_tail(
    const float* __restrict__ Qp, const float* __restrict__ Kp,
    const int* __restrict__ center_mask, const int* __restrict__ center_index,
    const float* __restrict__ cen_f, float* __restrict__ logp_out,
    float* __restrict__ sel_idx_out, float* __restrict__ sel_feat_out) {
  int b = blockIdx.x;
  int lane = threadIdx.x;
  const float4* qr = (const float4*)(Qp + b * kD);
  const float4* kr = (const float4*)(Kp + ((size_t)b * kNC + lane) * kD);
  float u = 0.f;
#pragma unroll
  for (int e = 0; e < kD / 4; e++) {
    float4 qv = qr[e], kv = kr[e];
    u += qv.x * kv.x + qv.y * kv.y + qv.z * kv.z + qv.w * kv.w;
  }
  u *= 0.08838834764831845f;
  u = 10.0f * tanhf(u);
  if (center_mask[b * kNC + lane] == 1) u = -1e8f;
  float m = wredmax(u);
  float ex = __expf(u - m);
  float sum = wredsum(ex);
  float logp = u - m - logf(sum);
  logp_out[b * kNC + lane] = logp;
  float bm = u; int bi = lane;
#pragma unroll
  for (int o = 32; o; o >>= 1) {
    float om = __shfl_xor(bm, o);
    int oi = __shfl_xor(bi, o);
    if (om > bm || (om == bm && oi < bi)) { bm = om; bi = oi; }
  }
  if (lane == 0) sel_idx_out[b] = (float)center_index[b * kNC + bi];
  const float* cf = cen_f + ((size_t)b * kNC + bi) * kD;
  sel_feat_out[b * kD + lane] = cf[lane];
  sel_feat_out[b * kD + 64 + lane] = cf[64 + lane];
}

// ---- host ----

extern "C" void kernel_launch(void* const* d_in, const int* in_sizes, int n_in,
                              void* d_out, int out_size, void* d_ws,
                              size_t ws_size, hipStream_t stream) {
  (void)in_sizes; (void)n_in; (void)out_size; (void)ws_size;
  const float* node_inputs = (const float*)d_in[0];
  const int* pad_mask = (const int*)d_in[1];
  const int* edge_mask = (const int*)d_in[2];
  const int* center_mask = (const int*)d_in[3];
  const int* center_index = (const int*)d_in[4];
  const int* target_index = (const int*)d_in[5];
  const int* current_index = (const int*)d_in[6];
  const float* init_W = (const float*)d_in[8];
  const float* init_b = (const float*)d_in[9];
  const float* enc_wq = (const float*)d_in[10];
  const float* enc_wk = (const float*)d_in[11];
  const float* enc_wv = (const float*)d_in[12];
  const float* enc_wo = (const float*)d_in[13];
  const float* enc_ln1_g = (const float*)d_in[14];
  const float* enc_ln1_b = (const float*)d_in[15];
  const float* enc_w1 = (const float*)d_in[16];
  const float* enc_b1 = (const float*)d_in[17];
  const float* enc_w2 = (const float*)d_in[18];
  const float* enc_b2 = (const float*)d_in[19];
  const float* enc_ln2_g = (const float*)d_in[20];
  const float* enc_ln2_b = (const float*)d_in[21];
  const float* dec_wq = (const float*)d_in[22];
  const float* dec_wk = (const float*)d_in[23];
  const float* dec_wv = (const float*)d_in[24];
  const float* dec_wo = (const float*)d_in[25];
  const float* dec_ln1_g = (const float*)d_in[26];
  const float* dec_ln1_b = (const float*)d_in[27];
  const float* dec_w1 = (const float*)d_in[28];
  const float* dec_b1 = (const float*)d_in[29];
  const float* dec_w2 = (const float*)d_in[30];
  const float* dec_b2 = (const float*)d_in[31];
  const float* dec_ln2_g = (const float*)d_in[32];
  const float* dec_ln2_b = (const float*)d_in[33];
  const float* tgt_W = (const float*)d_in[34];
  const float* tgt_b = (const float*)d_in[35];
  const float* ptr_wq = (const float*)d_in[36];
  const float* ptr_wk = (const float*)d_in[37];

  float* out_enh = (float*)d_out;
  float* out_curf = out_enh + kB * kN * kD;
  float* out_selidx = out_curf + kB * kD;
  float* out_selfeat = out_selidx + kB;
  float* out_logp = out_selfeat + kB * kD;
  float* out_cenf = out_logp + kB * kNC;

  char* wsp = (char*)d_ws;
  size_t off = 0;
  auto alloc = [&](size_t n) {
    char* p = wsp + off;
    off = (off + n + 255) & ~(size_t)255;
    return p;
  };
  float* x   = (float*)alloc(kR * kD * 4);
  float* h2  = (float*)alloc(kR * kD * 4);
  float* Qb  = (float*)alloc(kR * kD * 4);
  float* Kb  = (float*)alloc(kR * kD * 4);
  float* Vb  = (float*)alloc(kR * kD * 4);
  float* Hd  = (float*)alloc(kR * kD * 4);
  float* tb  = (float*)alloc(kR * kFF * 4);
  unsigned long long* bits_t  = (unsigned long long*)alloc(kR * 16 * 8);
  unsigned long long* padbits = (unsigned long long*)alloc(kB * 16 * 8);
  float* ewqkv = (float*)alloc(kEnc * 3 * kD * kD * 4);
  float* dqkvW = (float*)alloc(3 * kD * kD * 4);
  float* tgt_f = (float*)alloc(kB * kD * 4);
  float* tgt_n = (float*)alloc(kB * kD * 4);
  float* Qd    = (float*)alloc(kB * kD * 4);
  float* Hdd   = (float*)alloc(kB * kD * 4);
  float* dech  = (float*)alloc(kB * kD * 4);
  float* decf  = (float*)alloc(kB * kD * 4);
  float* dect  = (float*)alloc(kB * kFF * 4);
  float* enh_tgt = (float*)alloc(kB * kD * 4);
  float* catb  = (float*)alloc(kB * 2 * kD * 4);
  float* emb   = (float*)alloc(kB * kD * 4);
  float* Qp    = (float*)alloc(kB * kD * 4);
  float* Kp    = (float*)alloc(kB * kNC * kD * 4);
  float* cen_f = (float*)alloc(kB * kNC * kD * 4);

  // prologue
  repack_qkv<<<(kEnc * kD * kD + 255) / 256, 256, 0, stream>>>(
      enc_wq, enc_wk, enc_wv, ewqkv, kEnc);
  repack_qkv<<<(kD * kD + 255) / 256, 256, 0, stream>>>(
      dec_wq, dec_wk, dec_wv, dqkvW, 1);
  pack_mask<<<kB * kN, 256, 0, stream>>>(edge_mask, pad_mask, bits_t);
  pack_pad<<<kB, 256, 0, stream>>>(pad_mask, padbits);
  init_proj<<<kR * kD / 256, 256, 0, stream>>>(node_inputs, init_W, init_b, x);

  // encoder: 5 dispatches/layer
  for (int l = 0; l < kEnc; l++) {
    const float* wo_l = enc_wo + (size_t)l * kH * kDK * kD;
    tile16<128, 1, 0, 2><<<dim3(kR / 16, 3), 256, 0, stream>>>(
        x, ewqkv + (size_t)l * 3 * kD * kD, enc_ln1_g + l * kD,
        enc_ln1_b + l * kD, nullptr, nullptr, Qb, Kb, Vb, kD);
    attn_flash<<<dim3(kB * kH, kN / 64), 256, 0, stream>>>(Qb, Kb, Vb, bits_t, Hd);
    tile16<128, 0, 0, 0><<<dim3(kR / 16, 1), 256, 0, stream>>>(
        Hd, wo_l, nullptr, nullptr, nullptr, x, h2, nullptr, nullptr, kD);
    tile16<128, 1, 1, 0><<<dim3(kR / 16, kFF / 128), 256, 0, stream>>>(
        h2, enc_w1 + (size_t)l * kD * kFF, enc_ln2_g + l * kD,
        enc_ln2_b + l * kD, enc_b1 + l * kFF, nullptr, tb, nullptr, nullptr, kFF);
    float* xout = (l == kEnc - 1) ? out_enh : x;
    tile16<512, 0, 0, 0><<<dim3(kR / 16, 1), 256, 0, stream>>>(
        tb, enc_w2 + (size_t)l * kFF * kD, nullptr, nullptr, enc_b2 + l * kD,
        h2, xout, nullptr, nullptr, kD);
  }

  // decoder
  gather_kernel<<<kB, 256, 0, stream>>>(out_enh, target_index, current_index,
                                        center_index, tgt_f, out_curf, cen_f,
                                        out_cenf);
  // mem K/V: LN(dec_ln1) fused into QKV projection (Q computed, unused)
  tile16<128, 1, 0, 2><<<dim3(kR / 16, 3), 256, 0, stream>>>(
      out_enh, dqkvW, dec_ln1_g, dec_ln1_b, nullptr, nullptr, Qb, Kb, Vb, kD);
  ln_kernel<<<1, 256, 0, stream>>>(tgt_f, dec_ln1_g, dec_ln1_b, tgt_n, kB);
  gemm_f32<<<dim3(1, 1), 256, 0, stream>>>(tgt_n, dqkvW, nullptr, nullptr, Qd,
                                           kB, kD, kD, 0);
  attn_kernel<<<kB * kH * 64 / 256, 256, 0, stream>>>(Qd, Kb, Vb, padbits, Hdd, 1);
  gemm_f32<<<dim3(1, 1), 256, 0, stream>>>(Hdd, dec_wo, nullptr, tgt_f, dech,
                                           kB, kD, kD, 0);
  ln_kernel<<<1, 256, 0, stream>>>(dech, dec_ln2_g, dec_ln2_b, decf, kB);
  gemm_f32<<<dim3(1, kFF / 128), 256, 0, stream>>>(decf, dec_w1, dec_b1,
                                                   nullptr, dect, kB, kD, kFF, 1);
  gemm_f32<<<dim3(1, 1), 256, 0, stream>>>(dect, dec_w2, dec_b2, dech, enh_tgt,
                                           kB, kFF, kD, 0);
  concat_kernel<<<kB, 256, 0, stream>>>(enh_tgt, tgt_f, catb);
  gemm_f32<<<dim3(1, 1), 256, 0, stream>>>(catb, tgt_W, tgt_b, nullptr, emb,
                                           kB, 2 * kD, kD, 0);
  gemm_f32<<<dim3(1, 1), 256, 0, stream>>>(emb, ptr_wq, nullptr, nullptr, Qp,
                                           kB, kD, kD, 0);
  tile16<128, 0, 0, 0><<<dim3(kB * kNC / 16, 1), 256, 0, stream>>>(
      cen_f, ptr_wk, nullptr, nullptr, nullptr, nullptr, Kp, nullptr, nullptr, kD);
  ptr_tail<<<kB, 64, 0, stream>>>(Qp, Kp, center_mask, center_index, cen_f,
                                  out_logp, out_selidx, out_selfeat);
}

// Round 5
// 1508.496 us; speedup vs baseline: 2.6404x; 1.1194x over previous
//
#include <hip/hip_runtime.h>

constexpr int kB = 4, kN = 1024, kIn = 8, kD = 128, kH = 8, kNC = 64,
              kDK = 16, kFF = 512, kEnc = 6, kR = kB * kN;

__device__ __forceinline__ float wredsum(float v) {
  v += __shfl_xor(v, 1);  v += __shfl_xor(v, 2);  v += __shfl_xor(v, 4);
  v += __shfl_xor(v, 8);  v += __shfl_xor(v, 16); v += __shfl_xor(v, 32);
  return v;
}
__device__ __forceinline__ float wredmax(float v) {
  v = fmaxf(v, __shfl_xor(v, 1));  v = fmaxf(v, __shfl_xor(v, 2));
  v = fmaxf(v, __shfl_xor(v, 4));  v = fmaxf(v, __shfl_xor(v, 8));
  v = fmaxf(v, __shfl_xor(v, 16)); v = fmaxf(v, __shfl_xor(v, 32));
  return v;
}

// ---- prologue kernels ----

// repack (l,h,d,e) -> [l][3][128][128] row-major (d -> col h*16+e)
__global__ __launch_bounds__(256) void repack_qkv(
    const float* __restrict__ wq, const float* __restrict__ wk,
    const float* __restrict__ wv, float* __restrict__ out, int layers) {
  int i = blockIdx.x * 256 + threadIdx.x;
  if (i >= layers * kD * kD) return;
  int l = i / (kD * kD);
  int rem = i - l * kD * kD;
  int d = rem >> 7;
  int c = rem & 127;
  int src = ((l * kH + (c >> 4)) * kD + d) * kDK + (c & 15);
  out[(size_t)(l * 3 + 0) * 16384 + rem] = wq[src];
  out[(size_t)(l * 3 + 1) * 16384 + rem] = wk[src];
  out[(size_t)(l * 3 + 2) * 16384 + rem] = wv[src];
}

// transposed bit mask: bits_t[(b*16 + tile)*N + q], bit k-in-tile
__global__ __launch_bounds__(256) void pack_mask(
    const int* __restrict__ edge_mask, const int* __restrict__ pad_mask,
    unsigned long long* __restrict__ bits_t) {
  int row = blockIdx.x;  // b*N + q
  int b = row / kN;
  int q = row % kN;
  int lane = threadIdx.x & 63;
  int wv = threadIdx.x >> 6;
  for (int c0 = wv; c0 < 16; c0 += 4) {
    int k = c0 * 64 + lane;
    int m = edge_mask[(size_t)row * kN + k] + pad_mask[b * kN + k];
    unsigned long long bal = __ballot(m > 0);
    if (lane == 0) bits_t[((size_t)b * 16 + c0) * kN + q] = bal;
  }
}

__global__ __launch_bounds__(256) void pack_pad(
    const int* __restrict__ pad_mask, unsigned long long* __restrict__ bits) {
  int b = blockIdx.x;
  int lane = threadIdx.x & 63;
  int wv = threadIdx.x >> 6;
  for (int c0 = wv; c0 < 16; c0 += 4) {
    int k = c0 * 64 + lane;
    unsigned long long bal = __ballot(pad_mask[b * kN + k] > 0);
    if (lane == 0) bits[b * 16 + c0] = bal;
  }
}

__global__ __launch_bounds__(256) void init_proj(
    const float* __restrict__ ni, const float* __restrict__ W,
    const float* __restrict__ bias, float* __restrict__ x) {
  int i = blockIdx.x * 256 + threadIdx.x;  // r*128 + c
  int r = i >> 7, c = i & 127;
  float acc = bias[c];
#pragma unroll
  for (int k = 0; k < kIn; k++) acc = fmaf(ni[r * kIn + k], W[k * kD + c], acc);
  x[i] = acc;
}

// ---- tile16: pipelined fp32 GEMM, A(16 rows) staged once in LDS (opt LN),
// W staged in 32-row LDS chunks, double-buffered via register prefetch.
// MODE 0: out row-major [R][Cfull]; MODE 2: bhne out picked by blockIdx.y.
template <int K, int LN, int RELU, int MODE>
__global__ __launch_bounds__(256) void tile16(
    const float* __restrict__ A, const float* __restrict__ Wg,
    const float* __restrict__ gamma, const float* __restrict__ beta,
    const float* __restrict__ bias, const float* __restrict__ resid,
    float* __restrict__ O0, float* __restrict__ O1, float* __restrict__ O2,
    int Cfull) {
  __shared__ float As[16][K];
  __shared__ float Ws[2][32][128];
  constexpr int NC = K / 32;
  int r0 = blockIdx.x * 16;
  int y = blockIdx.y;
  const float* Wb;
  int wstride;
  if constexpr (MODE == 2) { Wb = Wg + (size_t)y * K * 128; wstride = 128; }
  else { Wb = Wg + (size_t)y * 128; wstride = Cfull; }

  // ---- stage A (with optional fused LN) ----
  if constexpr (LN) {
    static_assert(K == 128, "LN stage requires K==128");
    int w = threadIdx.x >> 6, lane = threadIdx.x & 63;
#pragma unroll
    for (int i = 0; i < 4; i++) {
      int rr = w * 4 + i;
      const float* xr = A + (size_t)(r0 + rr) * K;
      float2 v = *(const float2*)(xr + lane * 2);
      float mean = wredsum(v.x + v.y) * (1.0f / 128.f);
      float dx = v.x - mean, dy = v.y - mean;
      float var = wredsum(dx * dx + dy * dy) * (1.0f / 128.f);
      float rstd = rsqrtf(var + 1e-5f);
      int c = lane * 2;
      As[rr][c] = dx * rstd * gamma[c] + beta[c];
      As[rr][c + 1] = dy * rstd * gamma[c + 1] + beta[c + 1];
    }
  } else {
    constexpr int NF4 = K / 4;
#pragma unroll
    for (int f = threadIdx.x; f < 16 * NF4; f += 256) {
      int row = f / NF4, c4 = f % NF4;
      *(float4*)&As[row][c4 * 4] =
          *(const float4*)(A + (size_t)(r0 + row) * K + c4 * 4);
    }
  }

  int kk = threadIdx.x >> 3;       // 0..31 (W chunk row)
  int f8 = threadIdx.x & 7;        // 0..7
  float4 wreg[4];
  auto loadW = [&](int kc) {
    const float* Wrow = Wb + (size_t)(kc * 32 + kk) * wstride;
#pragma unroll
    for (int j = 0; j < 4; j++) wreg[j] = *(const float4*)(Wrow + (f8 + 8 * j) * 4);
  };
  auto writeW = [&](int buf) {
#pragma unroll
    for (int j = 0; j < 4; j++) *(float4*)&Ws[buf][kk][(f8 + 8 * j) * 4] = wreg[j];
  };

  loadW(0);
  writeW(0);

  int clocal = threadIdx.x & 127, rsel = threadIdx.x >> 7;
  float acc[8] = {};
  for (int kc = 0; kc < NC; kc++) {
    if (kc + 1 < NC) loadW(kc + 1);   // issue next chunk's global loads
    __syncthreads();                  // Ws[kc&1] (and As on first iter) ready
#pragma unroll
    for (int k4 = 0; k4 < 8; k4++) {
      float4 av[8];
#pragma unroll
      for (int j = 0; j < 8; j++)
        av[j] = *(const float4*)&As[rsel + 2 * j][kc * 32 + k4 * 4];
#pragma unroll
      for (int m = 0; m < 4; m++) {
        float w = Ws[kc & 1][k4 * 4 + m][clocal];
#pragma unroll
        for (int j = 0; j < 8; j++)
          acc[j] = fmaf(((const float*)&av[j])[m], w, acc[j]);
      }
    }
    if (kc + 1 < NC) writeW((kc + 1) & 1);  // waits loads, fills other buffer
  }

  // ---- epilogue ----
  int colg = y * 128 + clocal;
  float bv = bias ? bias[colg] : 0.f;
#pragma unroll
  for (int j = 0; j < 8; j++) {
    int r = r0 + rsel + 2 * j;
    float v = acc[j] + bv;
    if (resid) v += resid[(size_t)r * Cfull + colg];
    if (RELU) v = fmaxf(v, 0.f);
    if constexpr (MODE == 2) {
      int hh = clocal >> 4, e = clocal & 15;
      int bb = r >> 10, n = r & 1023;
      float* P = (y == 0) ? O0 : (y == 1) ? O1 : O2;
      P[(((size_t)(bb * kH + hh)) * kN + n) * kDK + e] = v;
    } else {
      O0[(size_t)r * Cfull + colg] = v;
    }
  }
}

// ---- flash attention: block = 64 q x 4 k-split waves ----
__global__ __launch_bounds__(256) void attn_flash(
    const float* __restrict__ Q, const float* __restrict__ K,
    const float* __restrict__ V, const unsigned long long* __restrict__ bits_t,
    float* __restrict__ Hd) {
  __shared__ float Ks[4][64][16];
  __shared__ float Vs[4][64][16];
  __shared__ float Ms[4][64][20];
  int bh = blockIdx.x, qt = blockIdx.y;
  int b = bh >> 3, h = bh & 7;
  int w = threadIdx.x >> 6, lane = threadIdx.x & 63;
  int q = qt * 64 + lane;
  const float4* qp = (const float4*)(Q + ((size_t)bh * kN + q) * kDK);
  float4 q0 = qp[0], q1 = qp[1], q2 = qp[2], q3 = qp[3];
  const float* Kb = K + (size_t)bh * kN * kDK;
  const float* Vb = V + (size_t)bh * kN * kDK;
  float mx = -3.0e38f, l = 0.f;
  float acc[16];
#pragma unroll
  for (int e = 0; e < 16; e++) acc[e] = 0.f;
  for (int t = 0; t < 4; t++) {
    int kk = w * 256 + t * 64 + lane;
    const float4* kp = (const float4*)(Kb + (size_t)kk * kDK);
    float4 ka = kp[0], kbv = kp[1], kc = kp[2], kd = kp[3];
    const float4* vp = (const float4*)(Vb + (size_t)kk * kDK);
    float4 va = vp[0], vb = vp[1], vc = vp[2], vd = vp[3];
    unsigned long long mb = bits_t[((size_t)b * 16 + w * 4 + t) * kN + q];
    ((float4*)Ks[w][lane])[0] = ka; ((float4*)Ks[w][lane])[1] = kbv;
    ((float4*)Ks[w][lane])[2] = kc; ((float4*)Ks[w][lane])[3] = kd;
    ((float4*)Vs[w][lane])[0] = va; ((float4*)Vs[w][lane])[1] = vb;
    ((float4*)Vs[w][lane])[2] = vc; ((float4*)Vs[w][lane])[3] = vd;
#pragma unroll 4
    for (int k2 = 0; k2 < 64; k2++) {
      const float4* kr = (const float4*)Ks[w][k2];
      float4 k0 = kr[0], k1 = kr[1], k2v = kr[2], k3 = kr[3];
      float s = q0.x * k0.x + q0.y * k0.y + q0.z * k0.z + q0.w * k0.w
              + q1.x * k1.x + q1.y * k1.y + q1.z * k1.z + q1.w * k1.w
              + q2.x * k2v.x + q2.y * k2v.y + q2.z * k2v.z + q2.w * k2v.w
              + q3.x * k3.x + q3.y * k3.y + q3.z * k3.z + q3.w * k3.w;
      s *= 0.25f;
      if ((mb >> k2) & 1ull) s = -1e8f;
      float d = s - mx;
      if (d > 8.f) {
        float sc = __expf(-d);
        l *= sc;
#pragma unroll
        for (int e = 0; e < 16; e++) acc[e] *= sc;
        mx = s; d = 0.f;
      }
      float p = __expf(d);
      l += p;
      const float4* vr = (const float4*)Vs[w][k2];
      float4 v0 = vr[0], v1 = vr[1], v2 = vr[2], v3 = vr[3];
      acc[0] = fmaf(p, v0.x, acc[0]);   acc[1] = fmaf(p, v0.y, acc[1]);
      acc[2] = fmaf(p, v0.z, acc[2]);   acc[3] = fmaf(p, v0.w, acc[3]);
      acc[4] = fmaf(p, v1.x, acc[4]);   acc[5] = fmaf(p, v1.y, acc[5]);
      acc[6] = fmaf(p, v1.z, acc[6]);   acc[7] = fmaf(p, v1.w, acc[7]);
      acc[8] = fmaf(p, v2.x, acc[8]);   acc[9] = fmaf(p, v2.y, acc[9]);
      acc[10] = fmaf(p, v2.z, acc[10]); acc[11] = fmaf(p, v2.w, acc[11]);
      acc[12] = fmaf(p, v3.x, acc[12]); acc[13] = fmaf(p, v3.y, acc[13]);
      acc[14] = fmaf(p, v3.z, acc[14]); acc[15] = fmaf(p, v3.w, acc[15]);
    }
  }
  ((float4*)Ms[w][lane])[0] = make_float4(acc[0], acc[1], acc[2], acc[3]);
  ((float4*)Ms[w][lane])[1] = make_float4(acc[4], acc[5], acc[6], acc[7]);
  ((float4*)Ms[w][lane])[2] = make_float4(acc[8], acc[9], acc[10], acc[11]);
  ((float4*)Ms[w][lane])[3] = make_float4(acc[12], acc[13], acc[14], acc[15]);
  Ms[w][lane][16] = mx;
  Ms[w][lane][17] = l;
  __syncthreads();
  float m0 = Ms[0][lane][16], m1 = Ms[1][lane][16];
  float m2 = Ms[2][lane][16], m3 = Ms[3][lane][16];
  float mstar = fmaxf(fmaxf(m0, m1), fmaxf(m2, m3));
  float f0 = __expf(m0 - mstar), f1 = __expf(m1 - mstar);
  float f2 = __expf(m2 - mstar), f3 = __expf(m3 - mstar);
  float L = f0 * Ms[0][lane][17] + f1 * Ms[1][lane][17] +
            f2 * Ms[2][lane][17] + f3 * Ms[3][lane][17];
  float invL = 1.0f / L;
  float o[4];
#pragma unroll
  for (int e = 0; e < 4; e++) {
    int ei = w * 4 + e;
    o[e] = (f0 * Ms[0][lane][ei] + f1 * Ms[1][lane][ei] +
            f2 * Ms[2][lane][ei] + f3 * Ms[3][lane][ei]) * invL;
  }
  *(float4*)(Hd + ((size_t)(b * kN + q)) * kD + h * kDK + w * 4) =
      make_float4(o[0], o[1], o[2], o[3]);
}

// ---- fully fused decoder tail: one block per batch ----
__global__ __launch_bounds__(256) void dec_fused(
    const float* __restrict__ enh,
    const int* __restrict__ tgt_idx, const int* __restrict__ cur_idx,
    const int* __restrict__ cen_idx, const int* __restrict__ center_mask,
    const unsigned long long* __restrict__ padbits,
    const float* __restrict__ Kb, const float* __restrict__ Vb,
    const float* __restrict__ Wq,   // dec Q proj, repacked [128][128]
    const float* __restrict__ dwo,  // dec_wo flattened [128][128]
    const float* __restrict__ ln1_g, const float* __restrict__ ln1_b,
    const float* __restrict__ ln2_g, const float* __restrict__ ln2_b,
    const float* __restrict__ w1, const float* __restrict__ b1,
    const float* __restrict__ w2, const float* __restrict__ b2,
    const float* __restrict__ tgt_W, const float* __restrict__ tgt_b,
    const float* __restrict__ ptr_wq, const float* __restrict__ ptr_wk,
    float* __restrict__ out_curf, float* __restrict__ out_selidx,
    float* __restrict__ out_selfeat, float* __restrict__ out_logp,
    float* __restrict__ out_cenf) {
  __shared__ float cenf[kNC][129];
  __shared__ float Kps[kNC][129];
  __shared__ float tgtf[128], tgtn[128], qd[128], hdd[128];
  __shared__ float dechs[128], decfs[128], dects[512], embs[128], qps[128];
  __shared__ int bi_s;
  int b = blockIdx.x, t = threadIdx.x;
  int lane = t & 63, w = t >> 6;

  // 1. gathers
  int ti = tgt_idx[b], cui = cur_idx[b];
  if (t < 128) {
    tgtf[t] = enh[((size_t)b * kN + ti) * kD + t];
    out_curf[b * kD + t] = enh[((size_t)b * kN + cui) * kD + t];
  }
  for (int i = t; i < kNC * kD; i += 256) {
    int c = i >> 7, e = i & 127;
    float v = enh[((size_t)b * kN + cen_idx[b * kNC + c]) * kD + e];
    cenf[c][e] = v;
    out_cenf[((size_t)b * kNC + c) * kD + e] = v;
  }
  __syncthreads();

  // 2. tgt_n = LN(tgt_f)
  if (w == 0) {
    float vx = tgtf[lane * 2], vy = tgtf[lane * 2 + 1];
    float mean = wredsum(vx + vy) * (1.0f / 128.f);
    float dx = vx - mean, dy = vy - mean;
    float var = wredsum(dx * dx + dy * dy) * (1.0f / 128.f);
    float rstd = rsqrtf(var + 1e-5f);
    tgtn[lane * 2] = dx * rstd * ln1_g[lane * 2] + ln1_b[lane * 2];
    tgtn[lane * 2 + 1] = dy * rstd * ln1_g[lane * 2 + 1] + ln1_b[lane * 2 + 1];
  }
  __syncthreads();

  // 3. Qd = tgt_n @ Wq
  if (t < 128) {
    float a = 0.f;
#pragma unroll 8
    for (int k = 0; k < 128; k++) a = fmaf(tgtn[k], Wq[k * 128 + t], a);
    qd[t] = a;
  }
  __syncthreads();

  // 4. attention over 1024 keys; wave w -> heads w, w+4
  for (int hi = 0; hi < 2; hi++) {
    int h = w + hi * 4;
    const float* Kh = Kb + ((size_t)(b * kH + h)) * kN * kDK;
    const float* Vh = Vb + ((size_t)(b * kH + h)) * kN * kDK;
    float qv[16];
#pragma unroll
    for (int e = 0; e < 16; e++) qv[e] = qd[h * 16 + e];
    float s[16];
#pragma unroll
    for (int cc = 0; cc < 16; cc++) {
      int k = cc * 64 + lane;
      const float4* kp = (const float4*)(Kh + (size_t)k * kDK);
      float d = 0.f;
#pragma unroll
      for (int j = 0; j < 4; j++) {
        float4 kv = kp[j];
        d += qv[j * 4] * kv.x + qv[j * 4 + 1] * kv.y +
             qv[j * 4 + 2] * kv.z + qv[j * 4 + 3] * kv.w;
      }
      bool mk = (padbits[b * 16 + cc] >> lane) & 1ull;
      s[cc] = mk ? -1e8f : d * 0.25f;
    }
    float m = s[0];
#pragma unroll
    for (int cc = 1; cc < 16; cc++) m = fmaxf(m, s[cc]);
    m = wredmax(m);
    float sum = 0.f;
#pragma unroll
    for (int cc = 0; cc < 16; cc++) { s[cc] = __expf(s[cc] - m); sum += s[cc]; }
    sum = wredsum(sum);
    float inv = 1.0f / sum;
    float acc[16];
#pragma unroll
    for (int e = 0; e < 16; e++) acc[e] = 0.f;
#pragma unroll
    for (int cc = 0; cc < 16; cc++) {
      int k = cc * 64 + lane;
      const float4* vp = (const float4*)(Vh + (size_t)k * kDK);
      float p = s[cc] * inv;
#pragma unroll
      for (int j = 0; j < 4; j++) {
        float4 vv = vp[j];
        acc[j * 4] = fmaf(p, vv.x, acc[j * 4]);
        acc[j * 4 + 1] = fmaf(p, vv.y, acc[j * 4 + 1]);
        acc[j * 4 + 2] = fmaf(p, vv.z, acc[j * 4 + 2]);
        acc[j * 4 + 3] = fmaf(p, vv.w, acc[j * 4 + 3]);
      }
    }
#pragma unroll
    for (int e = 0; e < 16; e++) acc[e] = wredsum(acc[e]);
    if (lane < 16) hdd[h * 16 + lane] = __shfl(acc[lane], 0) * 0.f + 
                                        [&]{ return 0.f; }();  // placeholder (see below)
    // NOTE: simpler exact write below
    if (lane == 0) {
#pragma unroll
      for (int e = 0; e < 16; e++) hdd[h * 16 + e] = acc[e];
    }
  }
  __syncthreads();

  // 5. WO + resid
  if (t < 128) {
    float a = 0.f;
#pragma unroll 8
    for (int k = 0; k < 128; k++) a = fmaf(hdd[k], dwo[k * 128 + t], a);
    dechs[t] = a + tgtf[t];
  }
  __syncthreads();

  // 6. LN2
  if (w == 0) {
    float vx = dechs[lane * 2], vy = dechs[lane * 2 + 1];
    float mean = wredsum(vx + vy) * (1.0f / 128.f);
    float dx = vx - mean, dy = vy - mean;
    float var = wredsum(dx * dx + dy * dy) * (1.0f / 128.f);
    float rstd = rsqrtf(var + 1e-5f);
    decfs[lane * 2] = dx * rstd * ln2_g[lane * 2] + ln2_b[lane * 2];
    decfs[lane * 2 + 1] = dy * rstd * ln2_g[lane * 2 + 1] + ln2_b[lane * 2 + 1];
  }
  __syncthreads();

  // 7. FFN1 (relu): 512 cols, 2 per thread
#pragma unroll
  for (int cc = 0; cc < 2; cc++) {
    int c = t + cc * 256;
    float a = b1[c];
#pragma unroll 8
    for (int k = 0; k < 128; k++) a = fmaf(decfs[k], w1[k * 512 + c], a);
    dects[c] = fmaxf(a, 0.f);
  }
  __syncthreads();

  // 8. FFN2 + resid -> enh_tgt (reuse decfs)
  if (t < 128) {
    float a = b2[t];
#pragma unroll 8
    for (int k = 0; k < 512; k++) a = fmaf(dects[k], w2[k * 128 + t], a);
    decfs[t] = a + dechs[t];  // enh_tgt
  }
  __syncthreads();

  // 9. emb = [enh_tgt, tgt_f] @ tgt_W + tgt_b
  if (t < 128) {
    float a = tgt_b[t];
#pragma unroll 8
    for (int k = 0; k < 128; k++) a = fmaf(decfs[k], tgt_W[k * 128 + t], a);
#pragma unroll 8
    for (int k = 0; k < 128; k++)
      a = fmaf(tgtf[k], tgt_W[(128 + k) * 128 + t], a);
    embs[t] = a;
  }
  __syncthreads();

  // 10. Qp = emb @ ptr_wq
  if (t < 128) {
    float a = 0.f;
#pragma unroll 8
    for (int k = 0; k < 128; k++) a = fmaf(embs[k], ptr_wq[k * 128 + t], a);
    qps[t] = a;
  }
  __syncthreads();

  // 11. Kp = cen_f @ ptr_wk : thread t -> (cen = t>>2, quarter = t&3)
  {
    int cen = t >> 2, qtr = t & 3;
#pragma unroll
    for (int cg = 0; cg < 32; cg++) {
      int c = qtr * 32 + cg;
      float a = 0.f;
#pragma unroll 8
      for (int k = 0; k < 128; k++) a = fmaf(cenf[cen][k], ptr_wk[k * 128 + c], a);
      Kps[cen][c] = a;
    }
  }
  __syncthreads();

  // 12. pointer head on wave 0
  if (w == 0) {
    float u = 0.f;
#pragma unroll 8
    for (int e = 0; e < 128; e++) u = fmaf(qps[e], Kps[lane][e], u);
    u *= 0.08838834764831845f;  // 1/sqrt(128)
    u = 10.0f * tanhf(u);
    if (center_mask[b * kNC + lane] == 1) u = -1e8f;
    float m = wredmax(u);
    float ex = __expf(u - m);
    float sum = wredsum(ex);
    out_logp[b * kNC + lane] = u - m - logf(sum);
    float bm = u; int bi = lane;
#pragma unroll
    for (int o = 32; o; o >>= 1) {
      float om = __shfl_xor(bm, o);
      int oi = __shfl_xor(bi, o);
      if (om > bm || (om == bm && oi < bi)) { bm = om; bi = oi; }
    }
    if (lane == 0) {
      out_selidx[b] = (float)cen_idx[b * kNC + bi];
      bi_s = bi;
    }
  }
  __syncthreads();
  if (t < 128) out_selfeat[b * kD + t] = cenf[bi_s][t];
}

// ---- host ----

extern "C" void kernel_launch(void* const* d_in, const int* in_sizes, int n_in,
                              void* d_out, int out_size, void* d_ws,
                              size_t ws_size, hipStream_t stream) {
  (void)in_sizes; (void)n_in; (void)out_size; (void)ws_size;
  const float* node_inputs = (const float*)d_in[0];
  const int* pad_mask = (const int*)d_in[1];
  const int* edge_mask = (const int*)d_in[2];
  const int* center_mask = (const int*)d_in[3];
  const int* center_index = (const int*)d_in[4];
  const int* target_index = (const int*)d_in[5];
  const int* current_index = (const int*)d_in[6];
  const float* init_W = (const float*)d_in[8];
  const float* init_b = (const float*)d_in[9];
  const float* enc_wq = (const float*)d_in[10];
  const float* enc_wk = (const float*)d_in[11];
  const float* enc_wv = (const float*)d_in[12];
  const float* enc_wo = (const float*)d_in[13];
  const float* enc_ln1_g = (const float*)d_in[14];
  const float* enc_ln1_b = (const float*)d_in[15];
  const float* enc_w1 = (const float*)d_in[16];
  const float* enc_b1 = (const float*)d_in[17];
  const float* enc_w2 = (const float*)d_in[18];
  const float* enc_b2 = (const float*)d_in[19];
  const float* enc_ln2_g = (const float*)d_in[20];
  const float* enc_ln2_b = (const float*)d_in[21];
  const float* dec_wq = (const float*)d_in[22];
  const float* dec_wk = (const float*)d_in[23];
  const float* dec_wv = (const float*)d_in[24];
  const float* dec_wo = (const float*)d_in[25];
  const float* dec_ln1_g = (const float*)d_in[26];
  const float* dec_ln1_b = (const float*)d_in[27];
  const float* dec_w1 = (const float*)d_in[28];
  const float* dec_b1 = (const float*)d_in[29];
  const float* dec_w2 = (const float*)d_in[30];
  const float* dec_b2 = (const float*)d_in[31];
  const float* dec_ln2_g = (const float*)d_in[32];
  const float* dec_ln2_b = (const float*)d_in[33];
  const float* tgt_W = (const float*)d_in[34];
  const float* tgt_b = (const float*)d_in[35];
  const float* ptr_wq = (const float*)d_in[36];
  const float* ptr_wk = (const float*)d_in[37];

  float* out_enh = (float*)d_out;
  float* out_curf = out_enh + kB * kN * kD;
  float* out_selidx = out_curf + kB * kD;
  float* out_selfeat = out_selidx + kB;
  float* out_logp = out_selfeat + kB * kD;
  float* out_cenf = out_logp + kB * kNC;

  char* wsp = (char*)d_ws;
  size_t off = 0;
  auto alloc = [&](size_t n) {
    char* p = wsp + off;
    off = (off + n + 255) & ~(size_t)255;
    return p;
  };
  float* x   = (float*)alloc(kR * kD * 4);
  float* h2  = (float*)alloc(kR * kD * 4);
  float* Qb  = (float*)alloc(kR * kD * 4);
  float* Kb  = (float*)alloc(kR * kD * 4);
  float* Vb  = (float*)alloc(kR * kD * 4);
  float* Hd  = (float*)alloc(kR * kD * 4);
  float* tb  = (float*)alloc(kR * kFF * 4);
  unsigned long long* bits_t  = (unsigned long long*)alloc(kR * 16 * 8);
  unsigned long long* padbits = (unsigned long long*)alloc(kB * 16 * 8);
  float* ewqkv = (float*)alloc(kEnc * 3 * kD * kD * 4);
  float* dqkvW = (float*)alloc(3 * kD * kD * 4);

  // prologue
  repack_qkv<<<(kEnc * kD * kD + 255) / 256, 256, 0, stream>>>(
      enc_wq, enc_wk, enc_wv, ewqkv, kEnc);
  repack_qkv<<<(kD * kD + 255) / 256, 256, 0, stream>>>(
      dec_wq, dec_wk, dec_wv, dqkvW, 1);
  pack_mask<<<kB * kN, 256, 0, stream>>>(edge_mask, pad_mask, bits_t);
  pack_pad<<<kB, 256, 0, stream>>>(pad_mask, padbits);
  init_proj<<<kR * kD / 256, 256, 0, stream>>>(node_inputs, init_W, init_b, x);

  // encoder: 5 dispatches/layer
  for (int l = 0; l < kEnc; l++) {
    const float* wo_l = enc_wo + (size_t)l * kH * kDK * kD;
    tile16<128, 1, 0, 2><<<dim3(kR / 16, 3), 256, 0, stream>>>(
        x, ewqkv + (size_t)l * 3 * kD * kD, enc_ln1_g + l * kD,
        enc_ln1_b + l * kD, nullptr, nullptr, Qb, Kb, Vb, kD);
    attn_flash<<<dim3(kB * kH, kN / 64), 256, 0, stream>>>(Qb, Kb, Vb, bits_t, Hd);
    tile16<128, 0, 0, 0><<<dim3(kR / 16, 1), 256, 0, stream>>>(
        Hd, wo_l, nullptr, nullptr, nullptr, x, h2, nullptr, nullptr, kD);
    tile16<128, 1, 1, 0><<<dim3(kR / 16, kFF / 128), 256, 0, stream>>>(
        h2, enc_w1 + (size_t)l * kD * kFF, enc_ln2_g + l * kD,
        enc_ln2_b + l * kD, enc_b1 + l * kFF, nullptr, tb, nullptr, nullptr, kFF);
    float* xout = (l == kEnc - 1) ? out_enh : x;
    tile16<512, 0, 0, 0><<<dim3(kR / 16, 1), 256, 0, stream>>>(
        tb, enc_w2 + (size_t)l * kFF * kD, nullptr, nullptr, enc_b2 + l * kD,
        h2, xout, nullptr, nullptr, kD);
  }

  // decoder: mem K/V projection (LN(dec_ln1) fused; Q part skipped)
  tile16<128, 1, 0, 2><<<dim3(kR / 16, 2), 256, 0, stream>>>(
      out_enh, dqkvW + 16384, dec_ln1_g, dec_ln1_b, nullptr, nullptr,
      Kb, Vb, nullptr, kD);
  // everything else in one kernel, one block per batch
  dec_fused<<<kB, 256, 0, stream>>>(
      out_enh, target_index, current_index, center_index, center_mask, padbits,
      Kb, Vb, dqkvW, dec_wo, dec_ln1_g, dec_ln1_b, dec_ln2_g, dec_ln2_b,
      dec_w1, dec_b1, dec_w2, dec_b2, tgt_W, tgt_b, ptr_wq, ptr_wk,
      out_curf, out_selidx, out_selfeat, out_logp, out_cenf);
}

// Round 6
// 1497.985 us; speedup vs baseline: 2.6590x; 1.0070x over previous
//
#include <hip/hip_runtime.h>

constexpr int kB = 4, kN = 1024, kIn = 8, kD = 128, kH = 8, kNC = 64,
              kDK = 16, kFF = 512, kEnc = 6, kR = kB * kN;

__device__ __forceinline__ float wredsum(float v) {
  v += __shfl_xor(v, 1);  v += __shfl_xor(v, 2);  v += __shfl_xor(v, 4);
  v += __shfl_xor(v, 8);  v += __shfl_xor(v, 16); v += __shfl_xor(v, 32);
  return v;
}
__device__ __forceinline__ float wredmax(float v) {
  v = fmaxf(v, __shfl_xor(v, 1));  v = fmaxf(v, __shfl_xor(v, 2));
  v = fmaxf(v, __shfl_xor(v, 4));  v = fmaxf(v, __shfl_xor(v, 8));
  v = fmaxf(v, __shfl_xor(v, 16)); v = fmaxf(v, __shfl_xor(v, 32));
  return v;
}
__device__ __forceinline__ float red4(float v) {
  v += __shfl_xor(v, 1);  v += __shfl_xor(v, 2);
  return v;
}

// ---- prologue kernels ----

// repack (l,h,d,e) -> [l][3][128][128] row-major (d -> col h*16+e)
__global__ __launch_bounds__(256) void repack_qkv(
    const float* __restrict__ wq, const float* __restrict__ wk,
    const float* __restrict__ wv, float* __restrict__ out, int layers) {
  int i = blockIdx.x * 256 + threadIdx.x;
  if (i >= layers * kD * kD) return;
  int l = i / (kD * kD);
  int rem = i - l * kD * kD;
  int d = rem >> 7;
  int c = rem & 127;
  int src = ((l * kH + (c >> 4)) * kD + d) * kDK + (c & 15);
  out[(size_t)(l * 3 + 0) * 16384 + rem] = wq[src];
  out[(size_t)(l * 3 + 1) * 16384 + rem] = wk[src];
  out[(size_t)(l * 3 + 2) * 16384 + rem] = wv[src];
}

// transposed bit mask: bits_t[(b*16 + tile)*N + q], bit k-in-tile
__global__ __launch_bounds__(256) void pack_mask(
    const int* __restrict__ edge_mask, const int* __restrict__ pad_mask,
    unsigned long long* __restrict__ bits_t) {
  int row = blockIdx.x;  // b*N + q
  int b = row / kN;
  int q = row % kN;
  int lane = threadIdx.x & 63;
  int wv = threadIdx.x >> 6;
  for (int c0 = wv; c0 < 16; c0 += 4) {
    int k = c0 * 64 + lane;
    int m = edge_mask[(size_t)row * kN + k] + pad_mask[b * kN + k];
    unsigned long long bal = __ballot(m > 0);
    if (lane == 0) bits_t[((size_t)b * 16 + c0) * kN + q] = bal;
  }
}

__global__ __launch_bounds__(256) void pack_pad(
    const int* __restrict__ pad_mask, unsigned long long* __restrict__ bits) {
  int b = blockIdx.x;
  int lane = threadIdx.x & 63;
  int wv = threadIdx.x >> 6;
  for (int c0 = wv; c0 < 16; c0 += 4) {
    int k = c0 * 64 + lane;
    unsigned long long bal = __ballot(pad_mask[b * kN + k] > 0);
    if (lane == 0) bits[b * 16 + c0] = bal;
  }
}

__global__ __launch_bounds__(256) void init_proj(
    const float* __restrict__ ni, const float* __restrict__ W,
    const float* __restrict__ bias, float* __restrict__ x) {
  int i = blockIdx.x * 256 + threadIdx.x;  // r*128 + c
  int r = i >> 7, c = i & 127;
  float acc = bias[c];
#pragma unroll
  for (int k = 0; k < kIn; k++) acc = fmaf(ni[r * kIn + k], W[k * kD + c], acc);
  x[i] = acc;
}

// ---- tile16: pipelined fp32 GEMM (encoder) ----
template <int K, int LN, int RELU, int MODE>
__global__ __launch_bounds__(256) void tile16(
    const float* __restrict__ A, const float* __restrict__ Wg,
    const float* __restrict__ gamma, const float* __restrict__ beta,
    const float* __restrict__ bias, const float* __restrict__ resid,
    float* __restrict__ O0, float* __restrict__ O1, float* __restrict__ O2,
    int Cfull) {
  __shared__ float As[16][K];
  __shared__ float Ws[2][32][128];
  constexpr int NC = K / 32;
  int r0 = blockIdx.x * 16;
  int y = blockIdx.y;
  const float* Wb;
  int wstride;
  if constexpr (MODE == 2) { Wb = Wg + (size_t)y * K * 128; wstride = 128; }
  else { Wb = Wg + (size_t)y * 128; wstride = Cfull; }

  if constexpr (LN) {
    static_assert(K == 128, "LN stage requires K==128");
    int w = threadIdx.x >> 6, lane = threadIdx.x & 63;
#pragma unroll
    for (int i = 0; i < 4; i++) {
      int rr = w * 4 + i;
      const float* xr = A + (size_t)(r0 + rr) * K;
      float2 v = *(const float2*)(xr + lane * 2);
      float mean = wredsum(v.x + v.y) * (1.0f / 128.f);
      float dx = v.x - mean, dy = v.y - mean;
      float var = wredsum(dx * dx + dy * dy) * (1.0f / 128.f);
      float rstd = rsqrtf(var + 1e-5f);
      int c = lane * 2;
      As[rr][c] = dx * rstd * gamma[c] + beta[c];
      As[rr][c + 1] = dy * rstd * gamma[c + 1] + beta[c + 1];
    }
  } else {
    constexpr int NF4 = K / 4;
#pragma unroll
    for (int f = threadIdx.x; f < 16 * NF4; f += 256) {
      int row = f / NF4, c4 = f % NF4;
      *(float4*)&As[row][c4 * 4] =
          *(const float4*)(A + (size_t)(r0 + row) * K + c4 * 4);
    }
  }

  int kk = threadIdx.x >> 3;
  int f8 = threadIdx.x & 7;
  float4 wreg[4];
  auto loadW = [&](int kc) {
    const float* Wrow = Wb + (size_t)(kc * 32 + kk) * wstride;
#pragma unroll
    for (int j = 0; j < 4; j++) wreg[j] = *(const float4*)(Wrow + (f8 + 8 * j) * 4);
  };
  auto writeW = [&](int buf) {
#pragma unroll
    for (int j = 0; j < 4; j++) *(float4*)&Ws[buf][kk][(f8 + 8 * j) * 4] = wreg[j];
  };

  loadW(0);
  writeW(0);

  int clocal = threadIdx.x & 127, rsel = threadIdx.x >> 7;
  float acc[8] = {};
  for (int kc = 0; kc < NC; kc++) {
    if (kc + 1 < NC) loadW(kc + 1);
    __syncthreads();
#pragma unroll
    for (int k4 = 0; k4 < 8; k4++) {
      float4 av[8];
#pragma unroll
      for (int j = 0; j < 8; j++)
        av[j] = *(const float4*)&As[rsel + 2 * j][kc * 32 + k4 * 4];
#pragma unroll
      for (int m = 0; m < 4; m++) {
        float w = Ws[kc & 1][k4 * 4 + m][clocal];
#pragma unroll
        for (int j = 0; j < 8; j++)
          acc[j] = fmaf(((const float*)&av[j])[m], w, acc[j]);
      }
    }
    if (kc + 1 < NC) writeW((kc + 1) & 1);
  }

  int colg = y * 128 + clocal;
  float bv = bias ? bias[colg] : 0.f;
#pragma unroll
  for (int j = 0; j < 8; j++) {
    int r = r0 + rsel + 2 * j;
    float v = acc[j] + bv;
    if (resid) v += resid[(size_t)r * Cfull + colg];
    if (RELU) v = fmaxf(v, 0.f);
    if constexpr (MODE == 2) {
      int hh = clocal >> 4, e = clocal & 15;
      int bb = r >> 10, n = r & 1023;
      float* P = (y == 0) ? O0 : (y == 1) ? O1 : O2;
      P[(((size_t)(bb * kH + hh)) * kN + n) * kDK + e] = v;
    } else {
      O0[(size_t)r * Cfull + colg] = v;
    }
  }
}

// ---- flash attention (encoder): block = 64 q x 4 k-split waves ----
__global__ __launch_bounds__(256) void attn_flash(
    const float* __restrict__ Q, const float* __restrict__ K,
    const float* __restrict__ V, const unsigned long long* __restrict__ bits_t,
    float* __restrict__ Hd) {
  __shared__ float Ks[4][64][16];
  __shared__ float Vs[4][64][16];
  __shared__ float Ms[4][64][20];
  int bh = blockIdx.x, qt = blockIdx.y;
  int b = bh >> 3, h = bh & 7;
  int w = threadIdx.x >> 6, lane = threadIdx.x & 63;
  int q = qt * 64 + lane;
  const float4* qp = (const float4*)(Q + ((size_t)bh * kN + q) * kDK);
  float4 q0 = qp[0], q1 = qp[1], q2 = qp[2], q3 = qp[3];
  const float* Kb = K + (size_t)bh * kN * kDK;
  const float* Vb = V + (size_t)bh * kN * kDK;
  float mx = -3.0e38f, l = 0.f;
  float acc[16];
#pragma unroll
  for (int e = 0; e < 16; e++) acc[e] = 0.f;
  for (int t = 0; t < 4; t++) {
    int kk = w * 256 + t * 64 + lane;
    const float4* kp = (const float4*)(Kb + (size_t)kk * kDK);
    float4 ka = kp[0], kbv = kp[1], kc = kp[2], kd = kp[3];
    const float4* vp = (const float4*)(Vb + (size_t)kk * kDK);
    float4 va = vp[0], vb = vp[1], vc = vp[2], vd = vp[3];
    unsigned long long mb = bits_t[((size_t)b * 16 + w * 4 + t) * kN + q];
    ((float4*)Ks[w][lane])[0] = ka; ((float4*)Ks[w][lane])[1] = kbv;
    ((float4*)Ks[w][lane])[2] = kc; ((float4*)Ks[w][lane])[3] = kd;
    ((float4*)Vs[w][lane])[0] = va; ((float4*)Vs[w][lane])[1] = vb;
    ((float4*)Vs[w][lane])[2] = vc; ((float4*)Vs[w][lane])[3] = vd;
#pragma unroll 4
    for (int k2 = 0; k2 < 64; k2++) {
      const float4* kr = (const float4*)Ks[w][k2];
      float4 k0 = kr[0], k1 = kr[1], k2v = kr[2], k3 = kr[3];
      float s = q0.x * k0.x + q0.y * k0.y + q0.z * k0.z + q0.w * k0.w
              + q1.x * k1.x + q1.y * k1.y + q1.z * k1.z + q1.w * k1.w
              + q2.x * k2v.x + q2.y * k2v.y + q2.z * k2v.z + q2.w * k2v.w
              + q3.x * k3.x + q3.y * k3.y + q3.z * k3.z + q3.w * k3.w;
      s *= 0.25f;
      if ((mb >> k2) & 1ull) s = -1e8f;
      float d = s - mx;
      if (d > 8.f) {
        float sc = __expf(-d);
        l *= sc;
#pragma unroll
        for (int e = 0; e < 16; e++) acc[e] *= sc;
        mx = s; d = 0.f;
      }
      float p = __expf(d);
      l += p;
      const float4* vr = (const float4*)Vs[w][k2];
      float4 v0 = vr[0], v1 = vr[1], v2 = vr[2], v3 = vr[3];
      acc[0] = fmaf(p, v0.x, acc[0]);   acc[1] = fmaf(p, v0.y, acc[1]);
      acc[2] = fmaf(p, v0.z, acc[2]);   acc[3] = fmaf(p, v0.w, acc[3]);
      acc[4] = fmaf(p, v1.x, acc[4]);   acc[5] = fmaf(p, v1.y, acc[5]);
      acc[6] = fmaf(p, v1.z, acc[6]);   acc[7] = fmaf(p, v1.w, acc[7]);
      acc[8] = fmaf(p, v2.x, acc[8]);   acc[9] = fmaf(p, v2.y, acc[9]);
      acc[10] = fmaf(p, v2.z, acc[10]); acc[11] = fmaf(p, v2.w, acc[11]);
      acc[12] = fmaf(p, v3.x, acc[12]); acc[13] = fmaf(p, v3.y, acc[13]);
      acc[14] = fmaf(p, v3.z, acc[14]); acc[15] = fmaf(p, v3.w, acc[15]);
    }
  }
  ((float4*)Ms[w][lane])[0] = make_float4(acc[0], acc[1], acc[2], acc[3]);
  ((float4*)Ms[w][lane])[1] = make_float4(acc[4], acc[5], acc[6], acc[7]);
  ((float4*)Ms[w][lane])[2] = make_float4(acc[8], acc[9], acc[10], acc[11]);
  ((float4*)Ms[w][lane])[3] = make_float4(acc[12], acc[13], acc[14], acc[15]);
  Ms[w][lane][16] = mx;
  Ms[w][lane][17] = l;
  __syncthreads();
  float m0 = Ms[0][lane][16], m1 = Ms[1][lane][16];
  float m2 = Ms[2][lane][16], m3 = Ms[3][lane][16];
  float mstar = fmaxf(fmaxf(m0, m1), fmaxf(m2, m3));
  float f0 = __expf(m0 - mstar), f1 = __expf(m1 - mstar);
  float f2 = __expf(m2 - mstar), f3 = __expf(m3 - mstar);
  float L = f0 * Ms[0][lane][17] + f1 * Ms[1][lane][17] +
            f2 * Ms[2][lane][17] + f3 * Ms[3][lane][17];
  float invL = 1.0f / L;
  float o[4];
#pragma unroll
  for (int e = 0; e < 4; e++) {
    int ei = w * 4 + e;
    o[e] = (f0 * Ms[0][lane][ei] + f1 * Ms[1][lane][ei] +
            f2 * Ms[2][lane][ei] + f3 * Ms[3][lane][ei]) * invL;
  }
  *(float4*)(Hd + ((size_t)(b * kN + q)) * kD + h * kDK + w * 4) =
      make_float4(o[0], o[1], o[2], o[3]);
}

// ==== decoder (algebraic: K/V never materialized) ====

// dec_prep: gathers + tgt LN + Qd + qk[b][h][d] = 0.25 * Wk_h @ Qd_h
__global__ __launch_bounds__(256) void dec_prep(
    const float* __restrict__ enh, const int* __restrict__ tgt_idx,
    const int* __restrict__ cur_idx, const int* __restrict__ cen_idx,
    const float* __restrict__ Wq,  // repacked [128][128]
    const float* __restrict__ ln1_g, const float* __restrict__ ln1_b,
    const float* __restrict__ dec_wk,  // (H,D,DK)
    float* __restrict__ out_curf, float* __restrict__ out_cenf,
    float* __restrict__ tgtf_ws, float* __restrict__ qk_ws) {
  __shared__ float tgtf_s[128], tgtn[128], qd[128];
  int b = blockIdx.x, t = threadIdx.x;
  int lane = t & 63, w = t >> 6;
  int ti = tgt_idx[b], cui = cur_idx[b];
  if (t < 128) {
    float tf = enh[((size_t)b * kN + ti) * kD + t];
    tgtf_s[t] = tf;
    tgtf_ws[b * kD + t] = tf;
    out_curf[b * kD + t] = enh[((size_t)b * kN + cui) * kD + t];
  }
  for (int i = t; i < kNC * kD; i += 256) {
    int c = i >> 7, e = i & 127;
    out_cenf[((size_t)b * kNC + c) * kD + e] =
        enh[((size_t)b * kN + cen_idx[b * kNC + c]) * kD + e];
  }
  __syncthreads();
  if (w == 0) {
    float vx = tgtf_s[lane * 2], vy = tgtf_s[lane * 2 + 1];
    float mean = wredsum(vx + vy) * (1.0f / 128.f);
    float dx = vx - mean, dy = vy - mean;
    float var = wredsum(dx * dx + dy * dy) * (1.0f / 128.f);
    float rstd = rsqrtf(var + 1e-5f);
    tgtn[lane * 2] = dx * rstd * ln1_g[lane * 2] + ln1_b[lane * 2];
    tgtn[lane * 2 + 1] = dy * rstd * ln1_g[lane * 2 + 1] + ln1_b[lane * 2 + 1];
  }
  __syncthreads();
  if (t < 128) {
    float a = 0.f;
#pragma unroll 8
    for (int k = 0; k < 128; k++) a = fmaf(tgtn[k], Wq[k * 128 + t], a);
    qd[t] = a;
  }
  __syncthreads();
  int h = t >> 5, d0 = (t & 31) * 4;
#pragma unroll
  for (int j = 0; j < 4; j++) {
    int d = d0 + j;
    const float4* wp = (const float4*)(dec_wk + (((size_t)h * 128 + d) << 4));
    float a = 0.f;
#pragma unroll
    for (int r = 0; r < 4; r++) {
      float4 wv = wp[r];
      a += wv.x * qd[h * 16 + r * 4] + wv.y * qd[h * 16 + r * 4 + 1] +
           wv.z * qd[h * 16 + r * 4 + 2] + wv.w * qd[h * 16 + r * 4 + 3];
    }
    qk_ws[b * 1024 + h * 128 + d] = 0.25f * a;
  }
}

// dec_score: per 64-row tile: fused LN -> ln_ws, scores[b][h][n]
__global__ __launch_bounds__(256) void dec_score(
    const float* __restrict__ enh, const float* __restrict__ ln_g,
    const float* __restrict__ ln_b, const float* __restrict__ qk_ws,
    const unsigned long long* __restrict__ padbits,
    float* __restrict__ ln_ws, float* __restrict__ scores) {
  __shared__ float qs[8][128];
  int b = blockIdx.x, nt = blockIdx.y, t = threadIdx.x;
  for (int i = t; i < 1024; i += 256) ((float*)qs)[i] = qk_ws[b * 1024 + i];
  __syncthreads();
  int w = t >> 6, lane = t & 63, ri = lane >> 2, q4 = lane & 3;
  int n = nt * 64 + w * 16 + ri;
  const float* row = enh + ((size_t)b * kN + n) * kD;
  // lane owns dims d = j*16 + q4*4 + (0..3), j = 0..7 (bank-safe interleave)
  float4 xv[8];
#pragma unroll
  for (int j = 0; j < 8; j++) xv[j] = *(const float4*)(row + j * 16 + q4 * 4);
  float s1 = 0.f;
#pragma unroll
  for (int j = 0; j < 8; j++) s1 += xv[j].x + xv[j].y + xv[j].z + xv[j].w;
  s1 = red4(s1);
  float mean = s1 * (1.0f / 128.f);
  float s2 = 0.f;
#pragma unroll
  for (int j = 0; j < 8; j++) {
    xv[j].x -= mean; xv[j].y -= mean; xv[j].z -= mean; xv[j].w -= mean;
    s2 += xv[j].x * xv[j].x + xv[j].y * xv[j].y + xv[j].z * xv[j].z +
          xv[j].w * xv[j].w;
  }
  s2 = red4(s2);
  float rstd = rsqrtf(s2 * (1.0f / 128.f) + 1e-5f);
#pragma unroll
  for (int j = 0; j < 8; j++) {
    int d0 = j * 16 + q4 * 4;
    float4 g = *(const float4*)(ln_g + d0);
    float4 be = *(const float4*)(ln_b + d0);
    xv[j].x = xv[j].x * rstd * g.x + be.x;
    xv[j].y = xv[j].y * rstd * g.y + be.y;
    xv[j].z = xv[j].z * rstd * g.z + be.z;
    xv[j].w = xv[j].w * rstd * g.w + be.w;
    *(float4*)(ln_ws + ((size_t)b * kN + n) * kD + d0) = xv[j];
  }
  bool mk = (padbits[b * 16 + (n >> 6)] >> (n & 63)) & 1ull;
#pragma unroll
  for (int h = 0; h < 8; h++) {
    float p = 0.f;
#pragma unroll
    for (int j = 0; j < 8; j++) {
      float4 qv = *(const float4*)&qs[h][j * 16 + q4 * 4];
      p += xv[j].x * qv.x + xv[j].y * qv.y + xv[j].z * qv.z + xv[j].w * qv.w;
    }
    p = red4(p);
    if (q4 == 0) scores[((size_t)b * 8 + h) * 1024 + n] = mk ? -1e8f : p;
  }
}

// dec_softmax: per batch, per head max + expsum
__global__ __launch_bounds__(256) void dec_softmax(
    const float* __restrict__ scores, float* __restrict__ ml) {
  int b = blockIdx.x, t = threadIdx.x, w = t >> 6, lane = t & 63;
  for (int hi = 0; hi < 2; hi++) {
    int h = w + hi * 4;
    const float* sr = scores + ((size_t)b * 8 + h) * 1024;
    float v[16];
    float m = -3.0e38f;
#pragma unroll
    for (int i = 0; i < 16; i++) { v[i] = sr[i * 64 + lane]; m = fmaxf(m, v[i]); }
    m = wredmax(m);
    float l = 0.f;
#pragma unroll
    for (int i = 0; i < 16; i++) l += __expf(v[i] - m);
    l = wredsum(l);
    if (lane == 0) { ml[(b * 8 + h) * 2] = m; ml[(b * 8 + h) * 2 + 1] = l; }
  }
}

// dec_attnsum: partial[b][tile][h][d] = sum_n p * ln_enh
__global__ __launch_bounds__(256) void dec_attnsum(
    const float* __restrict__ ln_ws, const float* __restrict__ scores,
    const float* __restrict__ ml, float* __restrict__ partial) {
  __shared__ float lns[64][128];
  __shared__ float ps[8][64];
  int b = blockIdx.x, nt = blockIdx.y, t = threadIdx.x;
  for (int i = t; i < 64 * 32; i += 256) {
    int nn = i >> 5, c4 = i & 31;
    *(float4*)&lns[nn][c4 * 4] =
        *(const float4*)(ln_ws + ((size_t)b * kN + nt * 64 + nn) * kD + c4 * 4);
  }
  for (int i = t; i < 512; i += 256) {
    int h = i >> 6, nn = i & 63;
    float m = ml[(b * 8 + h) * 2], l = ml[(b * 8 + h) * 2 + 1];
    ps[h][nn] =
        __expf(scores[((size_t)b * 8 + h) * 1024 + nt * 64 + nn] - m) / l;
  }
  __syncthreads();
  int h = t >> 5, d0 = (t & 31) * 4;
  float4 acc = make_float4(0.f, 0.f, 0.f, 0.f);
  for (int nn = 0; nn < 64; nn++) {
    float p = ps[h][nn];
    float4 lv = *(const float4*)&lns[nn][d0];
    acc.x = fmaf(p, lv.x, acc.x); acc.y = fmaf(p, lv.y, acc.y);
    acc.z = fmaf(p, lv.z, acc.z); acc.w = fmaf(p, lv.w, acc.w);
  }
  *(float4*)(partial + ((size_t)(b * 16 + nt) * 8 + h) * 128 + d0) = acc;
}

// dec_fused2: combine + Hd=wsum@Wv + WO/LN/FFN/pointer head
__global__ __launch_bounds__(256) void dec_fused2(
    const float* __restrict__ partial, const float* __restrict__ dec_wv,
    const float* __restrict__ dwo, const float* __restrict__ tgtf_ws,
    const float* __restrict__ cenf_g, const int* __restrict__ cen_idx,
    const int* __restrict__ center_mask,
    const float* __restrict__ ln2_g, const float* __restrict__ ln2_b,
    const float* __restrict__ w1, const float* __restrict__ b1,
    const float* __restrict__ w2, const float* __restrict__ b2,
    const float* __restrict__ tgt_W, const float* __restrict__ tgt_b,
    const float* __restrict__ ptr_wq, const float* __restrict__ ptr_wk,
    float* __restrict__ out_selidx, float* __restrict__ out_selfeat,
    float* __restrict__ out_logp) {
  __shared__ float cenf[kNC][129];
  __shared__ float Kps[kNC][129];
  __shared__ float wsum[8][132];
  __shared__ float hdd[128], tgtf[128], dechs[128], decfs[128], dects[512],
                   embs[128], qps[128];
  __shared__ int bi_s;
  int b = blockIdx.x, t = threadIdx.x, w = t >> 6, lane = t & 63;
  if (t < 128) tgtf[t] = tgtf_ws[b * kD + t];
  for (int i = t; i < kNC * kD; i += 256) {
    int c = i >> 7, e = i & 127;
    cenf[c][e] = cenf_g[((size_t)b * kNC + c) * kD + e];
  }
  {
    int h = t >> 5, d0 = (t & 31) * 4;
    float4 a = make_float4(0.f, 0.f, 0.f, 0.f);
#pragma unroll
    for (int tt = 0; tt < 16; tt++) {
      float4 pv =
          *(const float4*)(partial + ((size_t)(b * 16 + tt) * 8 + h) * 128 + d0);
      a.x += pv.x; a.y += pv.y; a.z += pv.z; a.w += pv.w;
    }
    wsum[h][d0] = a.x; wsum[h][d0 + 1] = a.y;
    wsum[h][d0 + 2] = a.z; wsum[h][d0 + 3] = a.w;
  }
  __syncthreads();
  if (t < 128) {
    int h = t >> 4, e = t & 15;
    float a = 0.f;
#pragma unroll 8
    for (int d = 0; d < 128; d++)
      a = fmaf(wsum[h][d], dec_wv[((size_t)h * 128 + d) * 16 + e], a);
    hdd[t] = a;
  }
  __syncthreads();
  // WO + resid
  if (t < 128) {
    float a = 0.f;
#pragma unroll 8
    for (int k = 0; k < 128; k++) a = fmaf(hdd[k], dwo[k * 128 + t], a);
    dechs[t] = a + tgtf[t];
  }
  __syncthreads();
  // LN2
  if (w == 0) {
    float vx = dechs[lane * 2], vy = dechs[lane * 2 + 1];
    float mean = wredsum(vx + vy) * (1.0f / 128.f);
    float dx = vx - mean, dy = vy - mean;
    float var = wredsum(dx * dx + dy * dy) * (1.0f / 128.f);
    float rstd = rsqrtf(var + 1e-5f);
    decfs[lane * 2] = dx * rstd * ln2_g[lane * 2] + ln2_b[lane * 2];
    decfs[lane * 2 + 1] = dy * rstd * ln2_g[lane * 2 + 1] + ln2_b[lane * 2 + 1];
  }
  __syncthreads();
  // FFN1 (relu)
#pragma unroll
  for (int cc = 0; cc < 2; cc++) {
    int c = t + cc * 256;
    float a = b1[c];
#pragma unroll 8
    for (int k = 0; k < 128; k++) a = fmaf(decfs[k], w1[k * 512 + c], a);
    dects[c] = fmaxf(a, 0.f);
  }
  __syncthreads();
  // FFN2 + resid -> enh_tgt
  if (t < 128) {
    float a = b2[t];
#pragma unroll 8
    for (int k = 0; k < 512; k++) a = fmaf(dects[k], w2[k * 128 + t], a);
    decfs[t] = a + dechs[t];
  }
  __syncthreads();
  // emb = [enh_tgt, tgt_f] @ tgt_W + tgt_b
  if (t < 128) {
    float a = tgt_b[t];
#pragma unroll 8
    for (int k = 0; k < 128; k++) a = fmaf(decfs[k], tgt_W[k * 128 + t], a);
#pragma unroll 8
    for (int k = 0; k < 128; k++)
      a = fmaf(tgtf[k], tgt_W[(128 + k) * 128 + t], a);
    embs[t] = a;
  }
  __syncthreads();
  // Qp
  if (t < 128) {
    float a = 0.f;
#pragma unroll 8
    for (int k = 0; k < 128; k++) a = fmaf(embs[k], ptr_wq[k * 128 + t], a);
    qps[t] = a;
  }
  __syncthreads();
  // Kp = cen_f @ ptr_wk
  {
    int cen = t >> 2, qtr = t & 3;
#pragma unroll
    for (int cg = 0; cg < 32; cg++) {
      int c = qtr * 32 + cg;
      float a = 0.f;
#pragma unroll 8
      for (int k = 0; k < 128; k++)
        a = fmaf(cenf[cen][k], ptr_wk[k * 128 + c], a);
      Kps[cen][c] = a;
    }
  }
  __syncthreads();
  // pointer head on wave 0
  if (w == 0) {
    float u = 0.f;
#pragma unroll 8
    for (int e = 0; e < 128; e++) u = fmaf(qps[e], Kps[lane][e], u);
    u *= 0.08838834764831845f;
    u = 10.0f * tanhf(u);
    if (center_mask[b * kNC + lane] == 1) u = -1e8f;
    float m = wredmax(u);
    float ex = __expf(u - m);
    float sum = wredsum(ex);
    out_logp[b * kNC + lane] = u - m - logf(sum);
    float bm = u; int bi = lane;
#pragma unroll
    for (int o = 32; o; o >>= 1) {
      float om = __shfl_xor(bm, o);
      int oi = __shfl_xor(bi, o);
      if (om > bm || (om == bm && oi < bi)) { bm = om; bi = oi; }
    }
    if (lane == 0) {
      out_selidx[b] = (float)cen_idx[b * kNC + bi];
      bi_s = bi;
    }
  }
  __syncthreads();
  if (t < 128) out_selfeat[b * kD + t] = cenf[bi_s][t];
}

// ---- host ----

extern "C" void kernel_launch(void* const* d_in, const int* in_sizes, int n_in,
                              void* d_out, int out_size, void* d_ws,
                              size_t ws_size, hipStream_t stream) {
  (void)in_sizes; (void)n_in; (void)out_size; (void)ws_size;
  const float* node_inputs = (const float*)d_in[0];
  const int* pad_mask = (const int*)d_in[1];
  const int* edge_mask = (const int*)d_in[2];
  const int* center_mask = (const int*)d_in[3];
  const int* center_index = (const int*)d_in[4];
  const int* target_index = (const int*)d_in[5];
  const int* current_index = (const int*)d_in[6];
  const float* init_W = (const float*)d_in[8];
  const float* init_b = (const float*)d_in[9];
  const float* enc_wq = (const float*)d_in[10];
  const float* enc_wk = (const float*)d_in[11];
  const float* enc_wv = (const float*)d_in[12];
  const float* enc_wo = (const float*)d_in[13];
  const float* enc_ln1_g = (const float*)d_in[14];
  const float* enc_ln1_b = (const float*)d_in[15];
  const float* enc_w1 = (const float*)d_in[16];
  const float* enc_b1 = (const float*)d_in[17];
  const float* enc_w2 = (const float*)d_in[18];
  const float* enc_b2 = (const float*)d_in[19];
  const float* enc_ln2_g = (const float*)d_in[20];
  const float* enc_ln2_b = (const float*)d_in[21];
  const float* dec_wq = (const float*)d_in[22];
  const float* dec_wk = (const float*)d_in[23];
  const float* dec_wv = (const float*)d_in[24];
  const float* dec_wo = (const float*)d_in[25];
  const float* dec_ln1_g = (const float*)d_in[26];
  const float* dec_ln1_b = (const float*)d_in[27];
  const float* dec_w1 = (const float*)d_in[28];
  const float* dec_b1 = (const float*)d_in[29];
  const float* dec_w2 = (const float*)d_in[30];
  const float* dec_b2 = (const float*)d_in[31];
  const float* dec_ln2_g = (const float*)d_in[32];
  const float* dec_ln2_b = (const float*)d_in[33];
  const float* tgt_W = (const float*)d_in[34];
  const float* tgt_b = (const float*)d_in[35];
  const float* ptr_wq = (const float*)d_in[36];
  const float* ptr_wk = (const float*)d_in[37];

  float* out_enh = (float*)d_out;
  float* out_curf = out_enh + kB * kN * kD;
  float* out_selidx = out_curf + kB * kD;
  float* out_selfeat = out_selidx + kB;
  float* out_logp = out_selfeat + kB * kD;
  float* out_cenf = out_logp + kB * kNC;

  char* wsp = (char*)d_ws;
  size_t off = 0;
  auto alloc = [&](size_t n) {
    char* p = wsp + off;
    off = (off + n + 255) & ~(size_t)255;
    return p;
  };
  float* x   = (float*)alloc(kR * kD * 4);
  float* h2  = (float*)alloc(kR * kD * 4);
  float* Qb  = (float*)alloc(kR * kD * 4);
  float* Kb  = (float*)alloc(kR * kD * 4);
  float* Vb  = (float*)alloc(kR * kD * 4);
  float* Hd  = (float*)alloc(kR * kD * 4);
  float* tb  = (float*)alloc(kR * kFF * 4);
  unsigned long long* bits_t  = (unsigned long long*)alloc(kR * 16 * 8);
  unsigned long long* padbits = (unsigned long long*)alloc(kB * 16 * 8);
  float* ewqkv = (float*)alloc(kEnc * 3 * kD * kD * 4);
  float* dqkvW = (float*)alloc(3 * kD * kD * 4);
  float* ln_ws = (float*)alloc(kR * kD * 4);
  float* scores_ws = (float*)alloc(kB * kH * kN * 4);
  float* ml_ws = (float*)alloc(kB * kH * 2 * 4);
  float* partial_ws = (float*)alloc(kB * 16 * kH * kD * 4);
  float* qk_ws = (float*)alloc(kB * kH * kD * 4);
  float* tgtf_ws = (float*)alloc(kB * kD * 4);

  // prologue
  repack_qkv<<<(kEnc * kD * kD + 255) / 256, 256, 0, stream>>>(
      enc_wq, enc_wk, enc_wv, ewqkv, kEnc);
  repack_qkv<<<(kD * kD + 255) / 256, 256, 0, stream>>>(
      dec_wq, dec_wk, dec_wv, dqkvW, 1);
  pack_mask<<<kB * kN, 256, 0, stream>>>(edge_mask, pad_mask, bits_t);
  pack_pad<<<kB, 256, 0, stream>>>(pad_mask, padbits);
  init_proj<<<kR * kD / 256, 256, 0, stream>>>(node_inputs, init_W, init_b, x);

  // encoder: 5 dispatches/layer (unchanged)
  for (int l = 0; l < kEnc; l++) {
    const float* wo_l = enc_wo + (size_t)l * kH * kDK * kD;
    tile16<128, 1, 0, 2><<<dim3(kR / 16, 3), 256, 0, stream>>>(
        x, ewqkv + (size_t)l * 3 * kD * kD, enc_ln1_g + l * kD,
        enc_ln1_b + l * kD, nullptr, nullptr, Qb, Kb, Vb, kD);
    attn_flash<<<dim3(kB * kH, kN / 64), 256, 0, stream>>>(Qb, Kb, Vb, bits_t, Hd);
    tile16<128, 0, 0, 0><<<dim3(kR / 16, 1), 256, 0, stream>>>(
        Hd, wo_l, nullptr, nullptr, nullptr, x, h2, nullptr, nullptr, kD);
    tile16<128, 1, 1, 0><<<dim3(kR / 16, kFF / 128), 256, 0, stream>>>(
        h2, enc_w1 + (size_t)l * kD * kFF, enc_ln2_g + l * kD,
        enc_ln2_b + l * kD, enc_b1 + l * kFF, nullptr, tb, nullptr, nullptr, kFF);
    float* xout = (l == kEnc - 1) ? out_enh : x;
    tile16<512, 0, 0, 0><<<dim3(kR / 16, 1), 256, 0, stream>>>(
        tb, enc_w2 + (size_t)l * kFF * kD, nullptr, nullptr, enc_b2 + l * kD,
        h2, xout, nullptr, nullptr, kD);
  }

  // decoder (algebraic)
  dec_prep<<<kB, 256, 0, stream>>>(out_enh, target_index, current_index,
                                   center_index, dqkvW, dec_ln1_g, dec_ln1_b,
                                   dec_wk, out_curf, out_cenf, tgtf_ws, qk_ws);
  dec_score<<<dim3(kB, 16), 256, 0, stream>>>(out_enh, dec_ln1_g, dec_ln1_b,
                                              qk_ws, padbits, ln_ws, scores_ws);
  dec_softmax<<<kB, 256, 0, stream>>>(scores_ws, ml_ws);
  dec_attnsum<<<dim3(kB, 16), 256, 0, stream>>>(ln_ws, scores_ws, ml_ws,
                                                partial_ws);
  dec_fused2<<<kB, 256, 0, stream>>>(
      partial_ws, dec_wv, dec_wo, tgtf_ws, out_cenf, center_index, center_mask,
      dec_ln2_g, dec_ln2_b, dec_w1, dec_b1, dec_w2, dec_b2, tgt_W, tgt_b,
      ptr_wq, ptr_wk, out_selidx, out_selfeat, out_logp);
}

// Round 7
// 1308.687 us; speedup vs baseline: 3.0436x; 1.1446x over previous
//
#include <hip/hip_runtime.h>

constexpr int kB = 4, kN = 1024, kIn = 8, kD = 128, kH = 8, kNC = 64,
              kDK = 16, kFF = 512, kEnc = 6, kR = kB * kN;

__device__ __forceinline__ float wredsum(float v) {
  v += __shfl_xor(v, 1);  v += __shfl_xor(v, 2);  v += __shfl_xor(v, 4);
  v += __shfl_xor(v, 8);  v += __shfl_xor(v, 16); v += __shfl_xor(v, 32);
  return v;
}
__device__ __forceinline__ float wredmax(float v) {
  v = fmaxf(v, __shfl_xor(v, 1));  v = fmaxf(v, __shfl_xor(v, 2));
  v = fmaxf(v, __shfl_xor(v, 4));  v = fmaxf(v, __shfl_xor(v, 8));
  v = fmaxf(v, __shfl_xor(v, 16)); v = fmaxf(v, __shfl_xor(v, 32));
  return v;
}
__device__ __forceinline__ float red4(float v) {
  v += __shfl_xor(v, 1);  v += __shfl_xor(v, 2);
  return v;
}

// ---- prologue kernels ----

__global__ __launch_bounds__(256) void repack_qkv(
    const float* __restrict__ wq, const float* __restrict__ wk,
    const float* __restrict__ wv, float* __restrict__ out, int layers) {
  int i = blockIdx.x * 256 + threadIdx.x;
  if (i >= layers * kD * kD) return;
  int l = i / (kD * kD);
  int rem = i - l * kD * kD;
  int d = rem >> 7;
  int c = rem & 127;
  int src = ((l * kH + (c >> 4)) * kD + d) * kDK + (c & 15);
  out[(size_t)(l * 3 + 0) * 16384 + rem] = wq[src];
  out[(size_t)(l * 3 + 1) * 16384 + rem] = wk[src];
  out[(size_t)(l * 3 + 2) * 16384 + rem] = wv[src];
}

__global__ __launch_bounds__(256) void pack_mask(
    const int* __restrict__ edge_mask, const int* __restrict__ pad_mask,
    unsigned long long* __restrict__ bits_t) {
  int row = blockIdx.x;  // b*N + q
  int b = row / kN;
  int q = row % kN;
  int lane = threadIdx.x & 63;
  int wv = threadIdx.x >> 6;
  for (int c0 = wv; c0 < 16; c0 += 4) {
    int k = c0 * 64 + lane;
    int m = edge_mask[(size_t)row * kN + k] + pad_mask[b * kN + k];
    unsigned long long bal = __ballot(m > 0);
    if (lane == 0) bits_t[((size_t)b * 16 + c0) * kN + q] = bal;
  }
}

__global__ __launch_bounds__(256) void pack_pad(
    const int* __restrict__ pad_mask, unsigned long long* __restrict__ bits) {
  int b = blockIdx.x;
  int lane = threadIdx.x & 63;
  int wv = threadIdx.x >> 6;
  for (int c0 = wv; c0 < 16; c0 += 4) {
    int k = c0 * 64 + lane;
    unsigned long long bal = __ballot(pad_mask[b * kN + k] > 0);
    if (lane == 0) bits[b * 16 + c0] = bal;
  }
}

__global__ __launch_bounds__(256) void init_proj(
    const float* __restrict__ ni, const float* __restrict__ W,
    const float* __restrict__ bias, float* __restrict__ x) {
  int i = blockIdx.x * 256 + threadIdx.x;  // r*128 + c
  int r = i >> 7, c = i & 127;
  float acc = bias[c];
#pragma unroll
  for (int k = 0; k < kIn; k++) acc = fmaf(ni[r * kIn + k], W[k * kD + c], acc);
  x[i] = acc;
}

// ---- tile32: K=128 GEMM, 32 rows x 128 cols, 8 rows x 2 cols per thread ----
// MODE 0: out row-major [R][Cfull]; MODE 2: QKV bhne out picked by blockIdx.y.
template <int LN, int RELU, int MODE>
__global__ __launch_bounds__(256) void tile32(
    const float* __restrict__ A, const float* __restrict__ Wg,
    const float* __restrict__ gamma, const float* __restrict__ beta,
    const float* __restrict__ bias, const float* __restrict__ resid,
    float* __restrict__ O0, float* __restrict__ O1, float* __restrict__ O2,
    int Cfull) {
  __shared__ float As[32][128];
  __shared__ float Ws[2][32][128];
  int r0 = blockIdx.x * 32;
  int y = blockIdx.y;
  const float* Wb;
  int wstride;
  if constexpr (MODE == 2) { Wb = Wg + (size_t)y * 128 * 128; wstride = 128; }
  else { Wb = Wg + (size_t)y * 128; wstride = Cfull; }

  if constexpr (LN) {
    int w = threadIdx.x >> 6, lane = threadIdx.x & 63;
#pragma unroll
    for (int i = 0; i < 8; i++) {
      int rr = w * 8 + i;
      const float* xr = A + (size_t)(r0 + rr) * 128;
      float2 v = *(const float2*)(xr + lane * 2);
      float mean = wredsum(v.x + v.y) * (1.0f / 128.f);
      float dx = v.x - mean, dy = v.y - mean;
      float var = wredsum(dx * dx + dy * dy) * (1.0f / 128.f);
      float rstd = rsqrtf(var + 1e-5f);
      int c = lane * 2;
      As[rr][c] = dx * rstd * gamma[c] + beta[c];
      As[rr][c + 1] = dy * rstd * gamma[c + 1] + beta[c + 1];
    }
  } else {
#pragma unroll
    for (int j = 0; j < 4; j++) {
      int idx = threadIdx.x + j * 256;   // 1024 float4s
      int row = idx >> 5, c4 = idx & 31;
      *(float4*)&As[row][c4 * 4] =
          *(const float4*)(A + (size_t)(r0 + row) * 128 + c4 * 4);
    }
  }

  int kk = threadIdx.x >> 3;
  int f8 = threadIdx.x & 7;
  float4 wreg[4];
  auto loadW = [&](int kc) {
    const float* Wrow = Wb + (size_t)(kc * 32 + kk) * wstride;
#pragma unroll
    for (int j = 0; j < 4; j++) wreg[j] = *(const float4*)(Wrow + (f8 + 8 * j) * 4);
  };
  auto writeW = [&](int buf) {
#pragma unroll
    for (int j = 0; j < 4; j++) *(float4*)&Ws[buf][kk][(f8 + 8 * j) * 4] = wreg[j];
  };

  loadW(0);
  writeW(0);

  int c0 = threadIdx.x & 63, rg = threadIdx.x >> 6;
  float acc[8][2] = {};
  for (int kc = 0; kc < 4; kc++) {
    if (kc + 1 < 4) loadW(kc + 1);
    __syncthreads();
#pragma unroll
    for (int k4 = 0; k4 < 8; k4++) {
      float4 av[8];
#pragma unroll
      for (int j = 0; j < 8; j++)
        av[j] = *(const float4*)&As[rg * 8 + j][kc * 32 + k4 * 4];
#pragma unroll
      for (int m = 0; m < 4; m++) {
        float w0 = Ws[kc & 1][k4 * 4 + m][c0];
        float w1 = Ws[kc & 1][k4 * 4 + m][c0 + 64];
#pragma unroll
        for (int j = 0; j < 8; j++) {
          float a = ((const float*)&av[j])[m];
          acc[j][0] = fmaf(a, w0, acc[j][0]);
          acc[j][1] = fmaf(a, w1, acc[j][1]);
        }
      }
    }
    if (kc + 1 < 4) writeW((kc + 1) & 1);
  }

#pragma unroll
  for (int cc = 0; cc < 2; cc++) {
    int c = c0 + cc * 64;
    int colg = y * 128 + c;
    float bv = bias ? bias[colg] : 0.f;
#pragma unroll
    for (int j = 0; j < 8; j++) {
      int r = r0 + rg * 8 + j;
      float v = acc[j][cc] + bv;
      if (resid) v += resid[(size_t)r * Cfull + colg];
      if (RELU) v = fmaxf(v, 0.f);
      if constexpr (MODE == 2) {
        int hh = c >> 4, e = c & 15;
        int bb = r >> 10, n = r & 1023;
        float* P = (y == 0) ? O0 : (y == 1) ? O1 : O2;
        P[(((size_t)(bb * kH + hh)) * kN + n) * kDK + e] = v;
      } else {
        O0[(size_t)r * Cfull + colg] = v;
      }
    }
  }
}

// ---- tile16: generic-K fp32 GEMM (FFN2 K=512; decoder Kp) ----
template <int K, int RELU>
__global__ __launch_bounds__(256) void tile16(
    const float* __restrict__ A, const float* __restrict__ Wg,
    const float* __restrict__ bias, const float* __restrict__ resid,
    float* __restrict__ O0, int Cfull) {
  __shared__ float As[16][K];
  __shared__ float Ws[2][32][128];
  constexpr int NC = K / 32;
  int r0 = blockIdx.x * 16;
  int y = blockIdx.y;
  const float* Wb = Wg + (size_t)y * 128;
  int wstride = Cfull;

  constexpr int NF4 = K / 4;
#pragma unroll
  for (int f = threadIdx.x; f < 16 * NF4; f += 256) {
    int row = f / NF4, c4 = f % NF4;
    *(float4*)&As[row][c4 * 4] =
        *(const float4*)(A + (size_t)(r0 + row) * K + c4 * 4);
  }

  int kk = threadIdx.x >> 3;
  int f8 = threadIdx.x & 7;
  float4 wreg[4];
  auto loadW = [&](int kc) {
    const float* Wrow = Wb + (size_t)(kc * 32 + kk) * wstride;
#pragma unroll
    for (int j = 0; j < 4; j++) wreg[j] = *(const float4*)(Wrow + (f8 + 8 * j) * 4);
  };
  auto writeW = [&](int buf) {
#pragma unroll
    for (int j = 0; j < 4; j++) *(float4*)&Ws[buf][kk][(f8 + 8 * j) * 4] = wreg[j];
  };

  loadW(0);
  writeW(0);

  int clocal = threadIdx.x & 127, rsel = threadIdx.x >> 7;
  float acc[8] = {};
  for (int kc = 0; kc < NC; kc++) {
    if (kc + 1 < NC) loadW(kc + 1);
    __syncthreads();
#pragma unroll
    for (int k4 = 0; k4 < 8; k4++) {
      float4 av[8];
#pragma unroll
      for (int j = 0; j < 8; j++)
        av[j] = *(const float4*)&As[rsel + 2 * j][kc * 32 + k4 * 4];
#pragma unroll
      for (int m = 0; m < 4; m++) {
        float w = Ws[kc & 1][k4 * 4 + m][clocal];
#pragma unroll
        for (int j = 0; j < 8; j++)
          acc[j] = fmaf(((const float*)&av[j])[m], w, acc[j]);
      }
    }
    if (kc + 1 < NC) writeW((kc + 1) & 1);
  }

  int colg = y * 128 + clocal;
  float bv = bias ? bias[colg] : 0.f;
#pragma unroll
  for (int j = 0; j < 8; j++) {
    int r = r0 + rsel + 2 * j;
    float v = acc[j] + bv;
    if (resid) v += resid[(size_t)r * Cfull + colg];
    if (RELU) v = fmaxf(v, 0.f);
    O0[(size_t)r * Cfull + colg] = v;
  }
}

// ---- flash attention (encoder) ----
__global__ __launch_bounds__(256) void attn_flash(
    const float* __restrict__ Q, const float* __restrict__ K,
    const float* __restrict__ V, const unsigned long long* __restrict__ bits_t,
    float* __restrict__ Hd) {
  __shared__ float Ks[4][64][16];
  __shared__ float Vs[4][64][16];
  __shared__ float Ms[4][64][20];
  int bh = blockIdx.x, qt = blockIdx.y;
  int b = bh >> 3, h = bh & 7;
  int w = threadIdx.x >> 6, lane = threadIdx.x & 63;
  int q = qt * 64 + lane;
  const float4* qp = (const float4*)(Q + ((size_t)bh * kN + q) * kDK);
  float4 q0 = qp[0], q1 = qp[1], q2 = qp[2], q3 = qp[3];
  const float* Kb = K + (size_t)bh * kN * kDK;
  const float* Vb = V + (size_t)bh * kN * kDK;
  float mx = -3.0e38f, l = 0.f;
  float acc[16];
#pragma unroll
  for (int e = 0; e < 16; e++) acc[e] = 0.f;
  for (int t = 0; t < 4; t++) {
    int kk = w * 256 + t * 64 + lane;
    const float4* kp = (const float4*)(Kb + (size_t)kk * kDK);
    float4 ka = kp[0], kbv = kp[1], kc = kp[2], kd = kp[3];
    const float4* vp = (const float4*)(Vb + (size_t)kk * kDK);
    float4 va = vp[0], vb = vp[1], vc = vp[2], vd = vp[3];
    unsigned long long mb = bits_t[((size_t)b * 16 + w * 4 + t) * kN + q];
    ((float4*)Ks[w][lane])[0] = ka; ((float4*)Ks[w][lane])[1] = kbv;
    ((float4*)Ks[w][lane])[2] = kc; ((float4*)Ks[w][lane])[3] = kd;
    ((float4*)Vs[w][lane])[0] = va; ((float4*)Vs[w][lane])[1] = vb;
    ((float4*)Vs[w][lane])[2] = vc; ((float4*)Vs[w][lane])[3] = vd;
#pragma unroll 4
    for (int k2 = 0; k2 < 64; k2++) {
      const float4* kr = (const float4*)Ks[w][k2];
      float4 k0 = kr[0], k1 = kr[1], k2v = kr[2], k3 = kr[3];
      float s = q0.x * k0.x + q0.y * k0.y + q0.z * k0.z + q0.w * k0.w
              + q1.x * k1.x + q1.y * k1.y + q1.z * k1.z + q1.w * k1.w
              + q2.x * k2v.x + q2.y * k2v.y + q2.z * k2v.z + q2.w * k2v.w
              + q3.x * k3.x + q3.y * k3.y + q3.z * k3.z + q3.w * k3.w;
      s *= 0.25f;
      if ((mb >> k2) & 1ull) s = -1e8f;
      float d = s - mx;
      if (d > 8.f) {
        float sc = __expf(-d);
        l *= sc;
#pragma unroll
        for (int e = 0; e < 16; e++) acc[e] *= sc;
        mx = s; d = 0.f;
      }
      float p = __expf(d);
      l += p;
      const float4* vr = (const float4*)Vs[w][k2];
      float4 v0 = vr[0], v1 = vr[1], v2 = vr[2], v3 = vr[3];
      acc[0] = fmaf(p, v0.x, acc[0]);   acc[1] = fmaf(p, v0.y, acc[1]);
      acc[2] = fmaf(p, v0.z, acc[2]);   acc[3] = fmaf(p, v0.w, acc[3]);
      acc[4] = fmaf(p, v1.x, acc[4]);   acc[5] = fmaf(p, v1.y, acc[5]);
      acc[6] = fmaf(p, v1.z, acc[6]);   acc[7] = fmaf(p, v1.w, acc[7]);
      acc[8] = fmaf(p, v2.x, acc[8]);   acc[9] = fmaf(p, v2.y, acc[9]);
      acc[10] = fmaf(p, v2.z, acc[10]); acc[11] = fmaf(p, v2.w, acc[11]);
      acc[12] = fmaf(p, v3.x, acc[12]); acc[13] = fmaf(p, v3.y, acc[13]);
      acc[14] = fmaf(p, v3.z, acc[14]); acc[15] = fmaf(p, v3.w, acc[15]);
    }
  }
  ((float4*)Ms[w][lane])[0] = make_float4(acc[0], acc[1], acc[2], acc[3]);
  ((float4*)Ms[w][lane])[1] = make_float4(acc[4], acc[5], acc[6], acc[7]);
  ((float4*)Ms[w][lane])[2] = make_float4(acc[8], acc[9], acc[10], acc[11]);
  ((float4*)Ms[w][lane])[3] = make_float4(acc[12], acc[13], acc[14], acc[15]);
  Ms[w][lane][16] = mx;
  Ms[w][lane][17] = l;
  __syncthreads();
  float m0 = Ms[0][lane][16], m1 = Ms[1][lane][16];
  float m2 = Ms[2][lane][16], m3 = Ms[3][lane][16];
  float mstar = fmaxf(fmaxf(m0, m1), fmaxf(m2, m3));
  float f0 = __expf(m0 - mstar), f1 = __expf(m1 - mstar);
  float f2 = __expf(m2 - mstar), f3 = __expf(m3 - mstar);
  float L = f0 * Ms[0][lane][17] + f1 * Ms[1][lane][17] +
            f2 * Ms[2][lane][17] + f3 * Ms[3][lane][17];
  float invL = 1.0f / L;
  float o[4];
#pragma unroll
  for (int e = 0; e < 4; e++) {
    int ei = w * 4 + e;
    o[e] = (f0 * Ms[0][lane][ei] + f1 * Ms[1][lane][ei] +
            f2 * Ms[2][lane][ei] + f3 * Ms[3][lane][ei]) * invL;
  }
  *(float4*)(Hd + ((size_t)(b * kN + q)) * kD + h * kDK + w * 4) =
      make_float4(o[0], o[1], o[2], o[3]);
}

// ==== decoder (algebraic: K/V never materialized) ====

__global__ __launch_bounds__(256) void dec_prep(
    const float* __restrict__ enh, const int* __restrict__ tgt_idx,
    const int* __restrict__ cur_idx, const int* __restrict__ cen_idx,
    const float* __restrict__ Wq,
    const float* __restrict__ ln1_g, const float* __restrict__ ln1_b,
    const float* __restrict__ dec_wk,
    float* __restrict__ out_curf, float* __restrict__ out_cenf,
    float* __restrict__ tgtf_ws, float* __restrict__ qk_ws) {
  __shared__ float tgtf_s[128], tgtn[128], qd[128];
  int b = blockIdx.x, t = threadIdx.x;
  int lane = t & 63, w = t >> 6;
  int ti = tgt_idx[b], cui = cur_idx[b];
  if (t < 128) {
    float tf = enh[((size_t)b * kN + ti) * kD + t];
    tgtf_s[t] = tf;
    tgtf_ws[b * kD + t] = tf;
    out_curf[b * kD + t] = enh[((size_t)b * kN + cui) * kD + t];
  }
  for (int i = t; i < kNC * kD; i += 256) {
    int c = i >> 7, e = i & 127;
    out_cenf[((size_t)b * kNC + c) * kD + e] =
        enh[((size_t)b * kN + cen_idx[b * kNC + c]) * kD + e];
  }
  __syncthreads();
  if (w == 0) {
    float vx = tgtf_s[lane * 2], vy = tgtf_s[lane * 2 + 1];
    float mean = wredsum(vx + vy) * (1.0f / 128.f);
    float dx = vx - mean, dy = vy - mean;
    float var = wredsum(dx * dx + dy * dy) * (1.0f / 128.f);
    float rstd = rsqrtf(var + 1e-5f);
    tgtn[lane * 2] = dx * rstd * ln1_g[lane * 2] + ln1_b[lane * 2];
    tgtn[lane * 2 + 1] = dy * rstd * ln1_g[lane * 2 + 1] + ln1_b[lane * 2 + 1];
  }
  __syncthreads();
  if (t < 128) {
    float a = 0.f;
#pragma unroll 8
    for (int k = 0; k < 128; k++) a = fmaf(tgtn[k], Wq[k * 128 + t], a);
    qd[t] = a;
  }
  __syncthreads();
  int h = t >> 5, d0 = (t & 31) * 4;
#pragma unroll
  for (int j = 0; j < 4; j++) {
    int d = d0 + j;
    const float4* wp = (const float4*)(dec_wk + (((size_t)h * 128 + d) << 4));
    float a = 0.f;
#pragma unroll
    for (int r = 0; r < 4; r++) {
      float4 wv = wp[r];
      a += wv.x * qd[h * 16 + r * 4] + wv.y * qd[h * 16 + r * 4 + 1] +
           wv.z * qd[h * 16 + r * 4 + 2] + wv.w * qd[h * 16 + r * 4 + 3];
    }
    qk_ws[b * 1024 + h * 128 + d] = 0.25f * a;
  }
}

__global__ __launch_bounds__(256) void dec_score(
    const float* __restrict__ enh, const float* __restrict__ ln_g,
    const float* __restrict__ ln_b, const float* __restrict__ qk_ws,
    const unsigned long long* __restrict__ padbits,
    float* __restrict__ ln_ws, float* __restrict__ scores) {
  __shared__ float qs[8][128];
  int b = blockIdx.x, nt = blockIdx.y, t = threadIdx.x;
  for (int i = t; i < 1024; i += 256) ((float*)qs)[i] = qk_ws[b * 1024 + i];
  __syncthreads();
  int w = t >> 6, lane = t & 63, ri = lane >> 2, q4 = lane & 3;
  int n = nt * 64 + w * 16 + ri;
  const float* row = enh + ((size_t)b * kN + n) * kD;
  float4 xv[8];
#pragma unroll
  for (int j = 0; j < 8; j++) xv[j] = *(const float4*)(row + j * 16 + q4 * 4);
  float s1 = 0.f;
#pragma unroll
  for (int j = 0; j < 8; j++) s1 += xv[j].x + xv[j].y + xv[j].z + xv[j].w;
  s1 = red4(s1);
  float mean = s1 * (1.0f / 128.f);
  float s2 = 0.f;
#pragma unroll
  for (int j = 0; j < 8; j++) {
    xv[j].x -= mean; xv[j].y -= mean; xv[j].z -= mean; xv[j].w -= mean;
    s2 += xv[j].x * xv[j].x + xv[j].y * xv[j].y + xv[j].z * xv[j].z +
          xv[j].w * xv[j].w;
  }
  s2 = red4(s2);
  float rstd = rsqrtf(s2 * (1.0f / 128.f) + 1e-5f);
#pragma unroll
  for (int j = 0; j < 8; j++) {
    int d0 = j * 16 + q4 * 4;
    float4 g = *(const float4*)(ln_g + d0);
    float4 be = *(const float4*)(ln_b + d0);
    xv[j].x = xv[j].x * rstd * g.x + be.x;
    xv[j].y = xv[j].y * rstd * g.y + be.y;
    xv[j].z = xv[j].z * rstd * g.z + be.z;
    xv[j].w = xv[j].w * rstd * g.w + be.w;
    *(float4*)(ln_ws + ((size_t)b * kN + n) * kD + d0) = xv[j];
  }
  bool mk = (padbits[b * 16 + (n >> 6)] >> (n & 63)) & 1ull;
#pragma unroll
  for (int h = 0; h < 8; h++) {
    float p = 0.f;
#pragma unroll
    for (int j = 0; j < 8; j++) {
      float4 qv = *(const float4*)&qs[h][j * 16 + q4 * 4];
      p += xv[j].x * qv.x + xv[j].y * qv.y + xv[j].z * qv.z + xv[j].w * qv.w;
    }
    p = red4(p);
    if (q4 == 0) scores[((size_t)b * 8 + h) * 1024 + n] = mk ? -1e8f : p;
  }
}

__global__ __launch_bounds__(256) void dec_softmax(
    const float* __restrict__ scores, float* __restrict__ ml) {
  int b = blockIdx.x, t = threadIdx.x, w = t >> 6, lane = t & 63;
  for (int hi = 0; hi < 2; hi++) {
    int h = w + hi * 4;
    const float* sr = scores + ((size_t)b * 8 + h) * 1024;
    float v[16];
    float m = -3.0e38f;
#pragma unroll
    for (int i = 0; i < 16; i++) { v[i] = sr[i * 64 + lane]; m = fmaxf(m, v[i]); }
    m = wredmax(m);
    float l = 0.f;
#pragma unroll
    for (int i = 0; i < 16; i++) l += __expf(v[i] - m);
    l = wredsum(l);
    if (lane == 0) { ml[(b * 8 + h) * 2] = m; ml[(b * 8 + h) * 2 + 1] = l; }
  }
}

__global__ __launch_bounds__(256) void dec_attnsum(
    const float* __restrict__ ln_ws, const float* __restrict__ scores,
    const float* __restrict__ ml, float* __restrict__ partial) {
  __shared__ float lns[64][128];
  __shared__ float ps[8][64];
  int b = blockIdx.x, nt = blockIdx.y, t = threadIdx.x;
  for (int i = t; i < 64 * 32; i += 256) {
    int nn = i >> 5, c4 = i & 31;
    *(float4*)&lns[nn][c4 * 4] =
        *(const float4*)(ln_ws + ((size_t)b * kN + nt * 64 + nn) * kD + c4 * 4);
  }
  for (int i = t; i < 512; i += 256) {
    int h = i >> 6, nn = i & 63;
    float m = ml[(b * 8 + h) * 2], l = ml[(b * 8 + h) * 2 + 1];
    ps[h][nn] =
        __expf(scores[((size_t)b * 8 + h) * 1024 + nt * 64 + nn] - m) / l;
  }
  __syncthreads();
  int h = t >> 5, d0 = (t & 31) * 4;
  float4 acc = make_float4(0.f, 0.f, 0.f, 0.f);
  for (int nn = 0; nn < 64; nn++) {
    float p = ps[h][nn];
    float4 lv = *(const float4*)&lns[nn][d0];
    acc.x = fmaf(p, lv.x, acc.x); acc.y = fmaf(p, lv.y, acc.y);
    acc.z = fmaf(p, lv.z, acc.z); acc.w = fmaf(p, lv.w, acc.w);
  }
  *(float4*)(partial + ((size_t)(b * 16 + nt) * 8 + h) * 128 + d0) = acc;
}

// dec_tail: 1024 threads, parallel-k matvecs via LDS partial reduce
__global__ __launch_bounds__(1024) void dec_tail(
    const float* __restrict__ partial, const float* __restrict__ dec_wv,
    const float* __restrict__ dwo, const float* __restrict__ tgtf_ws,
    const float* __restrict__ cenf_g, const float* __restrict__ Kp,
    const int* __restrict__ cen_idx, const int* __restrict__ center_mask,
    const float* __restrict__ ln2_g, const float* __restrict__ ln2_b,
    const float* __restrict__ w1, const float* __restrict__ b1,
    const float* __restrict__ w2, const float* __restrict__ b2,
    const float* __restrict__ tgt_W, const float* __restrict__ tgt_b,
    const float* __restrict__ ptr_wq,
    float* __restrict__ out_selidx, float* __restrict__ out_selfeat,
    float* __restrict__ out_logp) {
  __shared__ float wsum[8][132];
  __shared__ float red[8][132];
  __shared__ float red2[2][520];
  __shared__ float red16[16][68];
  __shared__ float tgtf[128], hdd[128], dechs[128], decfs[128], dects[512],
                   embs[128], qps[128];
  __shared__ int bi_s;
  int b = blockIdx.x, t = threadIdx.x;
  int c = t & 127, p = t >> 7;          // 8 parts x 128 cols
  int lane = t & 63, w = t >> 6;

  // phase 0: wsum combine (h=p, d=c) + tgtf load
  {
    float a = 0.f;
#pragma unroll
    for (int tt = 0; tt < 16; tt++)
      a += partial[((size_t)(b * 16 + tt) * 8 + p) * 128 + c];
    wsum[p][c] = a;
    if (t < 128) tgtf[t] = tgtf_ws[b * kD + t];
  }
  __syncthreads();

  // phase 1: hdd[c] = sum_d wsum[h][d] * dec_wv[(h*128+d)*16+e],  c=(h,e)
  {
    int h = c >> 4, e = c & 15;
    float a = 0.f;
#pragma unroll
    for (int i = 0; i < 16; i++) {
      int d = p * 16 + i;
      a = fmaf(wsum[h][d], dec_wv[((size_t)h * 128 + d) * 16 + e], a);
    }
    red[p][c] = a;
  }
  __syncthreads();
  if (t < 128) {
    float a = 0.f;
#pragma unroll
    for (int q = 0; q < 8; q++) a += red[q][t];
    hdd[t] = a;
  }
  __syncthreads();

  // phase 2: dechs = hdd @ dwo + tgtf
  {
    float a = 0.f;
#pragma unroll
    for (int i = 0; i < 16; i++) {
      int k = p * 16 + i;
      a = fmaf(hdd[k], dwo[k * 128 + c], a);
    }
    red[p][c] = a;
  }
  __syncthreads();
  if (t < 128) {
    float a = 0.f;
#pragma unroll
    for (int q = 0; q < 8; q++) a += red[q][t];
    dechs[t] = a + tgtf[t];
  }
  __syncthreads();

  // phase 3: LN2 (wave 0)
  if (w == 0) {
    float vx = dechs[lane * 2], vy = dechs[lane * 2 + 1];
    float mean = wredsum(vx + vy) * (1.0f / 128.f);
    float dx = vx - mean, dy = vy - mean;
    float var = wredsum(dx * dx + dy * dy) * (1.0f / 128.f);
    float rstd = rsqrtf(var + 1e-5f);
    decfs[lane * 2] = dx * rstd * ln2_g[lane * 2] + ln2_b[lane * 2];
    decfs[lane * 2 + 1] = dy * rstd * ln2_g[lane * 2 + 1] + ln2_b[lane * 2 + 1];
  }
  __syncthreads();

  // phase 4: FFN1 (relu): c5 = t&511, p2 = t>>9 (2 parts x 64 k)
  {
    int c5 = t & 511, p2 = t >> 9;
    float a = 0.f;
#pragma unroll 8
    for (int i = 0; i < 64; i++) {
      int k = p2 * 64 + i;
      a = fmaf(decfs[k], w1[k * 512 + c5], a);
    }
    red2[p2][c5] = a;
  }
  __syncthreads();
  if (t < 512) dects[t] = fmaxf(red2[0][t] + red2[1][t] + b1[t], 0.f);
  __syncthreads();

  // phase 5: FFN2 + resid -> enh_tgt (decfs)
  {
    float a = 0.f;
#pragma unroll 8
    for (int i = 0; i < 64; i++) {
      int k = p * 64 + i;
      a = fmaf(dects[k], w2[k * 128 + c], a);
    }
    red[p][c] = a;
  }
  __syncthreads();
  if (t < 128) {
    float a = 0.f;
#pragma unroll
    for (int q = 0; q < 8; q++) a += red[q][t];
    decfs[t] = a + b2[t] + dechs[t];
  }
  __syncthreads();

  // phase 6: emb = [enh_tgt; tgtf] @ tgt_W + tgt_b  (K=256, p covers 32)
  {
    float a = 0.f;
#pragma unroll
    for (int i = 0; i < 32; i++) {
      int k = p * 32 + i;
      float vkk = (k < 128) ? decfs[k] : tgtf[k - 128];
      a = fmaf(vkk, tgt_W[k * 128 + c], a);
    }
    red[p][c] = a;
  }
  __syncthreads();
  if (t < 128) {
    float a = 0.f;
#pragma unroll
    for (int q = 0; q < 8; q++) a += red[q][t];
    embs[t] = a + tgt_b[t];
  }
  __syncthreads();

  // phase 7: qps = emb @ ptr_wq
  {
    float a = 0.f;
#pragma unroll
    for (int i = 0; i < 16; i++) {
      int k = p * 16 + i;
      a = fmaf(embs[k], ptr_wq[k * 128 + c], a);
    }
    red[p][c] = a;
  }
  __syncthreads();
  if (t < 128) {
    float a = 0.f;
#pragma unroll
    for (int q = 0; q < 8; q++) a += red[q][t];
    qps[t] = a;
  }
  __syncthreads();

  // phase 8: logits u[cen] = qps . Kp[b*64+cen]  (16 parts x 8 k)
  {
    int cen = t & 63, p16 = t >> 6;
    float a = 0.f;
#pragma unroll
    for (int i = 0; i < 8; i++) {
      int k = p16 * 8 + i;
      a = fmaf(qps[k], Kp[((size_t)(b * kNC + cen)) * kD + k], a);
    }
    red16[p16][cen] = a;
  }
  __syncthreads();
  if (w == 0) {
    float u = 0.f;
#pragma unroll
    for (int q = 0; q < 16; q++) u += red16[q][lane];
    u *= 0.08838834764831845f;
    u = 10.0f * tanhf(u);
    if (center_mask[b * kNC + lane] == 1) u = -1e8f;
    float m = wredmax(u);
    float ex = __expf(u - m);
    float sum = wredsum(ex);
    out_logp[b * kNC + lane] = u - m - logf(sum);
    float bm = u; int bi = lane;
#pragma unroll
    for (int o = 32; o; o >>= 1) {
      float om = __shfl_xor(bm, o);
      int oi = __shfl_xor(bi, o);
      if (om > bm || (om == bm && oi < bi)) { bm = om; bi = oi; }
    }
    if (lane == 0) {
      out_selidx[b] = (float)cen_idx[b * kNC + bi];
      bi_s = bi;
    }
  }
  __syncthreads();
  if (t < 128)
    out_selfeat[b * kD + t] = cenf_g[((size_t)(b * kNC + bi_s)) * kD + t];
}

// ---- host ----

extern "C" void kernel_launch(void* const* d_in, const int* in_sizes, int n_in,
                              void* d_out, int out_size, void* d_ws,
                              size_t ws_size, hipStream_t stream) {
  (void)in_sizes; (void)n_in; (void)out_size; (void)ws_size;
  const float* node_inputs = (const float*)d_in[0];
  const int* pad_mask = (const int*)d_in[1];
  const int* edge_mask = (const int*)d_in[2];
  const int* center_mask = (const int*)d_in[3];
  const int* center_index = (const int*)d_in[4];
  const int* target_index = (const int*)d_in[5];
  const int* current_index = (const int*)d_in[6];
  const float* init_W = (const float*)d_in[8];
  const float* init_b = (const float*)d_in[9];
  const float* enc_wq = (const float*)d_in[10];
  const float* enc_wk = (const float*)d_in[11];
  const float* enc_wv = (const float*)d_in[12];
  const float* enc_wo = (const float*)d_in[13];
  const float* enc_ln1_g = (const float*)d_in[14];
  const float* enc_ln1_b = (const float*)d_in[15];
  const float* enc_w1 = (const float*)d_in[16];
  const float* enc_b1 = (const float*)d_in[17];
  const float* enc_w2 = (const float*)d_in[18];
  const float* enc_b2 = (const float*)d_in[19];
  const float* enc_ln2_g = (const float*)d_in[20];
  const float* enc_ln2_b = (const float*)d_in[21];
  const float* dec_wq = (const float*)d_in[22];
  const float* dec_wk = (const float*)d_in[23];
  const float* dec_wv = (const float*)d_in[24];
  const float* dec_wo = (const float*)d_in[25];
  const float* dec_ln1_g = (const float*)d_in[26];
  const float* dec_ln1_b = (const float*)d_in[27];
  const float* dec_w1 = (const float*)d_in[28];
  const float* dec_b1 = (const float*)d_in[29];
  const float* dec_w2 = (const float*)d_in[30];
  const float* dec_b2 = (const float*)d_in[31];
  const float* dec_ln2_g = (const float*)d_in[32];
  const float* dec_ln2_b = (const float*)d_in[33];
  const float* tgt_W = (const float*)d_in[34];
  const float* tgt_b = (const float*)d_in[35];
  const float* ptr_wq = (const float*)d_in[36];
  const float* ptr_wk = (const float*)d_in[37];

  float* out_enh = (float*)d_out;
  float* out_curf = out_enh + kB * kN * kD;
  float* out_selidx = out_curf + kB * kD;
  float* out_selfeat = out_selidx + kB;
  float* out_logp = out_selfeat + kB * kD;
  float* out_cenf = out_logp + kB * kNC;

  char* wsp = (char*)d_ws;
  size_t off = 0;
  auto alloc = [&](size_t n) {
    char* p = wsp + off;
    off = (off + n + 255) & ~(size_t)255;
    return p;
  };
  float* x   = (float*)alloc(kR * kD * 4);
  float* h2  = (float*)alloc(kR * kD * 4);
  float* Qb  = (float*)alloc(kR * kD * 4);
  float* Kb  = (float*)alloc(kR * kD * 4);
  float* Vb  = (float*)alloc(kR * kD * 4);
  float* Hd  = (float*)alloc(kR * kD * 4);
  float* tb  = (float*)alloc(kR * kFF * 4);
  unsigned long long* bits_t  = (unsigned long long*)alloc(kR * 16 * 8);
  unsigned long long* padbits = (unsigned long long*)alloc(kB * 16 * 8);
  float* ewqkv = (float*)alloc(kEnc * 3 * kD * kD * 4);
  float* dqkvW = (float*)alloc(3 * kD * kD * 4);
  float* ln_ws = (float*)alloc(kR * kD * 4);
  float* scores_ws = (float*)alloc(kB * kH * kN * 4);
  float* ml_ws = (float*)alloc(kB * kH * 2 * 4);
  float* partial_ws = (float*)alloc(kB * 16 * kH * kD * 4);
  float* qk_ws = (float*)alloc(kB * kH * kD * 4);
  float* tgtf_ws = (float*)alloc(kB * kD * 4);
  float* Kp_ws = (float*)alloc(kB * kNC * kD * 4);

  // prologue
  repack_qkv<<<(kEnc * kD * kD + 255) / 256, 256, 0, stream>>>(
      enc_wq, enc_wk, enc_wv, ewqkv, kEnc);
  repack_qkv<<<(kD * kD + 255) / 256, 256, 0, stream>>>(
      dec_wq, dec_wk, dec_wv, dqkvW, 1);
  pack_mask<<<kB * kN, 256, 0, stream>>>(edge_mask, pad_mask, bits_t);
  pack_pad<<<kB, 256, 0, stream>>>(pad_mask, padbits);
  init_proj<<<kR * kD / 256, 256, 0, stream>>>(node_inputs, init_W, init_b, x);

  // encoder
  for (int l = 0; l < kEnc; l++) {
    const float* wo_l = enc_wo + (size_t)l * kH * kDK * kD;
    tile32<1, 0, 2><<<dim3(kR / 32, 3), 256, 0, stream>>>(
        x, ewqkv + (size_t)l * 3 * kD * kD, enc_ln1_g + l * kD,
        enc_ln1_b + l * kD, nullptr, nullptr, Qb, Kb, Vb, kD);
    attn_flash<<<dim3(kB * kH, kN / 64), 256, 0, stream>>>(Qb, Kb, Vb, bits_t, Hd);
    tile32<0, 0, 0><<<dim3(kR / 32, 1), 256, 0, stream>>>(
        Hd, wo_l, nullptr, nullptr, nullptr, x, h2, nullptr, nullptr, kD);
    tile32<1, 1, 0><<<dim3(kR / 32, kFF / 128), 256, 0, stream>>>(
        h2, enc_w1 + (size_t)l * kD * kFF, enc_ln2_g + l * kD,
        enc_ln2_b + l * kD, enc_b1 + l * kFF, nullptr, tb, nullptr, nullptr, kFF);
    float* xout = (l == kEnc - 1) ? out_enh : x;
    tile16<512, 0><<<dim3(kR / 16, 1), 256, 0, stream>>>(
        tb, enc_w2 + (size_t)l * kFF * kD, enc_b2 + l * kD, h2, xout, kD);
  }

  // decoder (algebraic)
  dec_prep<<<kB, 256, 0, stream>>>(out_enh, target_index, current_index,
                                   center_index, dqkvW, dec_ln1_g, dec_ln1_b,
                                   dec_wk, out_curf, out_cenf, tgtf_ws, qk_ws);
  tile16<128, 0><<<dim3(kB * kNC / 16, 1), 256, 0, stream>>>(
      out_cenf, ptr_wk, nullptr, nullptr, Kp_ws, kD);
  dec_score<<<dim3(kB, 16), 256, 0, stream>>>(out_enh, dec_ln1_g, dec_ln1_b,
                                              qk_ws, padbits, ln_ws, scores_ws);
  dec_softmax<<<kB, 256, 0, stream>>>(scores_ws, ml_ws);
  dec_attnsum<<<dim3(kB, 16), 256, 0, stream>>>(ln_ws, scores_ws, ml_ws,
                                                partial_ws);
  dec_tail<<<kB, 1024, 0, stream>>>(
      partial_ws, dec_wv, dec_wo, tgtf_ws, out_cenf, Kp_ws, center_index,
      center_mask, dec_ln2_g, dec_ln2_b, dec_w1, dec_b1, dec_w2, dec_b2,
      tgt_W, tgt_b, ptr_wq, out_selidx, out_selfeat, out_logp);
}

// Round 8
// 1138.625 us; speedup vs baseline: 3.4982x; 1.1494x over previous
//
#include <hip/hip_runtime.h>

constexpr int kB = 4, kN = 1024, kIn = 8, kD = 128, kH = 8, kNC = 64,
              kDK = 16, kFF = 512, kEnc = 6, kR = kB * kN;

__device__ __forceinline__ float wredsum(float v) {
  v += __shfl_xor(v, 1);  v += __shfl_xor(v, 2);  v += __shfl_xor(v, 4);
  v += __shfl_xor(v, 8);  v += __shfl_xor(v, 16); v += __shfl_xor(v, 32);
  return v;
}
__device__ __forceinline__ float wredmax(float v) {
  v = fmaxf(v, __shfl_xor(v, 1));  v = fmaxf(v, __shfl_xor(v, 2));
  v = fmaxf(v, __shfl_xor(v, 4));  v = fmaxf(v, __shfl_xor(v, 8));
  v = fmaxf(v, __shfl_xor(v, 16)); v = fmaxf(v, __shfl_xor(v, 32));
  return v;
}
__device__ __forceinline__ float red4(float v) {
  v += __shfl_xor(v, 1);  v += __shfl_xor(v, 2);
  return v;
}

// ---- prologue kernels ----

__global__ __launch_bounds__(256) void repack_qkv(
    const float* __restrict__ wq, const float* __restrict__ wk,
    const float* __restrict__ wv, float* __restrict__ out, int layers) {
  int i = blockIdx.x * 256 + threadIdx.x;
  if (i >= layers * kD * kD) return;
  int l = i / (kD * kD);
  int rem = i - l * kD * kD;
  int d = rem >> 7;
  int c = rem & 127;
  int src = ((l * kH + (c >> 4)) * kD + d) * kDK + (c & 15);
  out[(size_t)(l * 3 + 0) * 16384 + rem] = wq[src];
  out[(size_t)(l * 3 + 1) * 16384 + rem] = wk[src];
  out[(size_t)(l * 3 + 2) * 16384 + rem] = wv[src];
}

__global__ __launch_bounds__(256) void pack_mask(
    const int* __restrict__ edge_mask, const int* __restrict__ pad_mask,
    unsigned long long* __restrict__ bits_t) {
  int row = blockIdx.x;  // b*N + q
  int b = row / kN;
  int q = row % kN;
  int lane = threadIdx.x & 63;
  int wv = threadIdx.x >> 6;
  for (int c0 = wv; c0 < 16; c0 += 4) {
    int k = c0 * 64 + lane;
    int m = edge_mask[(size_t)row * kN + k] + pad_mask[b * kN + k];
    unsigned long long bal = __ballot(m > 0);
    if (lane == 0) bits_t[((size_t)b * 16 + c0) * kN + q] = bal;
  }
}

__global__ __launch_bounds__(256) void pack_pad(
    const int* __restrict__ pad_mask, unsigned long long* __restrict__ bits) {
  int b = blockIdx.x;
  int lane = threadIdx.x & 63;
  int wv = threadIdx.x >> 6;
  for (int c0 = wv; c0 < 16; c0 += 4) {
    int k = c0 * 64 + lane;
    unsigned long long bal = __ballot(pad_mask[b * kN + k] > 0);
    if (lane == 0) bits[b * 16 + c0] = bal;
  }
}

__global__ __launch_bounds__(256) void init_proj(
    const float* __restrict__ ni, const float* __restrict__ W,
    const float* __restrict__ bias, float* __restrict__ x) {
  int i = blockIdx.x * 256 + threadIdx.x;  // r*128 + c
  int r = i >> 7, c = i & 127;
  float acc = bias[c];
#pragma unroll
  for (int k = 0; k < kIn; k++) acc = fmaf(ni[r * kIn + k], W[k * kD + c], acc);
  x[i] = acc;
}

// ---- gtile: fp32 GEMM, TR rows x 128 cols per block, W chunk-streamed with
// conflict-free lane-linear LDS staging, double-buffered.
// MODE 0: out row-major [R][Cfull]; MODE 2: QKV bhne out picked by blockIdx.y.
template <int K, int TR, int LN, int RELU, int MODE>
__global__ __launch_bounds__(256) void gtile(
    const float* __restrict__ A, const float* __restrict__ Wg,
    const float* __restrict__ gamma, const float* __restrict__ beta,
    const float* __restrict__ bias, const float* __restrict__ resid,
    float* __restrict__ O0, float* __restrict__ O1, float* __restrict__ O2,
    int Cfull) {
  __shared__ float As[TR][K];
  __shared__ float Ws[2][32][128];
  constexpr int NC = K / 32;
  constexpr int RPT = TR / 2;  // rows per thread
  int r0 = blockIdx.x * TR;
  int y = blockIdx.y;
  const float* Wb;
  int wstride;
  if constexpr (MODE == 2) { Wb = Wg + (size_t)y * K * 128; wstride = 128; }
  else { Wb = Wg + (size_t)y * 128; wstride = Cfull; }

  // ---- stage A (opt fused LN) ----
  if constexpr (LN) {
    static_assert(K == 128, "LN requires K==128");
    int w = threadIdx.x >> 6, lane = threadIdx.x & 63;
#pragma unroll
    for (int i = 0; i < TR / 4; i++) {
      int rr = w * (TR / 4) + i;
      const float* xr = A + (size_t)(r0 + rr) * 128;
      float2 v = *(const float2*)(xr + lane * 2);
      float mean = wredsum(v.x + v.y) * (1.0f / 128.f);
      float dx = v.x - mean, dy = v.y - mean;
      float var = wredsum(dx * dx + dy * dy) * (1.0f / 128.f);
      float rstd = rsqrtf(var + 1e-5f);
      int c = lane * 2;
      As[rr][c] = dx * rstd * gamma[c] + beta[c];
      As[rr][c + 1] = dy * rstd * gamma[c + 1] + beta[c + 1];
    }
  } else {
    constexpr int NF4 = K / 4;
#pragma unroll
    for (int f = threadIdx.x; f < TR * NF4; f += 256) {
      int row = f / NF4, c4 = f % NF4;
      *(float4*)&As[row][c4 * 4] =
          *(const float4*)(A + (size_t)(r0 + row) * K + c4 * 4);
    }
  }

  // W staging: thread t -> rows (t>>5)+8j (j=0..3), cols (t&31)*4..+3
  // global: 2 consecutive rows per wave, coalesced 16B/lane
  // LDS: 64 consecutive float4 per wave -> conflict-free b128 write
  int wrow = threadIdx.x >> 5;     // 0..7
  int wc4 = threadIdx.x & 31;      // 0..31
  float4 wreg[4];
  auto loadW = [&](int kc) {
    const float* Wr = Wb + (size_t)(kc * 32 + wrow) * wstride + wc4 * 4;
#pragma unroll
    for (int j = 0; j < 4; j++)
      wreg[j] = *(const float4*)(Wr + (size_t)8 * j * wstride);
  };
  auto writeW = [&](int buf) {
#pragma unroll
    for (int j = 0; j < 4; j++)
      *(float4*)&Ws[buf][wrow + 8 * j][wc4 * 4] = wreg[j];
  };

  loadW(0);
  writeW(0);

  int clocal = threadIdx.x & 127, rsel = threadIdx.x >> 7;
  float acc[RPT] = {};
  for (int kc = 0; kc < NC; kc++) {
    if (kc + 1 < NC) loadW(kc + 1);
    __syncthreads();
#pragma unroll
    for (int k4 = 0; k4 < 8; k4++) {
      float4 av[RPT];
#pragma unroll
      for (int j = 0; j < RPT; j++)
        av[j] = *(const float4*)&As[rsel + 2 * j][kc * 32 + k4 * 4];
#pragma unroll
      for (int m = 0; m < 4; m++) {
        float w = Ws[kc & 1][k4 * 4 + m][clocal];
#pragma unroll
        for (int j = 0; j < RPT; j++)
          acc[j] = fmaf(((const float*)&av[j])[m], w, acc[j]);
      }
    }
    if (kc + 1 < NC) writeW((kc + 1) & 1);
  }

  // ---- epilogue ----
  int colg = y * 128 + clocal;
  float bv = bias ? bias[colg] : 0.f;
#pragma unroll
  for (int j = 0; j < RPT; j++) {
    int r = r0 + rsel + 2 * j;
    float v = acc[j] + bv;
    if (resid) v += resid[(size_t)r * Cfull + colg];
    if (RELU) v = fmaxf(v, 0.f);
    if constexpr (MODE == 2) {
      int hh = clocal >> 4, e = clocal & 15;
      int bb = r >> 10, n = r & 1023;
      float* P = (y == 0) ? O0 : (y == 1) ? O1 : O2;
      P[(((size_t)(bb * kH + hh)) * kN + n) * kDK + e] = v;
    } else {
      O0[(size_t)r * Cfull + colg] = v;
    }
  }
}

// ---- flash attention (encoder) ----
__global__ __launch_bounds__(256) void attn_flash(
    const float* __restrict__ Q, const float* __restrict__ K,
    const float* __restrict__ V, const unsigned long long* __restrict__ bits_t,
    float* __restrict__ Hd) {
  __shared__ float Ks[4][64][16];
  __shared__ float Vs[4][64][16];
  __shared__ float Ms[4][64][20];
  int bh = blockIdx.x, qt = blockIdx.y;
  int b = bh >> 3, h = bh & 7;
  int w = threadIdx.x >> 6, lane = threadIdx.x & 63;
  int q = qt * 64 + lane;
  const float4* qp = (const float4*)(Q + ((size_t)bh * kN + q) * kDK);
  float4 q0 = qp[0], q1 = qp[1], q2 = qp[2], q3 = qp[3];
  const float* Kb = K + (size_t)bh * kN * kDK;
  const float* Vb = V + (size_t)bh * kN * kDK;
  float mx = -3.0e38f, l = 0.f;
  float acc[16];
#pragma unroll
  for (int e = 0; e < 16; e++) acc[e] = 0.f;
  for (int t = 0; t < 4; t++) {
    int kk = w * 256 + t * 64 + lane;
    const float4* kp = (const float4*)(Kb + (size_t)kk * kDK);
    float4 ka = kp[0], kbv = kp[1], kc = kp[2], kd = kp[3];
    const float4* vp = (const float4*)(Vb + (size_t)kk * kDK);
    float4 va = vp[0], vb = vp[1], vc = vp[2], vd = vp[3];
    unsigned long long mb = bits_t[((size_t)b * 16 + w * 4 + t) * kN + q];
    ((float4*)Ks[w][lane])[0] = ka; ((float4*)Ks[w][lane])[1] = kbv;
    ((float4*)Ks[w][lane])[2] = kc; ((float4*)Ks[w][lane])[3] = kd;
    ((float4*)Vs[w][lane])[0] = va; ((float4*)Vs[w][lane])[1] = vb;
    ((float4*)Vs[w][lane])[2] = vc; ((float4*)Vs[w][lane])[3] = vd;
#pragma unroll 4
    for (int k2 = 0; k2 < 64; k2++) {
      const float4* kr = (const float4*)Ks[w][k2];
      float4 k0 = kr[0], k1 = kr[1], k2v = kr[2], k3 = kr[3];
      float s = q0.x * k0.x + q0.y * k0.y + q0.z * k0.z + q0.w * k0.w
              + q1.x * k1.x + q1.y * k1.y + q1.z * k1.z + q1.w * k1.w
              + q2.x * k2v.x + q2.y * k2v.y + q2.z * k2v.z + q2.w * k2v.w
              + q3.x * k3.x + q3.y * k3.y + q3.z * k3.z + q3.w * k3.w;
      s *= 0.25f;
      if ((mb >> k2) & 1ull) s = -1e8f;
      float d = s - mx;
      if (d > 8.f) {
        float sc = __expf(-d);
        l *= sc;
#pragma unroll
        for (int e = 0; e < 16; e++) acc[e] *= sc;
        mx = s; d = 0.f;
      }
      float p = __expf(d);
      l += p;
      const float4* vr = (const float4*)Vs[w][k2];
      float4 v0 = vr[0], v1 = vr[1], v2 = vr[2], v3 = vr[3];
      acc[0] = fmaf(p, v0.x, acc[0]);   acc[1] = fmaf(p, v0.y, acc[1]);
      acc[2] = fmaf(p, v0.z, acc[2]);   acc[3] = fmaf(p, v0.w, acc[3]);
      acc[4] = fmaf(p, v1.x, acc[4]);   acc[5] = fmaf(p, v1.y, acc[5]);
      acc[6] = fmaf(p, v1.z, acc[6]);   acc[7] = fmaf(p, v1.w, acc[7]);
      acc[8] = fmaf(p, v2.x, acc[8]);   acc[9] = fmaf(p, v2.y, acc[9]);
      acc[10] = fmaf(p, v2.z, acc[10]); acc[11] = fmaf(p, v2.w, acc[11]);
      acc[12] = fmaf(p, v3.x, acc[12]); acc[13] = fmaf(p, v3.y, acc[13]);
      acc[14] = fmaf(p, v3.z, acc[14]); acc[15] = fmaf(p, v3.w, acc[15]);
    }
  }
  ((float4*)Ms[w][lane])[0] = make_float4(acc[0], acc[1], acc[2], acc[3]);
  ((float4*)Ms[w][lane])[1] = make_float4(acc[4], acc[5], acc[6], acc[7]);
  ((float4*)Ms[w][lane])[2] = make_float4(acc[8], acc[9], acc[10], acc[11]);
  ((float4*)Ms[w][lane])[3] = make_float4(acc[12], acc[13], acc[14], acc[15]);
  Ms[w][lane][16] = mx;
  Ms[w][lane][17] = l;
  __syncthreads();
  float m0 = Ms[0][lane][16], m1 = Ms[1][lane][16];
  float m2 = Ms[2][lane][16], m3 = Ms[3][lane][16];
  float mstar = fmaxf(fmaxf(m0, m1), fmaxf(m2, m3));
  float f0 = __expf(m0 - mstar), f1 = __expf(m1 - mstar);
  float f2 = __expf(m2 - mstar), f3 = __expf(m3 - mstar);
  float L = f0 * Ms[0][lane][17] + f1 * Ms[1][lane][17] +
            f2 * Ms[2][lane][17] + f3 * Ms[3][lane][17];
  float invL = 1.0f / L;
  float o[4];
#pragma unroll
  for (int e = 0; e < 4; e++) {
    int ei = w * 4 + e;
    o[e] = (f0 * Ms[0][lane][ei] + f1 * Ms[1][lane][ei] +
            f2 * Ms[2][lane][ei] + f3 * Ms[3][lane][ei]) * invL;
  }
  *(float4*)(Hd + ((size_t)(b * kN + q)) * kD + h * kDK + w * 4) =
      make_float4(o[0], o[1], o[2], o[3]);
}

// ==== decoder (algebraic: K/V never materialized) ====

__global__ __launch_bounds__(256) void dec_prep(
    const float* __restrict__ enh, const int* __restrict__ tgt_idx,
    const int* __restrict__ cur_idx, const int* __restrict__ cen_idx,
    const float* __restrict__ Wq,
    const float* __restrict__ ln1_g, const float* __restrict__ ln1_b,
    const float* __restrict__ dec_wk,
    float* __restrict__ out_curf, float* __restrict__ out_cenf,
    float* __restrict__ tgtf_ws, float* __restrict__ qk_ws) {
  __shared__ float tgtf_s[128], tgtn[128], qd[128];
  int b = blockIdx.x, t = threadIdx.x;
  int lane = t & 63, w = t >> 6;
  int ti = tgt_idx[b], cui = cur_idx[b];
  if (t < 128) {
    float tf = enh[((size_t)b * kN + ti) * kD + t];
    tgtf_s[t] = tf;
    tgtf_ws[b * kD + t] = tf;
    out_curf[b * kD + t] = enh[((size_t)b * kN + cui) * kD + t];
  }
  for (int i = t; i < kNC * kD; i += 256) {
    int c = i >> 7, e = i & 127;
    out_cenf[((size_t)b * kNC + c) * kD + e] =
        enh[((size_t)b * kN + cen_idx[b * kNC + c]) * kD + e];
  }
  __syncthreads();
  if (w == 0) {
    float vx = tgtf_s[lane * 2], vy = tgtf_s[lane * 2 + 1];
    float mean = wredsum(vx + vy) * (1.0f / 128.f);
    float dx = vx - mean, dy = vy - mean;
    float var = wredsum(dx * dx + dy * dy) * (1.0f / 128.f);
    float rstd = rsqrtf(var + 1e-5f);
    tgtn[lane * 2] = dx * rstd * ln1_g[lane * 2] + ln1_b[lane * 2];
    tgtn[lane * 2 + 1] = dy * rstd * ln1_g[lane * 2 + 1] + ln1_b[lane * 2 + 1];
  }
  __syncthreads();
  if (t < 128) {
    float a = 0.f;
#pragma unroll 8
    for (int k = 0; k < 128; k++) a = fmaf(tgtn[k], Wq[k * 128 + t], a);
    qd[t] = a;
  }
  __syncthreads();
  int h = t >> 5, d0 = (t & 31) * 4;
#pragma unroll
  for (int j = 0; j < 4; j++) {
    int d = d0 + j;
    const float4* wp = (const float4*)(dec_wk + (((size_t)h * 128 + d) << 4));
    float a = 0.f;
#pragma unroll
    for (int r = 0; r < 4; r++) {
      float4 wv = wp[r];
      a += wv.x * qd[h * 16 + r * 4] + wv.y * qd[h * 16 + r * 4 + 1] +
           wv.z * qd[h * 16 + r * 4 + 2] + wv.w * qd[h * 16 + r * 4 + 3];
    }
    qk_ws[b * 1024 + h * 128 + d] = 0.25f * a;
  }
}

__global__ __launch_bounds__(256) void dec_score(
    const float* __restrict__ enh, const float* __restrict__ ln_g,
    const float* __restrict__ ln_b, const float* __restrict__ qk_ws,
    const unsigned long long* __restrict__ padbits,
    float* __restrict__ ln_ws, float* __restrict__ scores) {
  __shared__ float qs[8][128];
  int b = blockIdx.x, nt = blockIdx.y, t = threadIdx.x;
  for (int i = t; i < 1024; i += 256) ((float*)qs)[i] = qk_ws[b * 1024 + i];
  __syncthreads();
  int w = t >> 6, lane = t & 63, ri = lane >> 2, q4 = lane & 3;
  int n = nt * 64 + w * 16 + ri;
  const float* row = enh + ((size_t)b * kN + n) * kD;
  float4 xv[8];
#pragma unroll
  for (int j = 0; j < 8; j++) xv[j] = *(const float4*)(row + j * 16 + q4 * 4);
  float s1 = 0.f;
#pragma unroll
  for (int j = 0; j < 8; j++) s1 += xv[j].x + xv[j].y + xv[j].z + xv[j].w;
  s1 = red4(s1);
  float mean = s1 * (1.0f / 128.f);
  float s2 = 0.f;
#pragma unroll
  for (int j = 0; j < 8; j++) {
    xv[j].x -= mean; xv[j].y -= mean; xv[j].z -= mean; xv[j].w -= mean;
    s2 += xv[j].x * xv[j].x + xv[j].y * xv[j].y + xv[j].z * xv[j].z +
          xv[j].w * xv[j].w;
  }
  s2 = red4(s2);
  float rstd = rsqrtf(s2 * (1.0f / 128.f) + 1e-5f);
#pragma unroll
  for (int j = 0; j < 8; j++) {
    int d0 = j * 16 + q4 * 4;
    float4 g = *(const float4*)(ln_g + d0);
    float4 be = *(const float4*)(ln_b + d0);
    xv[j].x = xv[j].x * rstd * g.x + be.x;
    xv[j].y = xv[j].y * rstd * g.y + be.y;
    xv[j].z = xv[j].z * rstd * g.z + be.z;
    xv[j].w = xv[j].w * rstd * g.w + be.w;
    *(float4*)(ln_ws + ((size_t)b * kN + n) * kD + d0) = xv[j];
  }
  bool mk = (padbits[b * 16 + (n >> 6)] >> (n & 63)) & 1ull;
#pragma unroll
  for (int h = 0; h < 8; h++) {
    float p = 0.f;
#pragma unroll
    for (int j = 0; j < 8; j++) {
      float4 qv = *(const float4*)&qs[h][j * 16 + q4 * 4];
      p += xv[j].x * qv.x + xv[j].y * qv.y + xv[j].z * qv.z + xv[j].w * qv.w;
    }
    p = red4(p);
    if (q4 == 0) scores[((size_t)b * 8 + h) * 1024 + n] = mk ? -1e8f : p;
  }
}

__global__ __launch_bounds__(256) void dec_softmax(
    const float* __restrict__ scores, float* __restrict__ ml) {
  int b = blockIdx.x, t = threadIdx.x, w = t >> 6, lane = t & 63;
  for (int hi = 0; hi < 2; hi++) {
    int h = w + hi * 4;
    const float* sr = scores + ((size_t)b * 8 + h) * 1024;
    float v[16];
    float m = -3.0e38f;
#pragma unroll
    for (int i = 0; i < 16; i++) { v[i] = sr[i * 64 + lane]; m = fmaxf(m, v[i]); }
    m = wredmax(m);
    float l = 0.f;
#pragma unroll
    for (int i = 0; i < 16; i++) l += __expf(v[i] - m);
    l = wredsum(l);
    if (lane == 0) { ml[(b * 8 + h) * 2] = m; ml[(b * 8 + h) * 2 + 1] = l; }
  }
}

__global__ __launch_bounds__(256) void dec_attnsum(
    const float* __restrict__ ln_ws, const float* __restrict__ scores,
    const float* __restrict__ ml, float* __restrict__ partial) {
  __shared__ float lns[64][128];
  __shared__ float ps[8][64];
  int b = blockIdx.x, nt = blockIdx.y, t = threadIdx.x;
  for (int i = t; i < 64 * 32; i += 256) {
    int nn = i >> 5, c4 = i & 31;
    *(float4*)&lns[nn][c4 * 4] =
        *(const float4*)(ln_ws + ((size_t)b * kN + nt * 64 + nn) * kD + c4 * 4);
  }
  for (int i = t; i < 512; i += 256) {
    int h = i >> 6, nn = i & 63;
    float m = ml[(b * 8 + h) * 2], l = ml[(b * 8 + h) * 2 + 1];
    ps[h][nn] =
        __expf(scores[((size_t)b * 8 + h) * 1024 + nt * 64 + nn] - m) / l;
  }
  __syncthreads();
  int h = t >> 5, d0 = (t & 31) * 4;
  float4 acc = make_float4(0.f, 0.f, 0.f, 0.f);
  for (int nn = 0; nn < 64; nn++) {
    float p = ps[h][nn];
    float4 lv = *(const float4*)&lns[nn][d0];
    acc.x = fmaf(p, lv.x, acc.x); acc.y = fmaf(p, lv.y, acc.y);
    acc.z = fmaf(p, lv.z, acc.z); acc.w = fmaf(p, lv.w, acc.w);
  }
  *(float4*)(partial + ((size_t)(b * 16 + nt) * 8 + h) * 128 + d0) = acc;
}

// dec_tail: 1024 threads, parallel-k matvecs via LDS partial reduce
__global__ __launch_bounds__(1024) void dec_tail(
    const float* __restrict__ partial, const float* __restrict__ dec_wv,
    const float* __restrict__ dwo, const float* __restrict__ tgtf_ws,
    const float* __restrict__ cenf_g, const float* __restrict__ Kp,
    const int* __restrict__ cen_idx, const int* __restrict__ center_mask,
    const float* __restrict__ ln2_g, const float* __restrict__ ln2_b,
    const float* __restrict__ w1, const float* __restrict__ b1,
    const float* __restrict__ w2, const float* __restrict__ b2,
    const float* __restrict__ tgt_W, const float* __restrict__ tgt_b,
    const float* __restrict__ ptr_wq,
    float* __restrict__ out_selidx, float* __restrict__ out_selfeat,
    float* __restrict__ out_logp) {
  __shared__ float wsum[8][132];
  __shared__ float red[8][132];
  __shared__ float red2[2][520];
  __shared__ float red16[16][68];
  __shared__ float tgtf[128], hdd[128], dechs[128], decfs[128], dects[512],
                   embs[128], qps[128];
  __shared__ int bi_s;
  int b = blockIdx.x, t = threadIdx.x;
  int c = t & 127, p = t >> 7;
  int lane = t & 63, w = t >> 6;

  {
    float a = 0.f;
#pragma unroll
    for (int tt = 0; tt < 16; tt++)
      a += partial[((size_t)(b * 16 + tt) * 8 + p) * 128 + c];
    wsum[p][c] = a;
    if (t < 128) tgtf[t] = tgtf_ws[b * kD + t];
  }
  __syncthreads();

  {
    int h = c >> 4, e = c & 15;
    float a = 0.f;
#pragma unroll
    for (int i = 0; i < 16; i++) {
      int d = p * 16 + i;
      a = fmaf(wsum[h][d], dec_wv[((size_t)h * 128 + d) * 16 + e], a);
    }
    red[p][c] = a;
  }
  __syncthreads();
  if (t < 128) {
    float a = 0.f;
#pragma unroll
    for (int q = 0; q < 8; q++) a += red[q][t];
    hdd[t] = a;
  }
  __syncthreads();

  {
    float a = 0.f;
#pragma unroll
    for (int i = 0; i < 16; i++) {
      int k = p * 16 + i;
      a = fmaf(hdd[k], dwo[k * 128 + c], a);
    }
    red[p][c] = a;
  }
  __syncthreads();
  if (t < 128) {
    float a = 0.f;
#pragma unroll
    for (int q = 0; q < 8; q++) a += red[q][t];
    dechs[t] = a + tgtf[t];
  }
  __syncthreads();

  if (w == 0) {
    float vx = dechs[lane * 2], vy = dechs[lane * 2 + 1];
    float mean = wredsum(vx + vy) * (1.0f / 128.f);
    float dx = vx - mean, dy = vy - mean;
    float var = wredsum(dx * dx + dy * dy) * (1.0f / 128.f);
    float rstd = rsqrtf(var + 1e-5f);
    decfs[lane * 2] = dx * rstd * ln2_g[lane * 2] + ln2_b[lane * 2];
    decfs[lane * 2 + 1] = dy * rstd * ln2_g[lane * 2 + 1] + ln2_b[lane * 2 + 1];
  }
  __syncthreads();

  {
    int c5 = t & 511, p2 = t >> 9;
    float a = 0.f;
#pragma unroll 8
    for (int i = 0; i < 64; i++) {
      int k = p2 * 64 + i;
      a = fmaf(decfs[k], w1[k * 512 + c5], a);
    }
    red2[p2][c5] = a;
  }
  __syncthreads();
  if (t < 512) dects[t] = fmaxf(red2[0][t] + red2[1][t] + b1[t], 0.f);
  __syncthreads();

  {
    float a = 0.f;
#pragma unroll 8
    for (int i = 0; i < 64; i++) {
      int k = p * 64 + i;
      a = fmaf(dects[k], w2[k * 128 + c], a);
    }
    red[p][c] = a;
  }
  __syncthreads();
  if (t < 128) {
    float a = 0.f;
#pragma unroll
    for (int q = 0; q < 8; q++) a += red[q][t];
    decfs[t] = a + b2[t] + dechs[t];
  }
  __syncthreads();

  {
    float a = 0.f;
#pragma unroll
    for (int i = 0; i < 32; i++) {
      int k = p * 32 + i;
      float vkk = (k < 128) ? decfs[k] : tgtf[k - 128];
      a = fmaf(vkk, tgt_W[k * 128 + c], a);
    }
    red[p][c] = a;
  }
  __syncthreads();
  if (t < 128) {
    float a = 0.f;
#pragma unroll
    for (int q = 0; q < 8; q++) a += red[q][t];
    embs[t] = a + tgt_b[t];
  }
  __syncthreads();

  {
    float a = 0.f;
#pragma unroll
    for (int i = 0; i < 16; i++) {
      int k = p * 16 + i;
      a = fmaf(embs[k], ptr_wq[k * 128 + c], a);
    }
    red[p][c] = a;
  }
  __syncthreads();
  if (t < 128) {
    float a = 0.f;
#pragma unroll
    for (int q = 0; q < 8; q++) a += red[q][t];
    qps[t] = a;
  }
  __syncthreads();

  {
    int cen = t & 63, p16 = t >> 6;
    float a = 0.f;
#pragma unroll
    for (int i = 0; i < 8; i++) {
      int k = p16 * 8 + i;
      a = fmaf(qps[k], Kp[((size_t)(b * kNC + cen)) * kD + k], a);
    }
    red16[p16][cen] = a;
  }
  __syncthreads();
  if (w == 0) {
    float u = 0.f;
#pragma unroll
    for (int q = 0; q < 16; q++) u += red16[q][lane];
    u *= 0.08838834764831845f;
    u = 10.0f * tanhf(u);
    if (center_mask[b * kNC + lane] == 1) u = -1e8f;
    float m = wredmax(u);
    float ex = __expf(u - m);
    float sum = wredsum(ex);
    out_logp[b * kNC + lane] = u - m - logf(sum);
    float bm = u; int bi = lane;
#pragma unroll
    for (int o = 32; o; o >>= 1) {
      float om = __shfl_xor(bm, o);
      int oi = __shfl_xor(bi, o);
      if (om > bm || (om == bm && oi < bi)) { bm = om; bi = oi; }
    }
    if (lane == 0) {
      out_selidx[b] = (float)cen_idx[b * kNC + bi];
      bi_s = bi;
    }
  }
  __syncthreads();
  if (t < 128)
    out_selfeat[b * kD + t] = cenf_g[((size_t)(b * kNC + bi_s)) * kD + t];
}

// ---- host ----

extern "C" void kernel_launch(void* const* d_in, const int* in_sizes, int n_in,
                              void* d_out, int out_size, void* d_ws,
                              size_t ws_size, hipStream_t stream) {
  (void)in_sizes; (void)n_in; (void)out_size; (void)ws_size;
  const float* node_inputs = (const float*)d_in[0];
  const int* pad_mask = (const int*)d_in[1];
  const int* edge_mask = (const int*)d_in[2];
  const int* center_mask = (const int*)d_in[3];
  const int* center_index = (const int*)d_in[4];
  const int* target_index = (const int*)d_in[5];
  const int* current_index = (const int*)d_in[6];
  const float* init_W = (const float*)d_in[8];
  const float* init_b = (const float*)d_in[9];
  const float* enc_wq = (const float*)d_in[10];
  const float* enc_wk = (const float*)d_in[11];
  const float* enc_wv = (const float*)d_in[12];
  const float* enc_wo = (const float*)d_in[13];
  const float* enc_ln1_g = (const float*)d_in[14];
  const float* enc_ln1_b = (const float*)d_in[15];
  const float* enc_w1 = (const float*)d_in[16];
  const float* enc_b1 = (const float*)d_in[17];
  const float* enc_w2 = (const float*)d_in[18];
  const float* enc_b2 = (const float*)d_in[19];
  const float* enc_ln2_g = (const float*)d_in[20];
  const float* enc_ln2_b = (const float*)d_in[21];
  const float* dec_wq = (const float*)d_in[22];
  const float* dec_wk = (const float*)d_in[23];
  const float* dec_wv = (const float*)d_in[24];
  const float* dec_wo = (const float*)d_in[25];
  const float* dec_ln1_g = (const float*)d_in[26];
  const float* dec_ln1_b = (const float*)d_in[27];
  const float* dec_w1 = (const float*)d_in[28];
  const float* dec_b1 = (const float*)d_in[29];
  const float* dec_w2 = (const float*)d_in[30];
  const float* dec_b2 = (const float*)d_in[31];
  const float* dec_ln2_g = (const float*)d_in[32];
  const float* dec_ln2_b = (const float*)d_in[33];
  const float* tgt_W = (const float*)d_in[34];
  const float* tgt_b = (const float*)d_in[35];
  const float* ptr_wq = (const float*)d_in[36];
  const float* ptr_wk = (const float*)d_in[37];

  float* out_enh = (float*)d_out;
  float* out_curf = out_enh + kB * kN * kD;
  float* out_selidx = out_curf + kB * kD;
  float* out_selfeat = out_selidx + kB;
  float* out_logp = out_selfeat + kB * kD;
  float* out_cenf = out_logp + kB * kNC;

  char* wsp = (char*)d_ws;
  size_t off = 0;
  auto alloc = [&](size_t n) {
    char* p = wsp + off;
    off = (off + n + 255) & ~(size_t)255;
    return p;
  };
  float* x   = (float*)alloc(kR * kD * 4);
  float* h2  = (float*)alloc(kR * kD * 4);
  float* Qb  = (float*)alloc(kR * kD * 4);
  float* Kb  = (float*)alloc(kR * kD * 4);
  float* Vb  = (float*)alloc(kR * kD * 4);
  float* Hd  = (float*)alloc(kR * kD * 4);
  float* tb  = (float*)alloc(kR * kFF * 4);
  unsigned long long* bits_t  = (unsigned long long*)alloc(kR * 16 * 8);
  unsigned long long* padbits = (unsigned long long*)alloc(kB * 16 * 8);
  float* ewqkv = (float*)alloc(kEnc * 3 * kD * kD * 4);
  float* dqkvW = (float*)alloc(3 * kD * kD * 4);
  float* ln_ws = (float*)alloc(kR * kD * 4);
  float* scores_ws = (float*)alloc(kB * kH * kN * 4);
  float* ml_ws = (float*)alloc(kB * kH * 2 * 4);
  float* partial_ws = (float*)alloc(kB * 16 * kH * kD * 4);
  float* qk_ws = (float*)alloc(kB * kH * kD * 4);
  float* tgtf_ws = (float*)alloc(kB * kD * 4);
  float* Kp_ws = (float*)alloc(kB * kNC * kD * 4);

  // prologue
  repack_qkv<<<(kEnc * kD * kD + 255) / 256, 256, 0, stream>>>(
      enc_wq, enc_wk, enc_wv, ewqkv, kEnc);
  repack_qkv<<<(kD * kD + 255) / 256, 256, 0, stream>>>(
      dec_wq, dec_wk, dec_wv, dqkvW, 1);
  pack_mask<<<kB * kN, 256, 0, stream>>>(edge_mask, pad_mask, bits_t);
  pack_pad<<<kB, 256, 0, stream>>>(pad_mask, padbits);
  init_proj<<<kR * kD / 256, 256, 0, stream>>>(node_inputs, init_W, init_b, x);

  // encoder
  for (int l = 0; l < kEnc; l++) {
    const float* wo_l = enc_wo + (size_t)l * kH * kDK * kD;
    gtile<128, 8, 1, 0, 2><<<dim3(kR / 8, 3), 256, 0, stream>>>(
        x, ewqkv + (size_t)l * 3 * kD * kD, enc_ln1_g + l * kD,
        enc_ln1_b + l * kD, nullptr, nullptr, Qb, Kb, Vb, kD);
    attn_flash<<<dim3(kB * kH, kN / 64), 256, 0, stream>>>(Qb, Kb, Vb, bits_t, Hd);
    gtile<128, 8, 0, 0, 0><<<dim3(kR / 8, 1), 256, 0, stream>>>(
        Hd, wo_l, nullptr, nullptr, nullptr, x, h2, nullptr, nullptr, kD);
    gtile<128, 8, 1, 1, 0><<<dim3(kR / 8, kFF / 128), 256, 0, stream>>>(
        h2, enc_w1 + (size_t)l * kD * kFF, enc_ln2_g + l * kD,
        enc_ln2_b + l * kD, enc_b1 + l * kFF, nullptr, tb, nullptr, nullptr, kFF);
    float* xout = (l == kEnc - 1) ? out_enh : x;
    gtile<512, 8, 0, 0, 0><<<dim3(kR / 8, 1), 256, 0, stream>>>(
        tb, enc_w2 + (size_t)l * kFF * kD, nullptr, nullptr, enc_b2 + l * kD,
        h2, xout, nullptr, nullptr, kD);
  }

  // decoder (algebraic)
  dec_prep<<<kB, 256, 0, stream>>>(out_enh, target_index, current_index,
                                   center_index, dqkvW, dec_ln1_g, dec_ln1_b,
                                   dec_wk, out_curf, out_cenf, tgtf_ws, qk_ws);
  gtile<128, 8, 0, 0, 0><<<dim3(kB * kNC / 8, 1), 256, 0, stream>>>(
      out_cenf, ptr_wk, nullptr, nullptr, nullptr, nullptr, Kp_ws, nullptr,
      nullptr, kD);
  dec_score<<<dim3(kB, 16), 256, 0, stream>>>(out_enh, dec_ln1_g, dec_ln1_b,
                                              qk_ws, padbits, ln_ws, scores_ws);
  dec_softmax<<<kB, 256, 0, stream>>>(scores_ws, ml_ws);
  dec_attnsum<<<dim3(kB, 16), 256, 0, stream>>>(ln_ws, scores_ws, ml_ws,
                                                partial_ws);
  dec_tail<<<kB, 1024, 0, stream>>>(
      partial_ws, dec_wv, dec_wo, tgtf_ws, out_cenf, Kp_ws, center_index,
      center_mask, dec_ln2_g, dec_ln2_b, dec_w1, dec_b1, dec_w2, dec_b2,
      tgt_W, tgt_b, ptr_wq, out_selidx, out_selfeat, out_logp);
}